// Round 7
// baseline (1547.613 us; speedup 1.0000x reference)
//
#include <hip/hip_runtime.h>
#include <hip/hip_bf16.h>
#include <math.h>

typedef __bf16 bf16_t;
typedef __bf16 bf16x8 __attribute__((ext_vector_type(8)));
typedef __bf16 bf16x4 __attribute__((ext_vector_type(4)));
typedef float  f32x4  __attribute__((ext_vector_type(4)));

#define S_TOT 1024
#define T_W   32
#define D_EMB 300
#define KP    320
#define G3    768
#define Hh    256
#define H2    512
#define E_TOT 3072
#define NCANON 33

// fast gate math: ~5 VALU ops each (v_exp_f32 + v_rcp_f32); error ~2ulp f32.
__device__ __forceinline__ float fsigm(float x) {
  float e = __builtin_amdgcn_exp2f(x * -1.4426950408889634f);
  return __builtin_amdgcn_rcpf(1.f + e);
}
__device__ __forceinline__ float ftanh_(float x) {
  float e = __builtin_amdgcn_exp2f(x * 2.8853900817779268f);
  return 1.f - 2.f * __builtin_amdgcn_rcpf(1.f + e);
}

// ---------- dtype detector ----------
__global__ void k_detect(const unsigned short* __restrict__ w, int* __restrict__ flag) {
  int lane = threadIdx.x;
  int sane = 0;
  for (int i = lane; i < 256; i += 64) {
    unsigned short v = w[2 * i];
    int ex = (v >> 7) & 0xFF;
    sane += (ex >= 96 && ex <= 134) ? 1 : 0;
  }
  #pragma unroll
  for (int o = 32; o > 0; o >>= 1) sane += __shfl_down(sane, o, 64);
  if (lane == 0) flag[0] = (sane >= 128) ? 1 : 0;
}

// ---------- canonicalize all float tensors to f32 ----------
struct Canon {
  const void* src[NCANON];
  int off[NCANON + 1];
};
__global__ void k_canon(Canon c, const int* __restrict__ flag, float* __restrict__ dst) {
  int i = blockIdx.x * 256 + threadIdx.x;
  if (i >= c.off[NCANON]) return;
  int seg = 0;
  while (c.off[seg + 1] <= i) ++seg;
  int j = i - c.off[seg];
  dst[i] = flag[0] ? (float)((const bf16_t*)c.src[seg])[j]
                   : ((const float*)c.src[seg])[j];
}

__global__ void k_lens(const int* __restrict__ x, int* __restrict__ lens) {
  int s = blockIdx.x * blockDim.x + threadIdx.x;
  if (s >= S_TOT) return;
  int c = 0;
  for (int t = 0; t < T_W; ++t) c += (x[s * T_W + t] != 0) ? 1 : 0;
  lens[s] = c;
}

// wih [2][768][512] f32 -> [2][512][768] f32
__global__ void k_transpose(const float* __restrict__ w, float* __restrict__ out) {
  __shared__ float tile[32][33];
  int d  = blockIdx.z;
  int n0 = blockIdx.x * 32, k0 = blockIdx.y * 32;
  int tx = threadIdx.x & 31, ty = threadIdx.x >> 5;
  for (int i = ty; i < 32; i += 8)
    tile[i][tx] = w[((size_t)d * G3 + n0 + i) * H2 + k0 + tx];
  __syncthreads();
  for (int i = ty; i < 32; i += 8)
    out[((size_t)d * H2 + k0 + i) * G3 + n0 + tx] = tile[tx][i];
}

// ---------- pack whh [2][768][256] f32 -> B-fragment-major bf16 ----------
// layout: [dir][wave(8)][sl(6)][k0(8)][lane(64)][8 bf16], sl = g*2+jt
__global__ void k_packB(const float* __restrict__ whh, bf16_t* __restrict__ packed) {
  int id = blockIdx.x * 256 + threadIdx.x;     // 49152 groups of 8 elems
  if (id >= 49152) return;
  int lane = id & 63;
  int k0 = (id >> 6) & 7;
  int t9 = id >> 9;
  int sl = t9 % 6;
  int wb = t9 / 6;
  int wv = wb & 7;
  int dir = wb >> 3;
  int g = sl >> 1, jt = sl & 1;
  int l16 = lane & 15, quad = lane >> 4;
  int n = g * Hh + wv * 32 + jt * 16 + l16;
  const float* src = whh + ((size_t)dir * G3 + n) * Hh + k0 * 32 + quad * 8;
  bf16_t* dst = packed + (size_t)id * 8;
  #pragma unroll
  for (int i = 0; i < 8; ++i) dst[i] = (bf16_t)src[i];
}

// ---------- pack wih [2][768][300] f32 -> MFMA-fragment-major bf16, K padded 320 ----------
__global__ void k_packWih(const float* __restrict__ wih, bf16_t* __restrict__ out) {
  int id = blockIdx.x * 256 + threadIdx.x;     // 61440 frags of 8
  if (id >= 61440) return;
  int lane = id & 63;
  int su = id >> 6;
  int s  = su % 40;
  int n0 = (su / 40) % 12;
  int dir = su / 480;
  int j = s / 10, k0 = s % 10;
  int l16 = lane & 15, quad = lane >> 4;
  int n = n0 * 64 + j * 16 + l16;
  int c = k0 * 32 + quad * 8;
  const float* src = wih + ((size_t)dir * G3 + n) * D_EMB + c;
  bf16_t* dst = out + (size_t)id * 8;
  #pragma unroll
  for (int i = 0; i < 8; ++i)
    dst[i] = (c + i < D_EMB) ? (bf16_t)src[i] : (bf16_t)0.f;
}

// ---------- combined bias ----------
__global__ void k_biasC(const float* __restrict__ bih, const float* __restrict__ bhh,
                        float* __restrict__ out) {
  int i = blockIdx.x * 256 + threadIdx.x;
  if (i >= 2 * G3) return;
  int c = i % G3;
  out[i] = bih[i] + (c < 2 * Hh ? bhh[i] : 0.f);
}

// Packed gi layout (consumer-ordered for k_gruM):
//   giP[sb][t][tid(512)][24] bf16, 48 B contiguous per consumer thread/step.
//   sb = sent/16; tid = w*64 + quad*16 + l16 (consumer coords);
//   slot = r*6 + g*2 + jt where sent = sb*16 + quad*4 + r, col = g*256+w*32+jt*16+l16.

// ---------- fused gather + input projection (packed output) ----------
__global__ __launch_bounds__(256, 1) void k_giB(
    const int* __restrict__ toks, const void* __restrict__ embed,
    const bf16_t* __restrict__ wpk,   // this dir: [12][40][64][8]
    const float* __restrict__ bih,    // this dir's combined bias [768]
    const int* __restrict__ flag, bf16_t* __restrict__ gi, int mbase, int tlog) {
  __shared__ __align__(16) bf16_t Bt[2][20480];   // 2 x 40KB
  int tid = threadIdx.x;
  int wave = tid >> 6, lane = tid & 63;
  int l16 = lane & 15, quad = lane >> 4;
  int m0 = blockIdx.x * 128;
  int isb = flag[0];
  int T = 1 << tlog;

  // ---- A fragments from global (once): ah/al[mi][k0] ----
  bf16x8 ah[2][10], al[2][10];
  #pragma unroll
  for (int mi = 0; mi < 2; ++mi) {
    int tok = toks[mbase + m0 + wave * 32 + mi * 16 + l16];
    if (isb) {
      const bf16_t* er = (const bf16_t*)embed + (size_t)tok * D_EMB;
      #pragma unroll
      for (int k0 = 0; k0 < 10; ++k0) {
        int c = k0 * 32 + quad * 8;
        bf16x8 v = {};
        if (c + 8 <= D_EMB) {
          bf16x4 t0 = *(const bf16x4*)(er + c);
          bf16x4 t1 = *(const bf16x4*)(er + c + 4);
          v[0]=t0[0]; v[1]=t0[1]; v[2]=t0[2]; v[3]=t0[3];
          v[4]=t1[0]; v[5]=t1[1]; v[6]=t1[2]; v[7]=t1[3];
        } else if (c < D_EMB) {
          bf16x4 t0 = *(const bf16x4*)(er + c);
          v[0]=t0[0]; v[1]=t0[1]; v[2]=t0[2]; v[3]=t0[3];
        }
        ah[mi][k0] = v;
        al[mi][k0] = (bf16x8){};
      }
    } else {
      const float* er = (const float*)embed + (size_t)tok * D_EMB;
      #pragma unroll
      for (int k0 = 0; k0 < 10; ++k0) {
        int c = k0 * 32 + quad * 8;
        float v[8];
        #pragma unroll
        for (int i = 0; i < 8; ++i) v[i] = 0.f;
        if (c + 4 <= D_EMB) { float4 t = *(const float4*)(er + c);
                              v[0]=t.x; v[1]=t.y; v[2]=t.z; v[3]=t.w; }
        if (c + 8 <= D_EMB) { float4 t = *(const float4*)(er + c + 4);
                              v[4]=t.x; v[5]=t.y; v[6]=t.z; v[7]=t.w; }
        bf16x8 h, l;
        #pragma unroll
        for (int i = 0; i < 8; ++i) {
          bf16_t hv = (bf16_t)v[i];
          h[i] = hv; l[i] = (bf16_t)(v[i] - (float)hv);
        }
        ah[mi][k0] = h; al[mi][k0] = l;
      }
    }
  }

  bf16x8 stg[10];
  {
    const bf16_t* base = wpk + (size_t)(wave * 10) * 512 + lane * 8;
    #pragma unroll
    for (int i = 0; i < 10; ++i) stg[i] = *(const bf16x8*)(base + i * 512);
    bf16_t* dst = &Bt[0][(wave * 10) * 512 + lane * 8];
    #pragma unroll
    for (int i = 0; i < 10; ++i) *(bf16x8*)(dst + i * 512) = stg[i];
  }
  __syncthreads();

  for (int n0 = 0; n0 < 12; ++n0) {
    int cur = n0 & 1;
    if (n0 + 1 < 12) {
      const bf16_t* base = wpk + (size_t)(n0 + 1) * 20480
                         + (size_t)(wave * 10) * 512 + lane * 8;
      #pragma unroll
      for (int i = 0; i < 10; ++i) stg[i] = *(const bf16x8*)(base + i * 512);
    }
    f32x4 acc[2][4];
    #pragma unroll
    for (int mi = 0; mi < 2; ++mi)
      #pragma unroll
      for (int j = 0; j < 4; ++j) acc[mi][j] = (f32x4){0.f, 0.f, 0.f, 0.f};
    const bf16_t* Bc = Bt[cur];
    #pragma unroll
    for (int k0 = 0; k0 < 10; ++k0) {
      bf16x8 b[4];
      #pragma unroll
      for (int j = 0; j < 4; ++j)
        b[j] = *(const bf16x8*)&Bc[((j * 10 + k0) * 64 + lane) * 8];
      if (isb) {
        #pragma unroll
        for (int mi = 0; mi < 2; ++mi)
          #pragma unroll
          for (int j = 0; j < 4; ++j)
            acc[mi][j] = __builtin_amdgcn_mfma_f32_16x16x32_bf16(ah[mi][k0], b[j], acc[mi][j], 0, 0, 0);
      } else {
        #pragma unroll
        for (int mi = 0; mi < 2; ++mi)
          #pragma unroll
          for (int j = 0; j < 4; ++j)
            acc[mi][j] = __builtin_amdgcn_mfma_f32_16x16x32_bf16(al[mi][k0], b[j], acc[mi][j], 0, 0, 0);
        #pragma unroll
        for (int mi = 0; mi < 2; ++mi)
          #pragma unroll
          for (int j = 0; j < 4; ++j)
            acc[mi][j] = __builtin_amdgcn_mfma_f32_16x16x32_bf16(ah[mi][k0], b[j], acc[mi][j], 0, 0, 0);
      }
    }
    // ---- epilogue: packed gi write ----
    #pragma unroll
    for (int mi = 0; mi < 2; ++mi) {
      #pragma unroll
      for (int j = 0; j < 4; ++j) {
        int col = n0 * 64 + j * 16 + l16;
        float bb = bih[col];
        int g  = col >> 8;
        int w  = (col >> 5) & 7;
        int jt = (col >> 4) & 1;
        #pragma unroll
        for (int rr = 0; rr < 4; ++rr) {
          int row = m0 + wave * 32 + mi * 16 + quad * 4 + rr;
          int sent = row >> tlog, t = row & (T - 1);
          int sb = sent >> 4, cq = (sent >> 2) & 3, cr = sent & 3;
          size_t idx = (((size_t)sb * T + t) * 512 + (w * 64 + cq * 16 + l16)) * 24
                     + cr * 6 + g * 2 + jt;
          gi[idx] = (bf16_t)(acc[mi][j][rr] + bb);
        }
      }
    }
    if (n0 + 1 < 12) {
      bf16_t* dst = &Bt[cur ^ 1][(wave * 10) * 512 + lane * 8];
      #pragma unroll
      for (int i = 0; i < 10; ++i) *(bf16x8*)(dst + i * 512) = stg[i];
      __syncthreads();
    }
  }
}

// ---------- f32 SGEMM. mode: 0=f32 out, 1=bf16 flat, 2=bf16 packed-gi (T=32) ----------
__global__ __launch_bounds__(256) void k_sgemm(
    const float* __restrict__ A, const float* __restrict__ B,
    const float* __restrict__ bias, void* __restrict__ C,
    int M, int N, int K, int mode) {
  __shared__ float As[32][65];
  __shared__ float Bs[32][65];
  int bm = blockIdx.x * 64, bn = blockIdx.y * 64;
  int tid = threadIdx.x;
  int tx = tid & 15, ty = tid >> 4;
  float acc[4][4] = {};
  for (int k0 = 0; k0 < K; k0 += 32) {
    for (int i = tid; i < 64 * 32; i += 256) {
      int m = i >> 5, k = i & 31;
      As[k][m] = (bm + m < M) ? A[(size_t)(bm + m) * K + k0 + k] : 0.f;
    }
    for (int i = tid; i < 32 * 64; i += 256) {
      int k = i >> 6, n = i & 63;
      Bs[k][n] = B[(size_t)(k0 + k) * N + bn + n];
    }
    __syncthreads();
    #pragma unroll 8
    for (int k = 0; k < 32; ++k) {
      float a[4], b[4];
      #pragma unroll
      for (int i = 0; i < 4; ++i) a[i] = As[k][ty + i * 16];
      #pragma unroll
      for (int j = 0; j < 4; ++j) b[j] = Bs[k][tx + j * 16];
      #pragma unroll
      for (int i = 0; i < 4; ++i)
        #pragma unroll
        for (int j = 0; j < 4; ++j) acc[i][j] += a[i] * b[j];
    }
    __syncthreads();
  }
  for (int i = 0; i < 4; ++i) {
    int m = bm + ty + i * 16;
    if (m >= M) continue;
    for (int j = 0; j < 4; ++j) {
      int n = bn + tx + j * 16;
      float v = acc[i][j] + (bias ? bias[n] : 0.f);
      if (mode == 0) ((float*)C)[(size_t)m * N + n] = v;
      else if (mode == 1) ((bf16_t*)C)[(size_t)m * N + n] = (bf16_t)v;
      else {
        int sent = m >> 5, t = m & 31;
        int sb = sent >> 4, cq = (sent >> 2) & 3, cr = sent & 3;
        int g = n >> 8, w = (n >> 5) & 7, jt = (n >> 4) & 1, cl = n & 15;
        size_t idx = (((size_t)sb * 32 + t) * 512 + (w * 64 + cq * 16 + cl)) * 24
                   + cr * 6 + g * 2 + jt;
        ((bf16_t*)C)[idx] = (bf16_t)v;
      }
    }
  }
}

// ---------- batched MFMA GRU v6: v2 structure + packed gv + hA write swizzle ----------
// v2 (115us) revert: Bf[48] resident, hreg f32 state, fast gates, one lgkm-only
// barrier/step. New:
//  - gv from packed gi: 3x b128 loads/thread/step (was 24 scalar ushort);
//    double-buffered (ga/gb) and issued BEFORE the gate phase -> load-to-use
//    distance ~ gates+barrier+MFMA ~ 1000cyc, covers HBM latency.
//  - hA write swizzle q2^quad (read a8 at quad^(l16>>2)): breaks the 4-way
//    same-bank write conflict (m-stride 256B ≡ 0 mod 128B) without disturbing
//    the b128 A-frag read.
#define GVAL(v0, v1, v2, i) \
  ((i) < 8 ? (float)(v0)[(i)] : ((i) < 16 ? (float)(v1)[(i) - 8] : (float)(v2)[(i) - 16]))

#define GRU_MFMA_PH() do {                                                      \
  _Pragma("unroll")                                                             \
  for (int g = 0; g < 3; ++g)                                                   \
    _Pragma("unroll")                                                           \
    for (int jt = 0; jt < 2; ++jt) C[g][jt] = (f32x4){0.f, 0.f, 0.f, 0.f};      \
  _Pragma("unroll")                                                             \
  for (int k0 = 0; k0 < 8; ++k0) {                                              \
    bf16x8 a8 = *(const bf16x8*)&hA[cur][k0][l16][quad ^ (l16 >> 2)][0];        \
    _Pragma("unroll")                                                           \
    for (int g = 0; g < 3; ++g)                                                 \
      _Pragma("unroll")                                                         \
      for (int jt = 0; jt < 2; ++jt)                                            \
        C[g][jt] = __builtin_amdgcn_mfma_f32_16x16x32_bf16(                     \
            a8, Bf[(g * 2 + jt) * 8 + k0], C[g][jt], 0, 0, 0);                  \
  }                                                                             \
} while (0)

#define GRU_GATES_PH(tt, v0, v1, v2) do {                                       \
  int tt_ = (tt);                                                               \
  _Pragma("unroll")                                                             \
  for (int jt = 0; jt < 2; ++jt) {                                              \
    int q2 = jt * 2 + (l16 >> 3);                                               \
    int ii = l16 & 7;                                                           \
    _Pragma("unroll")                                                           \
    for (int r = 0; r < 4; ++r) {                                               \
      int m = quad * 4 + r;                                                     \
      float hp = hreg[jt][r];                                                   \
      float rr = fsigm(GVAL(v0, v1, v2, r * 6 + 0 + jt) + C[0][jt][r]);         \
      float zz = fsigm(GVAL(v0, v1, v2, r * 6 + 2 + jt) + C[1][jt][r]);         \
      float nn = ftanh_(GVAL(v0, v1, v2, r * 6 + 4 + jt) + rr * (C[2][jt][r] + bhn[jt])); \
      float hnew = nn + zz * (hp - nn);                                         \
      hreg[jt][r] = hnew;                                                       \
      hA[cur ^ 1][wave][m][q2 ^ quad][ii] = (bf16_t)hnew;                       \
      if (tt_ < Lm[r]) pmax[jt][r] = fmaxf(pmax[jt][r], hnew);                  \
    }                                                                           \
  }                                                                             \
} while (0)

__global__ __launch_bounds__(512)
__attribute__((amdgpu_waves_per_eu(2, 2)))
void k_gruM(
    const bf16_t* __restrict__ gi, size_t gi_dstride,
    const bf16_t* __restrict__ whhP, const float* __restrict__ bhh,
    const int* __restrict__ lens, float* __restrict__ pool,
    int T, int sbase, int nsent) {
  int dir = blockIdx.y;
  int tid = threadIdx.x;
  int wave = tid >> 6, lane = tid & 63;
  int l16 = lane & 15, quad = lane >> 4;
  int sblk = blockIdx.x * 16;
  const bf16_t* giD  = gi + (size_t)dir * gi_dstride;
  const float*  bhhD = bhh + (size_t)dir * G3;

  __shared__ __align__(16) bf16_t hA[2][8][16][4][8];

  // whh fragments, register-resident (shared across all steps)
  bf16x8 Bf[48];
  {
    const bf16_t* Bb = whhP + (size_t)dir * G3 * Hh + (size_t)wave * 48 * 512 + lane * 8;
    #pragma unroll
    for (int s = 0; s < 48; ++s) Bf[s] = *(const bf16x8*)(Bb + s * 512);
  }
  float bhn[2];
  #pragma unroll
  for (int jt = 0; jt < 2; ++jt)
    bhn[jt] = bhhD[2 * Hh + wave * 32 + jt * 16 + l16];
  int Lm[4];
  #pragma unroll
  for (int r = 0; r < 4; ++r) {
    int sa = sblk + quad * 4 + r;
    Lm[r] = (lens && sa < nsent) ? lens[sbase + sa] : T;
  }
  float pmax[2][4], hreg[2][4];
  #pragma unroll
  for (int jt = 0; jt < 2; ++jt)
    #pragma unroll
    for (int r = 0; r < 4; ++r) { pmax[jt][r] = -1e30f; hreg[jt][r] = 0.f; }

  // packed gi pointer: one per thread, advances by +-(512*24) per step
  int t0 = dir ? (T - 1) : 0;
  long long stepoff = dir ? -(long long)(512 * 24) : (long long)(512 * 24);
  const bf16_t* gp = giD + (((size_t)(sblk >> 4) * T + t0) * 512 + tid) * 24;

  // zero read buffer 0
  {
    bf16_t* hz = &hA[0][0][0][0][0];
    for (int i = tid; i < 8 * 16 * 4 * 8; i += 512) hz[i] = (bf16_t)0.f;
  }

  bf16x8 ga0, ga1, ga2, gb0, gb1, gb2;
  ga0 = *(const bf16x8*)(gp);
  ga1 = *(const bf16x8*)(gp + 8);
  ga2 = *(const bf16x8*)(gp + 16);
  gp += stepoff;
  __syncthreads();

  f32x4 C[3][2];
  int cur = 0;
  for (int step = 0; step < T; step += 2) {
    // ---- even step: consume ga*, prefetch gb* (for step+1) before gates ----
    GRU_MFMA_PH();
    gb0 = *(const bf16x8*)(gp);
    gb1 = *(const bf16x8*)(gp + 8);
    gb2 = *(const bf16x8*)(gp + 16);
    gp += stepoff;
    GRU_GATES_PH(dir ? (T - 1 - step) : step, ga0, ga1, ga2);
    asm volatile("s_waitcnt lgkmcnt(0)" ::: "memory");
    __builtin_amdgcn_s_barrier();
    cur ^= 1;
    // ---- odd step: consume gb*, prefetch ga* (for step+2) before gates ----
    GRU_MFMA_PH();
    if (step + 2 < T) {
      ga0 = *(const bf16x8*)(gp);
      ga1 = *(const bf16x8*)(gp + 8);
      ga2 = *(const bf16x8*)(gp + 16);
      gp += stepoff;
    }
    GRU_GATES_PH(dir ? (T - 2 - step) : (step + 1), gb0, gb1, gb2);
    asm volatile("s_waitcnt lgkmcnt(0)" ::: "memory");
    __builtin_amdgcn_s_barrier();
    cur ^= 1;
  }

  #pragma unroll
  for (int jt = 0; jt < 2; ++jt) {
    int j = wave * 32 + jt * 16 + l16;
    #pragma unroll
    for (int r = 0; r < 4; ++r) {
      int sa = sblk + quad * 4 + r;
      if (sa < nsent) {
        float v = pmax[jt][r];
        if (v < -9e29f) v = 0.f;
        pool[(size_t)(sbase + sa) * H2 + dir * Hh + j] = v;
      }
    }
  }
}

// ---------- epilogue ----------
__global__ __launch_bounds__(512) void k_colsumP(const float* __restrict__ ev, float* __restrict__ part) {
  int t = threadIdx.x;
  int r0 = blockIdx.x * 64;
  float s = 0.f;
  for (int r = 0; r < 64; ++r) s += ev[(size_t)(r0 + r) * H2 + t];
  part[(size_t)blockIdx.x * H2 + t] = s;
}
__global__ __launch_bounds__(512) void k_esum(const float* __restrict__ part, float* __restrict__ out) {
  int t = threadIdx.x;
  float s = 0.f;
  for (int b = 0; b < 48; ++b) s += part[(size_t)b * H2 + t];
  out[t] = s;
}

__global__ void k_ves(const float* __restrict__ W, const float* __restrict__ sum, float* __restrict__ ves) {
  int d = blockIdx.x * 64 + threadIdx.x;
  const float* row = W + (size_t)d * H2;
  float s = 0.f;
  for (int f = 0; f < H2; ++f) s += row[f] * sum[f];
  ves[d] = s * (1.f / 3072.f);
}

__global__ void k_sal(const float* __restrict__ W, const float* __restrict__ blog,
                      const float* __restrict__ dv, float* __restrict__ out) {
  int doc = blockIdx.y;
  int i = blockIdx.x * 64 + threadIdx.x;
  const float* row = W + (size_t)i * (2 * H2);
  const float* dvr = dv + (size_t)doc * H2;
  float s = 0.f;
  for (int f = 0; f < H2; ++f) s += row[f] * blog[f];
  for (int f = 0; f < H2; ++f) s += row[H2 + f] * dvr[f];
  out[(size_t)doc * H2 + i] = s;
}

__global__ __launch_bounds__(256) void k_eventprobs(
    const float* __restrict__ evv, const float* __restrict__ ves,
    const float* __restrict__ w_ec, const float* __restrict__ tfs,
    const float* __restrict__ st, const float* __restrict__ c_tf,
    const float* __restrict__ c_sent, const float* __restrict__ c_bias,
    const int* __restrict__ flag, float* __restrict__ probs, void* __restrict__ outp) {
  int lane = threadIdx.x & 63;
  int e = blockIdx.x * 4 + (threadIdx.x >> 6);
  const float* row = evv + (size_t)e * H2;
  float s = 0.f;
  for (int f = lane; f < H2; f += 64) s += row[f] * (w_ec[f] + ves[f]);
  #pragma unroll
  for (int o = 32; o > 0; o >>= 1) s += __shfl_down(s, o, 64);
  if (lane == 0) {
    float p = s + c_tf[0] * tfs[e] + c_bias[0] + c_sent[0] * st[e / 3];
    probs[e] = p;
    if (flag[0]) ((bf16_t*)outp)[S_TOT + e] = (bf16_t)p;
    else         ((float*)outp)[S_TOT + e] = p;
  }
}

__global__ __launch_bounds__(256) void k_sentout(
    const float* __restrict__ sv, const float* __restrict__ u,
    const float* __restrict__ evv, const float* __restrict__ probs,
    const float* __restrict__ wsal, const float* __restrict__ w_sc,
    const float* __restrict__ dpe, const float* __restrict__ spe,
    const float* __restrict__ w_sdp, const float* __restrict__ w_sp,
    const float* __restrict__ b_rel, const float* __restrict__ para,
    const float* __restrict__ sbias, const int* __restrict__ flag,
    void* __restrict__ outp) {
  int lane = threadIdx.x & 63;
  int s = blockIdx.x * 4 + (threadIdx.x >> 6);
  int doc = s >> 5, jj = s & 31;
  const float* svr = sv + (size_t)s * H2;
  const float* ur  = u + (size_t)s * H2;
  const float* wd  = wsal + (size_t)doc * H2;
  float acc = 0.f, e0 = 0.f, e1 = 0.f, e2 = 0.f;
  for (int f = lane; f < H2; f += 64) {
    float svf = svr[f], uf = ur[f];
    acc += svf * (w_sc[f] + wd[f]);
    e0 += uf * evv[(size_t)(s * 3 + 0) * H2 + f];
    e1 += uf * evv[(size_t)(s * 3 + 1) * H2 + f];
    e2 += uf * evv[(size_t)(s * 3 + 2) * H2 + f];
  }
  if (lane < 50) {
    int dpos = (doc * 40) / 32;
    int spos = (jj * 30) / 32;
    acc += dpe[dpos * 50 + lane] * w_sdp[lane] + spe[spos * 50 + lane] * w_sp[lane];
  }
  #pragma unroll
  for (int o = 32; o > 0; o >>= 1) {
    acc += __shfl_down(acc, o, 64);
    e0  += __shfl_down(e0, o, 64);
    e1  += __shfl_down(e1, o, 64);
    e2  += __shfl_down(e2, o, 64);
  }
  if (lane == 0) {
    float br = b_rel[0];
    float rel = (e0 + br) * probs[s * 3 + 0] + (e1 + br) * probs[s * 3 + 1]
              + (e2 + br) * probs[s * 3 + 2];
    float v = acc + para[0] * rel + sbias[0];
    if (flag[0]) ((bf16_t*)outp)[s] = (bf16_t)v;
    else         ((float*)outp)[s] = v;
  }
}

// ---------------- launcher ----------------
extern "C" void kernel_launch(void* const* d_in, const int* in_sizes, int n_in,
                              void* d_out, int out_size, void* d_ws, size_t ws_size,
                              hipStream_t stream) {
  (void)in_sizes; (void)n_in; (void)out_size;
  const int* x      = (const int*)d_in[0];
  const int* events = (const int*)d_in[1];
  const void* embed = d_in[8];

  char* ws = (char*)d_ws;
  size_t off = 0;
  auto alloc = [&](size_t bytes) -> void* {
    void* p = ws + off;
    off += (bytes + 255) & ~(size_t)255;
    return p;
  };

  static const int cidx[NCANON] = {9,10,11,12, 13,14,15,16, 17,18,19,20, 21,22,23,24,
                                   25,26,27,28,29,30,31, 32,33,34,35, 36,37,38,40, 5,7};
  static const int csz[NCANON]  = {2*G3*D_EMB, 2*G3*Hh, 2*G3, 2*G3,
                                   2*G3*H2,    2*G3*Hh, 2*G3, 2*G3,
                                   2*G3*H2,    2*G3*Hh, 2*G3, 2*G3,
                                   2*G3*D_EMB, 2*G3*Hh, 2*G3, 2*G3,
                                   40*50, 30*50, H2, H2*H2, 1, 1, 1,
                                   H2, H2*2*H2, 50, 50,
                                   H2*H2, 1, 1, 1, E_TOT, S_TOT};
  Canon cd;
  int tot = 0;
  for (int i = 0; i < NCANON; ++i) { cd.src[i] = d_in[cidx[i]]; cd.off[i] = tot; tot += csz[i]; }
  cd.off[NCANON] = tot;

  int*   flag  = (int*)alloc(256);
  float* canon = (float*)alloc((size_t)tot * 4);
  float* cptr[NCANON];
  for (int i = 0; i < NCANON; ++i) cptr[i] = canon + cd.off[i];
  float *cw_wih = cptr[0], *cw_whh = cptr[1], *cw_bih = cptr[2], *cw_bhh = cptr[3];
  float *cs_wih = cptr[4], *cs_whh = cptr[5], *cs_bih = cptr[6], *cs_bhh = cptr[7];
  float *cd_wih = cptr[8], *cd_whh = cptr[9], *cd_bih = cptr[10], *cd_bhh = cptr[11];
  float *ce_wih = cptr[12], *ce_whh = cptr[13], *ce_bih = cptr[14], *ce_bhh = cptr[15];
  float *c_dpe = cptr[16], *c_spe = cptr[17], *c_wec = cptr[18], *c_Wes = cptr[19];
  float *c_tf = cptr[20], *c_sent = cptr[21], *c_ebias = cptr[22];
  float *c_wsc = cptr[23], *c_Wss = cptr[24], *c_wsdp = cptr[25], *c_wsp = cptr[26];
  float *c_Wer = cptr[27], *c_brel = cptr[28], *c_para = cptr[29], *c_sbias = cptr[30];
  float *c_tfs = cptr[31], *c_starg = cptr[32];

  bf16_t* packW = (bf16_t*)alloc((size_t)2 * G3 * Hh * 2);
  bf16_t* packE = (bf16_t*)alloc((size_t)2 * G3 * Hh * 2);
  bf16_t* packS = (bf16_t*)alloc((size_t)2 * G3 * Hh * 2);
  bf16_t* packD = (bf16_t*)alloc((size_t)2 * G3 * Hh * 2);
  bf16_t* packGiW = (bf16_t*)alloc((size_t)2 * 12 * 40 * 64 * 8 * 2);
  bf16_t* packGiE = (bf16_t*)alloc((size_t)2 * 12 * 40 * 64 * 8 * 2);
  float*  bcW  = (float*)alloc((size_t)2 * G3 * 4);
  float*  bcE  = (float*)alloc((size_t)2 * G3 * 4);
  float*  bcS  = (float*)alloc((size_t)2 * G3 * 4);
  float*  bcD  = (float*)alloc((size_t)2 * G3 * 4);
  float*  sv   = (float*)alloc((size_t)S_TOT * H2 * 4);
  float*  evv  = (float*)alloc((size_t)E_TOT * H2 * 4);
  float*  dv   = (float*)alloc((size_t)32 * H2 * 4);
  float*  blog = (float*)alloc((size_t)H2 * 4);
  float*  wSt  = (float*)alloc((size_t)2 * H2 * G3 * 4);
  float*  wDt  = (float*)alloc((size_t)2 * H2 * G3 * 4);
  float*  u    = (float*)alloc((size_t)S_TOT * H2 * 4);
  float*  part = (float*)alloc((size_t)48 * H2 * 4);
  float*  esum = (float*)alloc((size_t)H2 * 4);
  float*  ves  = (float*)alloc((size_t)H2 * 4);
  float*  wsal = (float*)alloc((size_t)32 * H2 * 4);
  float*  probs= (float*)alloc((size_t)E_TOT * 4);
  int*    lens = (int*)alloc((size_t)S_TOT * 4);
  bf16_t* sgi  = (bf16_t*)alloc((size_t)2 * S_TOT * G3 * 2);        // packed, 2 sb groups
  bf16_t* dgi  = (bf16_t*)alloc((size_t)2 * 16 * 32 * G3 * 2);      // packed, 1 sb group (16-padded)

  size_t fixed = off;
  size_t avail = (ws_size > fixed) ? (ws_size - fixed) : 0;
  long long rpc = (long long)(avail / ((size_t)G3 * 2 * 2));   // bf16 rows, both dirs
  rpc &= ~511LL;
  if (rpc < 512) rpc = 512;
  if (rpc > 32768) rpc = 32768;
  bf16_t* gib = (bf16_t*)(ws + fixed);

  // ---- prep ----
  k_detect<<<1, 64, 0, stream>>>((const unsigned short*)embed, flag);
  k_canon<<<(tot + 255) / 256, 256, 0, stream>>>(cd, flag, canon);
  k_packB<<<192, 256, 0, stream>>>(cw_whh, packW);
  k_packB<<<192, 256, 0, stream>>>(ce_whh, packE);
  k_packB<<<192, 256, 0, stream>>>(cs_whh, packS);
  k_packB<<<192, 256, 0, stream>>>(cd_whh, packD);
  k_packWih<<<240, 256, 0, stream>>>(cw_wih, packGiW);
  k_packWih<<<240, 256, 0, stream>>>(ce_wih, packGiE);
  k_biasC<<<6, 256, 0, stream>>>(cw_bih, cw_bhh, bcW);
  k_biasC<<<6, 256, 0, stream>>>(ce_bih, ce_bhh, bcE);
  k_biasC<<<6, 256, 0, stream>>>(cs_bih, cs_bhh, bcS);
  k_biasC<<<6, 256, 0, stream>>>(cd_bih, cd_bhh, bcD);
  k_lens<<<4, 256, 0, stream>>>(x, lens);
  k_transpose<<<dim3(24, 16, 2), 256, 0, stream>>>(cs_wih, wSt);
  k_transpose<<<dim3(24, 16, 2), 256, 0, stream>>>(cd_wih, wDt);

  // ---- word BiGRU -> sent_vec ----
  for (long long r0 = 0; r0 < 32768; r0 += rpc) {
    long long rows = 32768 - r0; if (rows > rpc) rows = rpc;
    for (int d = 0; d < 2; ++d)
      k_giB<<<dim3((int)(rows / 128)), 256, 0, stream>>>(
          x, embed, packGiW + (size_t)d * 245760, bcW + d * G3, flag,
          gib + (size_t)d * rows * G3, (int)r0, 5);
    k_gruM<<<dim3((int)(rows / 512), 2), 512, 0, stream>>>(
        gib, (size_t)rows * G3, packW, cw_bhh, lens, sv, 32, (int)(r0 / 32),
        (int)(rows / 32));
  }
  // ---- event BiGRU -> event_vec ----
  for (long long r0 = 0; r0 < 12288; r0 += rpc) {
    long long rows = 12288 - r0; if (rows > rpc) rows = rpc;
    for (int d = 0; d < 2; ++d)
      k_giB<<<dim3((int)(rows / 128)), 256, 0, stream>>>(
          events, embed, packGiE + (size_t)d * 245760, bcE + d * G3, flag,
          gib + (size_t)d * rows * G3, (int)r0, 2);
    k_gruM<<<dim3((int)(rows / 64), 2), 512, 0, stream>>>(
        gib, (size_t)rows * G3, packE, ce_bhh, nullptr, evv, 4, (int)(r0 / 4),
        (int)(rows / 4));
  }
  // ---- sent BiGRU (batch=32 docs, T=32) -> doc_vec ----
  for (int d = 0; d < 2; ++d)
    k_sgemm<<<dim3(16, 12), 256, 0, stream>>>(sv, wSt + (size_t)d * H2 * G3,
                                              bcS + d * G3,
                                              sgi + (size_t)d * S_TOT * G3, 1024, G3, H2, 2);
  k_gruM<<<dim3(2, 2), 512, 0, stream>>>(sgi, (size_t)S_TOT * G3, packS, cs_bhh,
                                         nullptr, dv, 32, 0, 32);
  // ---- doc BiGRU (batch=1, T=32) -> blog_vec ----
  for (int d = 0; d < 2; ++d)
    k_sgemm<<<dim3(1, 12), 256, 0, stream>>>(dv, wDt + (size_t)d * H2 * G3,
                                             bcD + d * G3,
                                             dgi + (size_t)d * 16 * 32 * G3, 32, G3, H2, 2);
  k_gruM<<<dim3(1, 2), 512, 0, stream>>>(dgi, (size_t)16 * 32 * G3, packD, cd_bhh,
                                         nullptr, blog, 32, 0, 1);
  // ---- u = sent_vec @ W_event_rel (f32 out) ----
  k_sgemm<<<dim3(16, 8), 256, 0, stream>>>(sv, c_Wer, nullptr, u, 1024, H2, H2, 0);
  // ---- event_sum, ves, wsal ----
  k_colsumP<<<48, 512, 0, stream>>>(evv, part);
  k_esum<<<1, 512, 0, stream>>>(part, esum);
  k_ves<<<8, 64, 0, stream>>>(c_Wes, esum, ves);
  k_sal<<<dim3(8, 32), 64, 0, stream>>>(c_Wss, blog, dv, wsal);
  // ---- outputs ----
  k_eventprobs<<<768, 256, 0, stream>>>(evv, ves, c_wec, c_tfs, c_starg,
                                        c_tf, c_sent, c_ebias, flag, probs, d_out);
  k_sentout<<<256, 256, 0, stream>>>(sv, u, evv, probs, wsal, c_wsc, c_dpe, c_spe,
                                     c_wsdp, c_wsp, c_brel, c_para, c_sbias, flag, d_out);
}

// Round 9
// 1288.346 us; speedup vs baseline: 1.2012x; 1.2012x over previous
//
#include <hip/hip_runtime.h>
#include <hip/hip_bf16.h>
#include <math.h>

typedef __bf16 bf16_t;
typedef __bf16 bf16x8 __attribute__((ext_vector_type(8)));
typedef __bf16 bf16x4 __attribute__((ext_vector_type(4)));
typedef float  f32x4  __attribute__((ext_vector_type(4)));

#define S_TOT 1024
#define T_W   32
#define D_EMB 300
#define KP    320
#define G3    768
#define Hh    256
#define H2    512
#define E_TOT 3072
#define NCANON 33

// fast gate math: ~5 VALU ops each (v_exp_f32 + v_rcp_f32); error ~2ulp f32.
__device__ __forceinline__ float fsigm(float x) {
  float e = __builtin_amdgcn_exp2f(x * -1.4426950408889634f);
  return __builtin_amdgcn_rcpf(1.f + e);
}
__device__ __forceinline__ float ftanh_(float x) {
  float e = __builtin_amdgcn_exp2f(x * 2.8853900817779268f);
  return 1.f - 2.f * __builtin_amdgcn_rcpf(1.f + e);
}

// ---------- dtype detector: flag=1 if float tensors are bf16, 0 if f32 ----------
__global__ void k_detect(const unsigned short* __restrict__ w, int* __restrict__ flag) {
  int lane = threadIdx.x;
  int sane = 0;
  for (int i = lane; i < 256; i += 64) {
    unsigned short v = w[2 * i];
    int ex = (v >> 7) & 0xFF;
    sane += (ex >= 96 && ex <= 134) ? 1 : 0;
  }
  #pragma unroll
  for (int o = 32; o > 0; o >>= 1) sane += __shfl_down(sane, o, 64);
  if (lane == 0) flag[0] = (sane >= 128) ? 1 : 0;
}

// ---------- canonicalize all float tensors to f32 ----------
struct Canon {
  const void* src[NCANON];
  int off[NCANON + 1];
};
__global__ void k_canon(Canon c, const int* __restrict__ flag, float* __restrict__ dst) {
  int i = blockIdx.x * 256 + threadIdx.x;
  if (i >= c.off[NCANON]) return;
  int seg = 0;
  while (c.off[seg + 1] <= i) ++seg;
  int j = i - c.off[seg];
  dst[i] = flag[0] ? (float)((const bf16_t*)c.src[seg])[j]
                   : ((const float*)c.src[seg])[j];
}

__global__ void k_lens(const int* __restrict__ x, int* __restrict__ lens) {
  int s = blockIdx.x * blockDim.x + threadIdx.x;
  if (s >= S_TOT) return;
  int c = 0;
  for (int t = 0; t < T_W; ++t) c += (x[s * T_W + t] != 0) ? 1 : 0;
  lens[s] = c;
}

// wih [2][768][512] f32 -> [2][512][768] f32
__global__ void k_transpose(const float* __restrict__ w, float* __restrict__ out) {
  __shared__ float tile[32][33];
  int d  = blockIdx.z;
  int n0 = blockIdx.x * 32, k0 = blockIdx.y * 32;
  int tx = threadIdx.x & 31, ty = threadIdx.x >> 5;
  for (int i = ty; i < 32; i += 8)
    tile[i][tx] = w[((size_t)d * G3 + n0 + i) * H2 + k0 + tx];
  __syncthreads();
  for (int i = ty; i < 32; i += 8)
    out[((size_t)d * H2 + k0 + i) * G3 + n0 + tx] = tile[tx][i];
}

// ---------- pack whh [2][768][256] f32 -> B-fragment-major bf16 ----------
// layout: [dir][wave(8)][sl(6)][k0(8)][lane(64)][8 bf16], sl = g*2+jt
__global__ void k_packB(const float* __restrict__ whh, bf16_t* __restrict__ packed) {
  int id = blockIdx.x * 256 + threadIdx.x;     // 49152 groups of 8 elems
  if (id >= 49152) return;
  int lane = id & 63;
  int k0 = (id >> 6) & 7;
  int t9 = id >> 9;
  int sl = t9 % 6;
  int wb = t9 / 6;
  int wv = wb & 7;
  int dir = wb >> 3;
  int g = sl >> 1, jt = sl & 1;
  int l16 = lane & 15, quad = lane >> 4;
  int n = g * Hh + wv * 32 + jt * 16 + l16;
  const float* src = whh + ((size_t)dir * G3 + n) * Hh + k0 * 32 + quad * 8;
  bf16_t* dst = packed + (size_t)id * 8;
  #pragma unroll
  for (int i = 0; i < 8; ++i) dst[i] = (bf16_t)src[i];
}

// ---------- pack wih [2][768][300] f32 -> MFMA-fragment-major bf16, K padded 320 ----------
// layout: [dir][n0(12)][slot s=j*10+k0 (40)][lane(64)][8 bf16]
__global__ void k_packWih(const float* __restrict__ wih, bf16_t* __restrict__ out) {
  int id = blockIdx.x * 256 + threadIdx.x;     // 61440 frags of 8
  if (id >= 61440) return;
  int lane = id & 63;
  int su = id >> 6;
  int s  = su % 40;
  int n0 = (su / 40) % 12;
  int dir = su / 480;
  int j = s / 10, k0 = s % 10;
  int l16 = lane & 15, quad = lane >> 4;
  int n = n0 * 64 + j * 16 + l16;
  int c = k0 * 32 + quad * 8;
  const float* src = wih + ((size_t)dir * G3 + n) * D_EMB + c;
  bf16_t* dst = out + (size_t)id * 8;
  #pragma unroll
  for (int i = 0; i < 8; ++i)
    dst[i] = (c + i < D_EMB) ? (bf16_t)src[i] : (bf16_t)0.f;
}

// ---------- combined bias: biasC[dir][c] = bih[dir][c] + (c<512 ? bhh[dir][c] : 0) ----------
__global__ void k_biasC(const float* __restrict__ bih, const float* __restrict__ bhh,
                        float* __restrict__ out) {
  int i = blockIdx.x * 256 + threadIdx.x;
  if (i >= 2 * G3) return;
  int c = i % G3;
  out[i] = bih[i] + (c < 2 * Hh ? bhh[i] : 0.f);
}

// ---------- fused gather + input projection (round-2 flat-gi version) ----------
__global__ __launch_bounds__(256, 1) void k_giB(
    const int* __restrict__ toks, const void* __restrict__ embed,
    const bf16_t* __restrict__ wpk,   // this dir: [12][40][64][8]
    const float* __restrict__ bih,    // this dir's combined bias [768]
    const int* __restrict__ flag, bf16_t* __restrict__ gi, int mbase) {
  __shared__ __align__(16) bf16_t Bt[2][20480];   // 2 x 40KB
  int tid = threadIdx.x;
  int wave = tid >> 6, lane = tid & 63;
  int l16 = lane & 15, quad = lane >> 4;
  int m0 = blockIdx.x * 128;
  int isb = flag[0];

  // ---- A fragments from global (once): ah/al[mi][k0] ----
  bf16x8 ah[2][10], al[2][10];
  #pragma unroll
  for (int mi = 0; mi < 2; ++mi) {
    int tok = toks[mbase + m0 + wave * 32 + mi * 16 + l16];
    if (isb) {
      const bf16_t* er = (const bf16_t*)embed + (size_t)tok * D_EMB;
      #pragma unroll
      for (int k0 = 0; k0 < 10; ++k0) {
        int c = k0 * 32 + quad * 8;
        bf16x8 v = {};
        if (c + 8 <= D_EMB) {
          bf16x4 t0 = *(const bf16x4*)(er + c);
          bf16x4 t1 = *(const bf16x4*)(er + c + 4);
          v[0]=t0[0]; v[1]=t0[1]; v[2]=t0[2]; v[3]=t0[3];
          v[4]=t1[0]; v[5]=t1[1]; v[6]=t1[2]; v[7]=t1[3];
        } else if (c < D_EMB) {
          bf16x4 t0 = *(const bf16x4*)(er + c);
          v[0]=t0[0]; v[1]=t0[1]; v[2]=t0[2]; v[3]=t0[3];
        }
        ah[mi][k0] = v;
        al[mi][k0] = (bf16x8){};
      }
    } else {
      const float* er = (const float*)embed + (size_t)tok * D_EMB;
      #pragma unroll
      for (int k0 = 0; k0 < 10; ++k0) {
        int c = k0 * 32 + quad * 8;
        float v[8];
        #pragma unroll
        for (int i = 0; i < 8; ++i) v[i] = 0.f;
        if (c + 4 <= D_EMB) { float4 t = *(const float4*)(er + c);
                              v[0]=t.x; v[1]=t.y; v[2]=t.z; v[3]=t.w; }
        if (c + 8 <= D_EMB) { float4 t = *(const float4*)(er + c + 4);
                              v[4]=t.x; v[5]=t.y; v[6]=t.z; v[7]=t.w; }
        bf16x8 h, l;
        #pragma unroll
        for (int i = 0; i < 8; ++i) {
          bf16_t hv = (bf16_t)v[i];
          h[i] = hv; l[i] = (bf16_t)(v[i] - (float)hv);
        }
        ah[mi][k0] = h; al[mi][k0] = l;
      }
    }
  }

  bf16x8 stg[10];
  {
    const bf16_t* base = wpk + (size_t)(wave * 10) * 512 + lane * 8;
    #pragma unroll
    for (int i = 0; i < 10; ++i) stg[i] = *(const bf16x8*)(base + i * 512);
    bf16_t* dst = &Bt[0][(wave * 10) * 512 + lane * 8];
    #pragma unroll
    for (int i = 0; i < 10; ++i) *(bf16x8*)(dst + i * 512) = stg[i];
  }
  __syncthreads();

  for (int n0 = 0; n0 < 12; ++n0) {
    int cur = n0 & 1;
    if (n0 + 1 < 12) {
      const bf16_t* base = wpk + (size_t)(n0 + 1) * 20480
                         + (size_t)(wave * 10) * 512 + lane * 8;
      #pragma unroll
      for (int i = 0; i < 10; ++i) stg[i] = *(const bf16x8*)(base + i * 512);
    }
    f32x4 acc[2][4];
    #pragma unroll
    for (int mi = 0; mi < 2; ++mi)
      #pragma unroll
      for (int j = 0; j < 4; ++j) acc[mi][j] = (f32x4){0.f, 0.f, 0.f, 0.f};
    const bf16_t* Bc = Bt[cur];
    #pragma unroll
    for (int k0 = 0; k0 < 10; ++k0) {
      bf16x8 b[4];
      #pragma unroll
      for (int j = 0; j < 4; ++j)
        b[j] = *(const bf16x8*)&Bc[((j * 10 + k0) * 64 + lane) * 8];
      if (isb) {
        #pragma unroll
        for (int mi = 0; mi < 2; ++mi)
          #pragma unroll
          for (int j = 0; j < 4; ++j)
            acc[mi][j] = __builtin_amdgcn_mfma_f32_16x16x32_bf16(ah[mi][k0], b[j], acc[mi][j], 0, 0, 0);
      } else {
        #pragma unroll
        for (int mi = 0; mi < 2; ++mi)
          #pragma unroll
          for (int j = 0; j < 4; ++j)
            acc[mi][j] = __builtin_amdgcn_mfma_f32_16x16x32_bf16(al[mi][k0], b[j], acc[mi][j], 0, 0, 0);
        #pragma unroll
        for (int mi = 0; mi < 2; ++mi)
          #pragma unroll
          for (int j = 0; j < 4; ++j)
            acc[mi][j] = __builtin_amdgcn_mfma_f32_16x16x32_bf16(ah[mi][k0], b[j], acc[mi][j], 0, 0, 0);
      }
    }
    #pragma unroll
    for (int mi = 0; mi < 2; ++mi) {
      int row0 = m0 + wave * 32 + mi * 16 + quad * 4;
      #pragma unroll
      for (int j = 0; j < 4; ++j) {
        int col = n0 * 64 + j * 16 + l16;
        float bb = bih[col];
        #pragma unroll
        for (int rr = 0; rr < 4; ++rr)
          gi[(size_t)(row0 + rr) * G3 + col] = (bf16_t)(acc[mi][j][rr] + bb);
      }
    }
    if (n0 + 1 < 12) {
      bf16_t* dst = &Bt[cur ^ 1][(wave * 10) * 512 + lane * 8];
      #pragma unroll
      for (int i = 0; i < 10; ++i) *(bf16x8*)(dst + i * 512) = stg[i];
      __syncthreads();
    }
  }
}

// ---------- f32 SGEMM: C[M][N] = A[M][K] @ B[K][N] (+bias), out f32 or bf16 ----------
__global__ __launch_bounds__(256) void k_sgemm(
    const float* __restrict__ A, const float* __restrict__ B,
    const float* __restrict__ bias, void* __restrict__ C,
    int M, int N, int K, int obf) {
  __shared__ float As[32][65];
  __shared__ float Bs[32][65];
  int bm = blockIdx.x * 64, bn = blockIdx.y * 64;
  int tid = threadIdx.x;
  int tx = tid & 15, ty = tid >> 4;
  float acc[4][4] = {};
  for (int k0 = 0; k0 < K; k0 += 32) {
    for (int i = tid; i < 64 * 32; i += 256) {
      int m = i >> 5, k = i & 31;
      As[k][m] = (bm + m < M) ? A[(size_t)(bm + m) * K + k0 + k] : 0.f;
    }
    for (int i = tid; i < 32 * 64; i += 256) {
      int k = i >> 6, n = i & 63;
      Bs[k][n] = B[(size_t)(k0 + k) * N + bn + n];
    }
    __syncthreads();
    #pragma unroll 8
    for (int k = 0; k < 32; ++k) {
      float a[4], b[4];
      #pragma unroll
      for (int i = 0; i < 4; ++i) a[i] = As[k][ty + i * 16];
      #pragma unroll
      for (int j = 0; j < 4; ++j) b[j] = Bs[k][tx + j * 16];
      #pragma unroll
      for (int i = 0; i < 4; ++i)
        #pragma unroll
        for (int j = 0; j < 4; ++j) acc[i][j] += a[i] * b[j];
    }
    __syncthreads();
  }
  for (int i = 0; i < 4; ++i) {
    int m = bm + ty + i * 16;
    if (m >= M) continue;
    for (int j = 0; j < 4; ++j) {
      int n = bn + tx + j * 16;
      float v = acc[i][j] + (bias ? bias[n] : 0.f);
      if (obf) ((bf16_t*)C)[(size_t)m * N + n] = (bf16_t)v;
      else     ((float*)C)[(size_t)m * N + n] = v;
    }
  }
}

// ---------- batched MFMA GRU v7 = round-2 v2 + spb split + hA write swizzle ----------
// r7 finding: gruM is MLP-bound (384 gi lines/CU/step, ~64 outstanding misses,
// 450-900cyc latency -> ~4-5K cyc/step wall), and 128 blocks leave half the
// CUs' miss-handling idle. Fix: spb (sents/block) param. Word uses spb=8:
// grid doubles to 256 blocks (all CUs), per-block gi lines/step halve.
// Inactive quads (quad*4 >= spb) mirror quad-0 rows on loads (same cache
// lines, no divergence) and skip hA/pool writes; A-tile rows spb..15 stay
// zero (both buffers zero-init) so MFMA garbage is confined to unused C rows.
// hA XOR write swizzle (slot ^= writer quad; read slot = quad ^ (l16>>2)):
// 4-way -> 2-way write conflict, read stays contiguous b128 (verified
// consistent: stored q2 = jt*2+(l16w>>3), writer quad = m>>2, reader m = l16).
__global__ __launch_bounds__(512)
__attribute__((amdgpu_waves_per_eu(2, 2)))
void k_gruM(
    const bf16_t* __restrict__ gi, size_t gi_dstride,
    const bf16_t* __restrict__ whhP, const float* __restrict__ bhh,
    const int* __restrict__ lens, float* __restrict__ pool,
    int T, int sbase, int nsent, int spb) {
  int dir = blockIdx.y;
  int tid = threadIdx.x;
  int wave = tid >> 6, lane = tid & 63;
  int l16 = lane & 15, quad = lane >> 4;
  int sblk = blockIdx.x * spb;
  bool act = (quad * 4) < spb;
  const bf16_t* giD  = gi + (size_t)dir * gi_dstride;
  const float*  bhhD = bhh + (size_t)dir * G3;

  // [buf][k0][m(16)][slot(4)][ii(8)] bf16; slot XOR-swizzled by writer quad
  __shared__ __align__(16) bf16_t hA[2][8][16][4][8];

  // whh fragments, register-resident
  bf16x8 Bf[48];
  {
    const bf16_t* Bb = whhP + (size_t)dir * G3 * Hh + (size_t)wave * 48 * 512 + lane * 8;
    #pragma unroll
    for (int s = 0; s < 48; ++s) Bf[s] = *(const bf16x8*)(Bb + s * 512);
  }
  float bhn[2];
  #pragma unroll
  for (int jt = 0; jt < 2; ++jt)
    bhn[jt] = bhhD[2 * Hh + wave * 32 + jt * 16 + l16];
  int Lm[4];
  #pragma unroll
  for (int r = 0; r < 4; ++r) {
    int sa = sblk + quad * 4 + r;
    Lm[r] = (lens && act && sa < nsent) ? lens[sbase + sa] : T;
  }
  float pmax[2][4], hreg[2][4];
  #pragma unroll
  for (int jt = 0; jt < 2; ++jt)
    #pragma unroll
    for (int r = 0; r < 4; ++r) { pmax[jt][r] = -1e30f; hreg[jt][r] = 0.f; }

  // incremental gi row pointers; inactive quads mirror quad 0 (same lines)
  int t0 = dir ? (T - 1) : 0;
  long long stepoff = dir ? -(long long)G3 : (long long)G3;
  const bf16_t* rp[4];
  #pragma unroll
  for (int r = 0; r < 4; ++r) {
    int sa = sblk + (act ? quad * 4 : 0) + r;
    if (sa >= nsent) sa = nsent - 1;
    rp[r] = giD + ((size_t)sa * T + t0) * (size_t)G3;
  }

  // zero BOTH hA buffers (rows spb..15 are never written by gates)
  {
    bf16_t* hz = &hA[0][0][0][0][0];
    for (int i = tid; i < 2 * 8 * 16 * 4 * 8; i += 512) hz[i] = (bf16_t)0.f;
  }

  // prefetch gv for step 0
  bf16_t gv[3][2][4];
  #pragma unroll
  for (int jt = 0; jt < 2; ++jt) {
    int j = wave * 32 + jt * 16 + l16;
    #pragma unroll
    for (int r = 0; r < 4; ++r) {
      gv[0][jt][r] = rp[r][j];
      gv[1][jt][r] = rp[r][Hh + j];
      gv[2][jt][r] = rp[r][2 * Hh + j];
    }
  }
  __syncthreads();

  int cur = 0;
  for (int step = 0; step < T; ++step) {
    int t = dir ? (T - 1 - step) : step;
    // MFMA phase: gh = h @ whh^T (B register-resident, A from LDS buf[cur])
    f32x4 C[3][2];
    #pragma unroll
    for (int g = 0; g < 3; ++g)
      #pragma unroll
      for (int jt = 0; jt < 2; ++jt) C[g][jt] = (f32x4){0.f, 0.f, 0.f, 0.f};
    #pragma unroll
    for (int k0 = 0; k0 < 8; ++k0) {
      bf16x8 a8 = *(const bf16x8*)&hA[cur][k0][l16][quad ^ (l16 >> 2)][0];
      #pragma unroll
      for (int g = 0; g < 3; ++g)
        #pragma unroll
        for (int jt = 0; jt < 2; ++jt)
          C[g][jt] = __builtin_amdgcn_mfma_f32_16x16x32_bf16(a8, Bf[(g * 2 + jt) * 8 + k0], C[g][jt], 0, 0, 0);
    }
    // gate phase: h state in hreg; writes h(t) to hA buf[cur^1] (active quads)
    #pragma unroll
    for (int jt = 0; jt < 2; ++jt) {
      int q2 = jt * 2 + (l16 >> 3);
      int ii = l16 & 7;
      #pragma unroll
      for (int r = 0; r < 4; ++r) {
        int m = quad * 4 + r;
        float hp = hreg[jt][r];
        float rr = fsigm((float)gv[0][jt][r] + C[0][jt][r]);
        float zz = fsigm((float)gv[1][jt][r] + C[1][jt][r]);
        float nn = ftanh_((float)gv[2][jt][r] + rr * (C[2][jt][r] + bhn[jt]));
        float hnew = nn + zz * (hp - nn);
        hreg[jt][r] = hnew;
        if (act) hA[cur ^ 1][wave][m][q2 ^ quad][ii] = (bf16_t)hnew;
        if (t < Lm[r]) pmax[jt][r] = fmaxf(pmax[jt][r], hnew);
      }
    }
    // advance pointers; issue next step's gv loads BEFORE the lgkm-only
    // barrier so they stay in flight across it.
    #pragma unroll
    for (int r = 0; r < 4; ++r) rp[r] += stepoff;
    if (step + 1 < T) {
      #pragma unroll
      for (int jt = 0; jt < 2; ++jt) {
        int j = wave * 32 + jt * 16 + l16;
        #pragma unroll
        for (int r = 0; r < 4; ++r) {
          gv[0][jt][r] = rp[r][j];
          gv[1][jt][r] = rp[r][Hh + j];
          gv[2][jt][r] = rp[r][2 * Hh + j];
        }
      }
    }
    asm volatile("s_waitcnt lgkmcnt(0)" ::: "memory");
    __builtin_amdgcn_s_barrier();
    cur ^= 1;
  }
  #pragma unroll
  for (int jt = 0; jt < 2; ++jt) {
    int j = wave * 32 + jt * 16 + l16;
    #pragma unroll
    for (int r = 0; r < 4; ++r) {
      int sa = sblk + quad * 4 + r;
      if (act && sa < nsent) {
        float v = pmax[jt][r];
        if (v < -9e29f) v = 0.f;
        pool[(size_t)(sbase + sa) * H2 + dir * Hh + j] = v;
      }
    }
  }
}

// ---------- epilogue ----------
__global__ __launch_bounds__(512) void k_colsumP(const float* __restrict__ ev, float* __restrict__ part) {
  int t = threadIdx.x;
  int r0 = blockIdx.x * 64;
  float s = 0.f;
  for (int r = 0; r < 64; ++r) s += ev[(size_t)(r0 + r) * H2 + t];
  part[(size_t)blockIdx.x * H2 + t] = s;
}
__global__ __launch_bounds__(512) void k_esum(const float* __restrict__ part, float* __restrict__ out) {
  int t = threadIdx.x;
  float s = 0.f;
  for (int b = 0; b < 48; ++b) s += part[(size_t)b * H2 + t];
  out[t] = s;
}

__global__ void k_ves(const float* __restrict__ W, const float* __restrict__ sum, float* __restrict__ ves) {
  int d = blockIdx.x * 64 + threadIdx.x;
  const float* row = W + (size_t)d * H2;
  float s = 0.f;
  for (int f = 0; f < H2; ++f) s += row[f] * sum[f];
  ves[d] = s * (1.f / 3072.f);
}

__global__ void k_sal(const float* __restrict__ W, const float* __restrict__ blog,
                      const float* __restrict__ dv, float* __restrict__ out) {
  int doc = blockIdx.y;
  int i = blockIdx.x * 64 + threadIdx.x;
  const float* row = W + (size_t)i * (2 * H2);
  const float* dvr = dv + (size_t)doc * H2;
  float s = 0.f;
  for (int f = 0; f < H2; ++f) s += row[f] * blog[f];
  for (int f = 0; f < H2; ++f) s += row[H2 + f] * dvr[f];
  out[(size_t)doc * H2 + i] = s;
}

__global__ __launch_bounds__(256) void k_eventprobs(
    const float* __restrict__ evv, const float* __restrict__ ves,
    const float* __restrict__ w_ec, const float* __restrict__ tfs,
    const float* __restrict__ st, const float* __restrict__ c_tf,
    const float* __restrict__ c_sent, const float* __restrict__ c_bias,
    const int* __restrict__ flag, float* __restrict__ probs, void* __restrict__ outp) {
  int lane = threadIdx.x & 63;
  int e = blockIdx.x * 4 + (threadIdx.x >> 6);
  const float* row = evv + (size_t)e * H2;
  float s = 0.f;
  for (int f = lane; f < H2; f += 64) s += row[f] * (w_ec[f] + ves[f]);
  #pragma unroll
  for (int o = 32; o > 0; o >>= 1) s += __shfl_down(s, o, 64);
  if (lane == 0) {
    float p = s + c_tf[0] * tfs[e] + c_bias[0] + c_sent[0] * st[e / 3];
    probs[e] = p;
    if (flag[0]) ((bf16_t*)outp)[S_TOT + e] = (bf16_t)p;
    else         ((float*)outp)[S_TOT + e] = p;
  }
}

__global__ __launch_bounds__(256) void k_sentout(
    const float* __restrict__ sv, const float* __restrict__ u,
    const float* __restrict__ evv, const float* __restrict__ probs,
    const float* __restrict__ wsal, const float* __restrict__ w_sc,
    const float* __restrict__ dpe, const float* __restrict__ spe,
    const float* __restrict__ w_sdp, const float* __restrict__ w_sp,
    const float* __restrict__ b_rel, const float* __restrict__ para,
    const float* __restrict__ sbias, const int* __restrict__ flag,
    void* __restrict__ outp) {
  int lane = threadIdx.x & 63;
  int s = blockIdx.x * 4 + (threadIdx.x >> 6);
  int doc = s >> 5, jj = s & 31;
  const float* svr = sv + (size_t)s * H2;
  const float* ur  = u + (size_t)s * H2;
  const float* wd  = wsal + (size_t)doc * H2;
  float acc = 0.f, e0 = 0.f, e1 = 0.f, e2 = 0.f;
  for (int f = lane; f < H2; f += 64) {
    float svf = svr[f], uf = ur[f];
    acc += svf * (w_sc[f] + wd[f]);
    e0 += uf * evv[(size_t)(s * 3 + 0) * H2 + f];
    e1 += uf * evv[(size_t)(s * 3 + 1) * H2 + f];
    e2 += uf * evv[(size_t)(s * 3 + 2) * H2 + f];
  }
  if (lane < 50) {
    int dpos = (doc * 40) / 32;
    int spos = (jj * 30) / 32;
    acc += dpe[dpos * 50 + lane] * w_sdp[lane] + spe[spos * 50 + lane] * w_sp[lane];
  }
  #pragma unroll
  for (int o = 32; o > 0; o >>= 1) {
    acc += __shfl_down(acc, o, 64);
    e0  += __shfl_down(e0, o, 64);
    e1  += __shfl_down(e1, o, 64);
    e2  += __shfl_down(e2, o, 64);
  }
  if (lane == 0) {
    float br = b_rel[0];
    float rel = (e0 + br) * probs[s * 3 + 0] + (e1 + br) * probs[s * 3 + 1]
              + (e2 + br) * probs[s * 3 + 2];
    float v = acc + para[0] * rel + sbias[0];
    if (flag[0]) ((bf16_t*)outp)[s] = (bf16_t)v;
    else         ((float*)outp)[s] = v;
  }
}

// ---------------- launcher ----------------
extern "C" void kernel_launch(void* const* d_in, const int* in_sizes, int n_in,
                              void* d_out, int out_size, void* d_ws, size_t ws_size,
                              hipStream_t stream) {
  (void)in_sizes; (void)n_in; (void)out_size;
  const int* x      = (const int*)d_in[0];
  const int* events = (const int*)d_in[1];
  const void* embed = d_in[8];

  char* ws = (char*)d_ws;
  size_t off = 0;
  auto alloc = [&](size_t bytes) -> void* {
    void* p = ws + off;
    off += (bytes + 255) & ~(size_t)255;
    return p;
  };

  static const int cidx[NCANON] = {9,10,11,12, 13,14,15,16, 17,18,19,20, 21,22,23,24,
                                   25,26,27,28,29,30,31, 32,33,34,35, 36,37,38,40, 5,7};
  static const int csz[NCANON]  = {2*G3*D_EMB, 2*G3*Hh, 2*G3, 2*G3,
                                   2*G3*H2,    2*G3*Hh, 2*G3, 2*G3,
                                   2*G3*H2,    2*G3*Hh, 2*G3, 2*G3,
                                   2*G3*D_EMB, 2*G3*Hh, 2*G3, 2*G3,
                                   40*50, 30*50, H2, H2*H2, 1, 1, 1,
                                   H2, H2*2*H2, 50, 50,
                                   H2*H2, 1, 1, 1, E_TOT, S_TOT};
  Canon cd;
  int tot = 0;
  for (int i = 0; i < NCANON; ++i) { cd.src[i] = d_in[cidx[i]]; cd.off[i] = tot; tot += csz[i]; }
  cd.off[NCANON] = tot;

  int*   flag  = (int*)alloc(256);
  float* canon = (float*)alloc((size_t)tot * 4);
  float* cptr[NCANON];
  for (int i = 0; i < NCANON; ++i) cptr[i] = canon + cd.off[i];
  float *cw_wih = cptr[0], *cw_whh = cptr[1], *cw_bih = cptr[2], *cw_bhh = cptr[3];
  float *cs_wih = cptr[4], *cs_whh = cptr[5], *cs_bih = cptr[6], *cs_bhh = cptr[7];
  float *cd_wih = cptr[8], *cd_whh = cptr[9], *cd_bih = cptr[10], *cd_bhh = cptr[11];
  float *ce_wih = cptr[12], *ce_whh = cptr[13], *ce_bih = cptr[14], *ce_bhh = cptr[15];
  float *c_dpe = cptr[16], *c_spe = cptr[17], *c_wec = cptr[18], *c_Wes = cptr[19];
  float *c_tf = cptr[20], *c_sent = cptr[21], *c_ebias = cptr[22];
  float *c_wsc = cptr[23], *c_Wss = cptr[24], *c_wsdp = cptr[25], *c_wsp = cptr[26];
  float *c_Wer = cptr[27], *c_brel = cptr[28], *c_para = cptr[29], *c_sbias = cptr[30];
  float *c_tfs = cptr[31], *c_starg = cptr[32];

  bf16_t* packW = (bf16_t*)alloc((size_t)2 * G3 * Hh * 2);
  bf16_t* packE = (bf16_t*)alloc((size_t)2 * G3 * Hh * 2);
  bf16_t* packS = (bf16_t*)alloc((size_t)2 * G3 * Hh * 2);
  bf16_t* packD = (bf16_t*)alloc((size_t)2 * G3 * Hh * 2);
  bf16_t* packGiW = (bf16_t*)alloc((size_t)2 * 12 * 40 * 64 * 8 * 2);
  bf16_t* packGiE = (bf16_t*)alloc((size_t)2 * 12 * 40 * 64 * 8 * 2);
  float*  bcW  = (float*)alloc((size_t)2 * G3 * 4);
  float*  bcE  = (float*)alloc((size_t)2 * G3 * 4);
  float*  bcS  = (float*)alloc((size_t)2 * G3 * 4);
  float*  bcD  = (float*)alloc((size_t)2 * G3 * 4);
  float*  sv   = (float*)alloc((size_t)S_TOT * H2 * 4);
  float*  evv  = (float*)alloc((size_t)E_TOT * H2 * 4);
  float*  dv   = (float*)alloc((size_t)32 * H2 * 4);
  float*  blog = (float*)alloc((size_t)H2 * 4);
  float*  wSt  = (float*)alloc((size_t)2 * H2 * G3 * 4);
  float*  wDt  = (float*)alloc((size_t)2 * H2 * G3 * 4);
  float*  u    = (float*)alloc((size_t)S_TOT * H2 * 4);
  float*  part = (float*)alloc((size_t)48 * H2 * 4);
  float*  esum = (float*)alloc((size_t)H2 * 4);
  float*  ves  = (float*)alloc((size_t)H2 * 4);
  float*  wsal = (float*)alloc((size_t)32 * H2 * 4);
  float*  probs= (float*)alloc((size_t)E_TOT * 4);
  int*    lens = (int*)alloc((size_t)S_TOT * 4);
  bf16_t* sgi  = (bf16_t*)alloc((size_t)2 * S_TOT * G3 * 2);
  bf16_t* dgi  = (bf16_t*)alloc((size_t)2 * 32 * G3 * 2);

  size_t fixed = off;
  size_t avail = (ws_size > fixed) ? (ws_size - fixed) : 0;
  long long rpc = (long long)(avail / ((size_t)G3 * 2 * 2));   // bf16 rows, both dirs
  rpc &= ~511LL;
  if (rpc < 512) rpc = 512;
  if (rpc > 32768) rpc = 32768;
  bf16_t* gib = (bf16_t*)(ws + fixed);

  // ---- prep ----
  k_detect<<<1, 64, 0, stream>>>((const unsigned short*)embed, flag);
  k_canon<<<(tot + 255) / 256, 256, 0, stream>>>(cd, flag, canon);
  k_packB<<<192, 256, 0, stream>>>(cw_whh, packW);
  k_packB<<<192, 256, 0, stream>>>(ce_whh, packE);
  k_packB<<<192, 256, 0, stream>>>(cs_whh, packS);
  k_packB<<<192, 256, 0, stream>>>(cd_whh, packD);
  k_packWih<<<240, 256, 0, stream>>>(cw_wih, packGiW);
  k_packWih<<<240, 256, 0, stream>>>(ce_wih, packGiE);
  k_biasC<<<6, 256, 0, stream>>>(cw_bih, cw_bhh, bcW);
  k_biasC<<<6, 256, 0, stream>>>(ce_bih, ce_bhh, bcE);
  k_biasC<<<6, 256, 0, stream>>>(cs_bih, cs_bhh, bcS);
  k_biasC<<<6, 256, 0, stream>>>(cd_bih, cd_bhh, bcD);
  k_lens<<<4, 256, 0, stream>>>(x, lens);
  k_transpose<<<dim3(24, 16, 2), 256, 0, stream>>>(cs_wih, wSt);
  k_transpose<<<dim3(24, 16, 2), 256, 0, stream>>>(cd_wih, wDt);

  // ---- word BiGRU -> sent_vec (spb=8: 256 blocks, half gi lines/block/step) ----
  for (long long r0 = 0; r0 < 32768; r0 += rpc) {
    long long rows = 32768 - r0; if (rows > rpc) rows = rpc;
    for (int d = 0; d < 2; ++d)
      k_giB<<<dim3((int)(rows / 128)), 256, 0, stream>>>(
          x, embed, packGiW + (size_t)d * 245760, bcW + d * G3, flag,
          gib + (size_t)d * rows * G3, (int)r0);
    k_gruM<<<dim3((int)(rows / 256), 2), 512, 0, stream>>>(
        gib, (size_t)rows * G3, packW, cw_bhh, lens, sv, 32, (int)(r0 / 32),
        (int)(rows / 32), 8);
  }
  // ---- event BiGRU -> event_vec (spb=16; blocks already plentiful) ----
  for (long long r0 = 0; r0 < 12288; r0 += rpc) {
    long long rows = 12288 - r0; if (rows > rpc) rows = rpc;
    for (int d = 0; d < 2; ++d)
      k_giB<<<dim3((int)(rows / 128)), 256, 0, stream>>>(
          events, embed, packGiE + (size_t)d * 245760, bcE + d * G3, flag,
          gib + (size_t)d * rows * G3, (int)r0);
    k_gruM<<<dim3((int)(rows / 64), 2), 512, 0, stream>>>(
        gib, (size_t)rows * G3, packE, ce_bhh, nullptr, evv, 4, (int)(r0 / 4),
        (int)(rows / 4), 16);
  }
  // ---- sent BiGRU (batch=32 docs, T=32) -> doc_vec ----
  for (int d = 0; d < 2; ++d)
    k_sgemm<<<dim3(16, 12), 256, 0, stream>>>(sv, wSt + (size_t)d * H2 * G3,
                                              bcS + d * G3,
                                              sgi + (size_t)d * S_TOT * G3, 1024, G3, H2, 1);
  k_gruM<<<dim3(2, 2), 512, 0, stream>>>(sgi, (size_t)S_TOT * G3, packS, cs_bhh,
                                         nullptr, dv, 32, 0, 32, 16);
  // ---- doc BiGRU (batch=1, T=32) -> blog_vec ----
  for (int d = 0; d < 2; ++d)
    k_sgemm<<<dim3(1, 12), 256, 0, stream>>>(dv, wDt + (size_t)d * H2 * G3,
                                             bcD + d * G3,
                                             dgi + (size_t)d * 32 * G3, 32, G3, H2, 1);
  k_gruM<<<dim3(1, 2), 512, 0, stream>>>(dgi, (size_t)32 * G3, packD, cd_bhh,
                                         nullptr, blog, 32, 0, 1, 16);
  // ---- u = sent_vec @ W_event_rel (f32 out) ----
  k_sgemm<<<dim3(16, 8), 256, 0, stream>>>(sv, c_Wer, nullptr, u, 1024, H2, H2, 0);
  // ---- event_sum, ves, wsal ----
  k_colsumP<<<48, 512, 0, stream>>>(evv, part);
  k_esum<<<1, 512, 0, stream>>>(part, esum);
  k_ves<<<8, 64, 0, stream>>>(c_Wes, esum, ves);
  k_sal<<<dim3(8, 32), 64, 0, stream>>>(c_Wss, blog, dv, wsal);
  // ---- outputs ----
  k_eventprobs<<<768, 256, 0, stream>>>(evv, ves, c_wec, c_tfs, c_starg,
                                        c_tf, c_sent, c_ebias, flag, probs, d_out);
  k_sentout<<<256, 256, 0, stream>>>(sv, u, evv, probs, wsal, c_wsc, c_dpe, c_spe,
                                     c_wsdp, c_wsp, c_brel, c_para, c_sbias, flag, d_out);
}

// Round 10
// 1234.275 us; speedup vs baseline: 1.2539x; 1.0438x over previous
//
#include <hip/hip_runtime.h>
#include <hip/hip_bf16.h>
#include <math.h>

typedef __bf16 bf16_t;
typedef __bf16 bf16x8 __attribute__((ext_vector_type(8)));
typedef __bf16 bf16x4 __attribute__((ext_vector_type(4)));
typedef float  f32x4  __attribute__((ext_vector_type(4)));

#define S_TOT 1024
#define T_W   32
#define D_EMB 300
#define KP    320
#define G3    768
#define Hh    256
#define H2    512
#define E_TOT 3072
#define NCANON 33

// fast gate math: ~5 VALU ops each (v_exp_f32 + v_rcp_f32); error ~2ulp f32.
__device__ __forceinline__ float fsigm(float x) {
  float e = __builtin_amdgcn_exp2f(x * -1.4426950408889634f);
  return __builtin_amdgcn_rcpf(1.f + e);
}
__device__ __forceinline__ float ftanh_(float x) {
  float e = __builtin_amdgcn_exp2f(x * 2.8853900817779268f);
  return 1.f - 2.f * __builtin_amdgcn_rcpf(1.f + e);
}

// ---------- dtype detector: flag=1 if float tensors are bf16, 0 if f32 ----------
__global__ void k_detect(const unsigned short* __restrict__ w, int* __restrict__ flag) {
  int lane = threadIdx.x;
  int sane = 0;
  for (int i = lane; i < 256; i += 64) {
    unsigned short v = w[2 * i];
    int ex = (v >> 7) & 0xFF;
    sane += (ex >= 96 && ex <= 134) ? 1 : 0;
  }
  #pragma unroll
  for (int o = 32; o > 0; o >>= 1) sane += __shfl_down(sane, o, 64);
  if (lane == 0) flag[0] = (sane >= 128) ? 1 : 0;
}

// ---------- canonicalize all float tensors to f32 ----------
struct Canon {
  const void* src[NCANON];
  int off[NCANON + 1];
};
__global__ void k_canon(Canon c, const int* __restrict__ flag, float* __restrict__ dst) {
  int i = blockIdx.x * 256 + threadIdx.x;
  if (i >= c.off[NCANON]) return;
  int seg = 0;
  while (c.off[seg + 1] <= i) ++seg;
  int j = i - c.off[seg];
  dst[i] = flag[0] ? (float)((const bf16_t*)c.src[seg])[j]
                   : ((const float*)c.src[seg])[j];
}

__global__ void k_lens(const int* __restrict__ x, int* __restrict__ lens) {
  int s = blockIdx.x * blockDim.x + threadIdx.x;
  if (s >= S_TOT) return;
  int c = 0;
  for (int t = 0; t < T_W; ++t) c += (x[s * T_W + t] != 0) ? 1 : 0;
  lens[s] = c;
}

// wih [2][768][512] f32 -> [2][512][768] f32
__global__ void k_transpose(const float* __restrict__ w, float* __restrict__ out) {
  __shared__ float tile[32][33];
  int d  = blockIdx.z;
  int n0 = blockIdx.x * 32, k0 = blockIdx.y * 32;
  int tx = threadIdx.x & 31, ty = threadIdx.x >> 5;
  for (int i = ty; i < 32; i += 8)
    tile[i][tx] = w[((size_t)d * G3 + n0 + i) * H2 + k0 + tx];
  __syncthreads();
  for (int i = ty; i < 32; i += 8)
    out[((size_t)d * H2 + k0 + i) * G3 + n0 + tx] = tile[tx][i];
}

// ---------- pack whh [2][768][256] f32 -> B-fragment-major bf16 ----------
// layout: [dir][wave(8)][sl(6)][k0(8)][lane(64)][8 bf16], sl = g*2+jt
__global__ void k_packB(const float* __restrict__ whh, bf16_t* __restrict__ packed) {
  int id = blockIdx.x * 256 + threadIdx.x;     // 49152 groups of 8 elems
  if (id >= 49152) return;
  int lane = id & 63;
  int k0 = (id >> 6) & 7;
  int t9 = id >> 9;
  int sl = t9 % 6;
  int wb = t9 / 6;
  int wv = wb & 7;
  int dir = wb >> 3;
  int g = sl >> 1, jt = sl & 1;
  int l16 = lane & 15, quad = lane >> 4;
  int n = g * Hh + wv * 32 + jt * 16 + l16;
  const float* src = whh + ((size_t)dir * G3 + n) * Hh + k0 * 32 + quad * 8;
  bf16_t* dst = packed + (size_t)id * 8;
  #pragma unroll
  for (int i = 0; i < 8; ++i) dst[i] = (bf16_t)src[i];
}

// ---------- pack wih [2][768][300] f32 -> MFMA-fragment-major bf16, K padded 320 ----------
// layout: [dir][n0(12)][slot s=j*10+k0 (40)][lane(64)][8 bf16]
__global__ void k_packWih(const float* __restrict__ wih, bf16_t* __restrict__ out) {
  int id = blockIdx.x * 256 + threadIdx.x;     // 61440 frags of 8
  if (id >= 61440) return;
  int lane = id & 63;
  int su = id >> 6;
  int s  = su % 40;
  int n0 = (su / 40) % 12;
  int dir = su / 480;
  int j = s / 10, k0 = s % 10;
  int l16 = lane & 15, quad = lane >> 4;
  int n = n0 * 64 + j * 16 + l16;
  int c = k0 * 32 + quad * 8;
  const float* src = wih + ((size_t)dir * G3 + n) * D_EMB + c;
  bf16_t* dst = out + (size_t)id * 8;
  #pragma unroll
  for (int i = 0; i < 8; ++i)
    dst[i] = (c + i < D_EMB) ? (bf16_t)src[i] : (bf16_t)0.f;
}

// ---------- combined bias: biasC[dir][c] = bih[dir][c] + (c<512 ? bhh[dir][c] : 0) ----------
__global__ void k_biasC(const float* __restrict__ bih, const float* __restrict__ bhh,
                        float* __restrict__ out) {
  int i = blockIdx.x * 256 + threadIdx.x;
  if (i >= 2 * G3) return;
  int c = i % G3;
  out[i] = bih[i] + (c < 2 * Hh ? bhh[i] : 0.f);
}

// ---------- fused gather + input projection, v3: 512 threads for 2 waves/SIMD ----------
// r9 finding: giB ran at 1 wave/SIMD (80KB LDS, 256 threads -> 1 block/CU, 4
// waves) -> 90% idle on the scattered embed gather (MfmaUtil 10%, VALUBusy 6%).
// v3: 512 threads, wave owns 16 rows (was 32). Same 128 rows/block, same LDS,
// same total MFMA; 8 waves/CU = 2/SIMD doubles latency hiding; VGPR ~150.
__global__ __launch_bounds__(512, 1) void k_giB(
    const int* __restrict__ toks, const void* __restrict__ embed,
    const bf16_t* __restrict__ wpk,   // this dir: [12][40][64][8]
    const float* __restrict__ bih,    // this dir's combined bias [768]
    const int* __restrict__ flag, bf16_t* __restrict__ gi, int mbase) {
  __shared__ __align__(16) bf16_t Bt[2][20480];   // 2 x 40KB
  int tid = threadIdx.x;
  int wave = tid >> 6, lane = tid & 63;
  int l16 = lane & 15, quad = lane >> 4;
  int m0 = blockIdx.x * 128;
  int isb = flag[0];

  // ---- A fragments from global (once): wave owns rows m0 + wave*16 + l16 ----
  bf16x8 ah[10], al[10];
  {
    int tok = toks[mbase + m0 + wave * 16 + l16];
    if (isb) {
      const bf16_t* er = (const bf16_t*)embed + (size_t)tok * D_EMB;
      #pragma unroll
      for (int k0 = 0; k0 < 10; ++k0) {
        int c = k0 * 32 + quad * 8;
        bf16x8 v = {};
        if (c + 8 <= D_EMB) {
          bf16x4 t0 = *(const bf16x4*)(er + c);
          bf16x4 t1 = *(const bf16x4*)(er + c + 4);
          v[0]=t0[0]; v[1]=t0[1]; v[2]=t0[2]; v[3]=t0[3];
          v[4]=t1[0]; v[5]=t1[1]; v[6]=t1[2]; v[7]=t1[3];
        } else if (c < D_EMB) {
          bf16x4 t0 = *(const bf16x4*)(er + c);
          v[0]=t0[0]; v[1]=t0[1]; v[2]=t0[2]; v[3]=t0[3];
        }
        ah[k0] = v;
        al[k0] = (bf16x8){};
      }
    } else {
      const float* er = (const float*)embed + (size_t)tok * D_EMB;
      #pragma unroll
      for (int k0 = 0; k0 < 10; ++k0) {
        int c = k0 * 32 + quad * 8;
        float v[8];
        #pragma unroll
        for (int i = 0; i < 8; ++i) v[i] = 0.f;
        if (c + 4 <= D_EMB) { float4 t = *(const float4*)(er + c);
                              v[0]=t.x; v[1]=t.y; v[2]=t.z; v[3]=t.w; }
        if (c + 8 <= D_EMB) { float4 t = *(const float4*)(er + c + 4);
                              v[4]=t.x; v[5]=t.y; v[6]=t.z; v[7]=t.w; }
        bf16x8 h, l;
        #pragma unroll
        for (int i = 0; i < 8; ++i) {
          bf16_t hv = (bf16_t)v[i];
          h[i] = hv; l[i] = (bf16_t)(v[i] - (float)hv);
        }
        ah[k0] = h; al[k0] = l;
      }
    }
  }

  // ---- B staging: 512 threads x 5 bf16x8 per 40KB tile ----
  bf16x8 stg[5];
  {
    const bf16_t* base = wpk + (size_t)tid * 8;
    #pragma unroll
    for (int i = 0; i < 5; ++i) stg[i] = *(const bf16x8*)(base + i * 4096);
    bf16_t* dst = &Bt[0][tid * 8];
    #pragma unroll
    for (int i = 0; i < 5; ++i) *(bf16x8*)(dst + i * 4096) = stg[i];
  }
  __syncthreads();

  for (int n0 = 0; n0 < 12; ++n0) {
    int cur = n0 & 1;
    if (n0 + 1 < 12) {
      const bf16_t* base = wpk + (size_t)(n0 + 1) * 20480 + (size_t)tid * 8;
      #pragma unroll
      for (int i = 0; i < 5; ++i) stg[i] = *(const bf16x8*)(base + i * 4096);
    }
    f32x4 acc[4];
    #pragma unroll
    for (int j = 0; j < 4; ++j) acc[j] = (f32x4){0.f, 0.f, 0.f, 0.f};
    const bf16_t* Bc = Bt[cur];
    #pragma unroll
    for (int k0 = 0; k0 < 10; ++k0) {
      bf16x8 b[4];
      #pragma unroll
      for (int j = 0; j < 4; ++j)
        b[j] = *(const bf16x8*)&Bc[((j * 10 + k0) * 64 + lane) * 8];
      if (isb) {
        #pragma unroll
        for (int j = 0; j < 4; ++j)
          acc[j] = __builtin_amdgcn_mfma_f32_16x16x32_bf16(ah[k0], b[j], acc[j], 0, 0, 0);
      } else {
        #pragma unroll
        for (int j = 0; j < 4; ++j)
          acc[j] = __builtin_amdgcn_mfma_f32_16x16x32_bf16(al[k0], b[j], acc[j], 0, 0, 0);
        #pragma unroll
        for (int j = 0; j < 4; ++j)
          acc[j] = __builtin_amdgcn_mfma_f32_16x16x32_bf16(ah[k0], b[j], acc[j], 0, 0, 0);
      }
    }
    {
      int row0 = m0 + wave * 16 + quad * 4;
      #pragma unroll
      for (int j = 0; j < 4; ++j) {
        int col = n0 * 64 + j * 16 + l16;
        float bb = bih[col];
        #pragma unroll
        for (int rr = 0; rr < 4; ++rr)
          gi[(size_t)(row0 + rr) * G3 + col] = (bf16_t)(acc[j][rr] + bb);
      }
    }
    if (n0 + 1 < 12) {
      bf16_t* dst = &Bt[cur ^ 1][tid * 8];
      #pragma unroll
      for (int i = 0; i < 5; ++i) *(bf16x8*)(dst + i * 4096) = stg[i];
      __syncthreads();
    }
  }
}

// ---------- f32 SGEMM: C[M][N] = A[M][K] @ B[K][N] (+bias), out f32 or bf16 ----------
__global__ __launch_bounds__(256) void k_sgemm(
    const float* __restrict__ A, const float* __restrict__ B,
    const float* __restrict__ bias, void* __restrict__ C,
    int M, int N, int K, int obf) {
  __shared__ float As[32][65];
  __shared__ float Bs[32][65];
  int bm = blockIdx.x * 64, bn = blockIdx.y * 64;
  int tid = threadIdx.x;
  int tx = tid & 15, ty = tid >> 4;
  float acc[4][4] = {};
  for (int k0 = 0; k0 < K; k0 += 32) {
    for (int i = tid; i < 64 * 32; i += 256) {
      int m = i >> 5, k = i & 31;
      As[k][m] = (bm + m < M) ? A[(size_t)(bm + m) * K + k0 + k] : 0.f;
    }
    for (int i = tid; i < 32 * 64; i += 256) {
      int k = i >> 6, n = i & 63;
      Bs[k][n] = B[(size_t)(k0 + k) * N + bn + n];
    }
    __syncthreads();
    #pragma unroll 8
    for (int k = 0; k < 32; ++k) {
      float a[4], b[4];
      #pragma unroll
      for (int i = 0; i < 4; ++i) a[i] = As[k][ty + i * 16];
      #pragma unroll
      for (int j = 0; j < 4; ++j) b[j] = Bs[k][tx + j * 16];
      #pragma unroll
      for (int i = 0; i < 4; ++i)
        #pragma unroll
        for (int j = 0; j < 4; ++j) acc[i][j] += a[i] * b[j];
    }
    __syncthreads();
  }
  for (int i = 0; i < 4; ++i) {
    int m = bm + ty + i * 16;
    if (m >= M) continue;
    for (int j = 0; j < 4; ++j) {
      int n = bn + tx + j * 16;
      float v = acc[i][j] + (bias ? bias[n] : 0.f);
      if (obf) ((bf16_t*)C)[(size_t)m * N + n] = (bf16_t)v;
      else     ((float*)C)[(size_t)m * N + n] = v;
    }
  }
}

// ---------- batched MFMA GRU (exact round-2 v2: proven 115us local optimum) ----------
// r9 closed the book on gruM perturbations: v3 (LDS gi staging) +15us, v5
// (streamed bn) +20us, v6 (packed gi) +15us, v7 (spb split) +20us. v7's
// counters proved the per-step wall is not per-CU miss-parallelism (2x CUs,
// same step time). Keep v2 exactly.
__global__ __launch_bounds__(512)
__attribute__((amdgpu_waves_per_eu(2, 2)))
void k_gruM(
    const bf16_t* __restrict__ gi, size_t gi_dstride,
    const bf16_t* __restrict__ whhP, const float* __restrict__ bhh,
    const int* __restrict__ lens, float* __restrict__ pool,
    int T, int sbase, int nsent) {
  int dir = blockIdx.y;
  int tid = threadIdx.x;
  int wave = tid >> 6, lane = tid & 63;
  int l16 = lane & 15, quad = lane >> 4;
  int sblk = blockIdx.x * 16;
  const bf16_t* giD  = gi + (size_t)dir * gi_dstride;
  const float*  bhhD = bhh + (size_t)dir * G3;

  // [buf][k0][m(16)][q(4)][ii(8)] bf16 -> A-frag read is 16B contiguous/lane
  __shared__ __align__(16) bf16_t hA[2][8][16][4][8];

  // whh fragments, register-resident
  bf16x8 Bf[48];
  {
    const bf16_t* Bb = whhP + (size_t)dir * G3 * Hh + (size_t)wave * 48 * 512 + lane * 8;
    #pragma unroll
    for (int s = 0; s < 48; ++s) Bf[s] = *(const bf16x8*)(Bb + s * 512);
  }
  float bhn[2];
  #pragma unroll
  for (int jt = 0; jt < 2; ++jt)
    bhn[jt] = bhhD[2 * Hh + wave * 32 + jt * 16 + l16];
  int Lm[4];
  #pragma unroll
  for (int r = 0; r < 4; ++r) {
    int sa = sblk + quad * 4 + r;
    Lm[r] = (lens && sa < nsent) ? lens[sbase + sa] : T;
  }
  float pmax[2][4];
  #pragma unroll
  for (int jt = 0; jt < 2; ++jt)
    #pragma unroll
    for (int r = 0; r < 4; ++r) pmax[jt][r] = -1e30f;

  // h state in registers: hreg[jt][r]
  float hreg[2][4];
  #pragma unroll
  for (int jt = 0; jt < 2; ++jt)
    #pragma unroll
    for (int r = 0; r < 4; ++r) hreg[jt][r] = 0.f;

  // incremental gi row pointers (advance by +-G3 per step)
  int t0 = dir ? (T - 1) : 0;
  long long stepoff = dir ? -(long long)G3 : (long long)G3;
  const bf16_t* rp[4];
  #pragma unroll
  for (int r = 0; r < 4; ++r)
    rp[r] = giD + ((size_t)(sblk + quad * 4 + r) * T + t0) * (size_t)G3;

  // zero read buffer 0
  {
    bf16_t* hz = &hA[0][0][0][0][0];
    for (int i = tid; i < 8 * 16 * 4 * 8; i += 512) hz[i] = (bf16_t)0.f;
  }

  // prefetch gv for step 0
  bf16_t gv[3][2][4];
  #pragma unroll
  for (int jt = 0; jt < 2; ++jt) {
    int j = wave * 32 + jt * 16 + l16;
    #pragma unroll
    for (int r = 0; r < 4; ++r) {
      gv[0][jt][r] = rp[r][j];
      gv[1][jt][r] = rp[r][Hh + j];
      gv[2][jt][r] = rp[r][2 * Hh + j];
    }
  }
  __syncthreads();

  int cur = 0;
  for (int step = 0; step < T; ++step) {
    int t = dir ? (T - 1 - step) : step;
    // MFMA phase: gh = h @ whh^T (B register-resident, A from LDS buf[cur])
    f32x4 C[3][2];
    #pragma unroll
    for (int g = 0; g < 3; ++g)
      #pragma unroll
      for (int jt = 0; jt < 2; ++jt) C[g][jt] = (f32x4){0.f, 0.f, 0.f, 0.f};
    #pragma unroll
    for (int k0 = 0; k0 < 8; ++k0) {
      bf16x8 a8 = *(const bf16x8*)&hA[cur][k0][l16][quad][0];
      #pragma unroll
      for (int g = 0; g < 3; ++g)
        #pragma unroll
        for (int jt = 0; jt < 2; ++jt)
          C[g][jt] = __builtin_amdgcn_mfma_f32_16x16x32_bf16(a8, Bf[(g * 2 + jt) * 8 + k0], C[g][jt], 0, 0, 0);
    }
    // gate phase: uses gv prefetched last step; writes h to buf[cur^1]
    #pragma unroll
    for (int jt = 0; jt < 2; ++jt) {
      int q2 = jt * 2 + (l16 >> 3);
      int ii = l16 & 7;
      #pragma unroll
      for (int r = 0; r < 4; ++r) {
        int m = quad * 4 + r;
        float hp = hreg[jt][r];
        float rr = fsigm((float)gv[0][jt][r] + C[0][jt][r]);
        float zz = fsigm((float)gv[1][jt][r] + C[1][jt][r]);
        float nn = ftanh_((float)gv[2][jt][r] + rr * (C[2][jt][r] + bhn[jt]));
        float hnew = nn + zz * (hp - nn);
        hreg[jt][r] = hnew;
        hA[cur ^ 1][wave][m][q2][ii] = (bf16_t)hnew;
        if (t < Lm[r]) pmax[jt][r] = fmaxf(pmax[jt][r], hnew);
      }
    }
    // advance pointers; issue next step's gv loads BEFORE the barrier;
    // the lgkm-only barrier leaves them in flight across it.
    #pragma unroll
    for (int r = 0; r < 4; ++r) rp[r] += stepoff;
    if (step + 1 < T) {
      #pragma unroll
      for (int jt = 0; jt < 2; ++jt) {
        int j = wave * 32 + jt * 16 + l16;
        #pragma unroll
        for (int r = 0; r < 4; ++r) {
          gv[0][jt][r] = rp[r][j];
          gv[1][jt][r] = rp[r][Hh + j];
          gv[2][jt][r] = rp[r][2 * Hh + j];
        }
      }
    }
    asm volatile("s_waitcnt lgkmcnt(0)" ::: "memory");
    __builtin_amdgcn_s_barrier();
    cur ^= 1;
  }
  #pragma unroll
  for (int jt = 0; jt < 2; ++jt) {
    int j = wave * 32 + jt * 16 + l16;
    #pragma unroll
    for (int r = 0; r < 4; ++r) {
      int sa = sblk + quad * 4 + r;
      if (sa < nsent) {
        float v = pmax[jt][r];
        if (v < -9e29f) v = 0.f;
        pool[(size_t)(sbase + sa) * H2 + dir * Hh + j] = v;
      }
    }
  }
}

// ---------- epilogue ----------
__global__ __launch_bounds__(512) void k_colsumP(const float* __restrict__ ev, float* __restrict__ part) {
  int t = threadIdx.x;
  int r0 = blockIdx.x * 64;
  float s = 0.f;
  for (int r = 0; r < 64; ++r) s += ev[(size_t)(r0 + r) * H2 + t];
  part[(size_t)blockIdx.x * H2 + t] = s;
}
__global__ __launch_bounds__(512) void k_esum(const float* __restrict__ part, float* __restrict__ out) {
  int t = threadIdx.x;
  float s = 0.f;
  for (int b = 0; b < 48; ++b) s += part[(size_t)b * H2 + t];
  out[t] = s;
}

__global__ void k_ves(const float* __restrict__ W, const float* __restrict__ sum, float* __restrict__ ves) {
  int d = blockIdx.x * 64 + threadIdx.x;
  const float* row = W + (size_t)d * H2;
  float s = 0.f;
  for (int f = 0; f < H2; ++f) s += row[f] * sum[f];
  ves[d] = s * (1.f / 3072.f);
}

__global__ void k_sal(const float* __restrict__ W, const float* __restrict__ blog,
                      const float* __restrict__ dv, float* __restrict__ out) {
  int doc = blockIdx.y;
  int i = blockIdx.x * 64 + threadIdx.x;
  const float* row = W + (size_t)i * (2 * H2);
  const float* dvr = dv + (size_t)doc * H2;
  float s = 0.f;
  for (int f = 0; f < H2; ++f) s += row[f] * blog[f];
  for (int f = 0; f < H2; ++f) s += row[H2 + f] * dvr[f];
  out[(size_t)doc * H2 + i] = s;
}

__global__ __launch_bounds__(256) void k_eventprobs(
    const float* __restrict__ evv, const float* __restrict__ ves,
    const float* __restrict__ w_ec, const float* __restrict__ tfs,
    const float* __restrict__ st, const float* __restrict__ c_tf,
    const float* __restrict__ c_sent, const float* __restrict__ c_bias,
    const int* __restrict__ flag, float* __restrict__ probs, void* __restrict__ outp) {
  int lane = threadIdx.x & 63;
  int e = blockIdx.x * 4 + (threadIdx.x >> 6);
  const float* row = evv + (size_t)e * H2;
  float s = 0.f;
  for (int f = lane; f < H2; f += 64) s += row[f] * (w_ec[f] + ves[f]);
  #pragma unroll
  for (int o = 32; o > 0; o >>= 1) s += __shfl_down(s, o, 64);
  if (lane == 0) {
    float p = s + c_tf[0] * tfs[e] + c_bias[0] + c_sent[0] * st[e / 3];
    probs[e] = p;
    if (flag[0]) ((bf16_t*)outp)[S_TOT + e] = (bf16_t)p;
    else         ((float*)outp)[S_TOT + e] = p;
  }
}

__global__ __launch_bounds__(256) void k_sentout(
    const float* __restrict__ sv, const float* __restrict__ u,
    const float* __restrict__ evv, const float* __restrict__ probs,
    const float* __restrict__ wsal, const float* __restrict__ w_sc,
    const float* __restrict__ dpe, const float* __restrict__ spe,
    const float* __restrict__ w_sdp, const float* __restrict__ w_sp,
    const float* __restrict__ b_rel, const float* __restrict__ para,
    const float* __restrict__ sbias, const int* __restrict__ flag,
    void* __restrict__ outp) {
  int lane = threadIdx.x & 63;
  int s = blockIdx.x * 4 + (threadIdx.x >> 6);
  int doc = s >> 5, jj = s & 31;
  const float* svr = sv + (size_t)s * H2;
  const float* ur  = u + (size_t)s * H2;
  const float* wd  = wsal + (size_t)doc * H2;
  float acc = 0.f, e0 = 0.f, e1 = 0.f, e2 = 0.f;
  for (int f = lane; f < H2; f += 64) {
    float svf = svr[f], uf = ur[f];
    acc += svf * (w_sc[f] + wd[f]);
    e0 += uf * evv[(size_t)(s * 3 + 0) * H2 + f];
    e1 += uf * evv[(size_t)(s * 3 + 1) * H2 + f];
    e2 += uf * evv[(size_t)(s * 3 + 2) * H2 + f];
  }
  if (lane < 50) {
    int dpos = (doc * 40) / 32;
    int spos = (jj * 30) / 32;
    acc += dpe[dpos * 50 + lane] * w_sdp[lane] + spe[spos * 50 + lane] * w_sp[lane];
  }
  #pragma unroll
  for (int o = 32; o > 0; o >>= 1) {
    acc += __shfl_down(acc, o, 64);
    e0  += __shfl_down(e0, o, 64);
    e1  += __shfl_down(e1, o, 64);
    e2  += __shfl_down(e2, o, 64);
  }
  if (lane == 0) {
    float br = b_rel[0];
    float rel = (e0 + br) * probs[s * 3 + 0] + (e1 + br) * probs[s * 3 + 1]
              + (e2 + br) * probs[s * 3 + 2];
    float v = acc + para[0] * rel + sbias[0];
    if (flag[0]) ((bf16_t*)outp)[s] = (bf16_t)v;
    else         ((float*)outp)[s] = v;
  }
}

// ---------------- launcher ----------------
extern "C" void kernel_launch(void* const* d_in, const int* in_sizes, int n_in,
                              void* d_out, int out_size, void* d_ws, size_t ws_size,
                              hipStream_t stream) {
  (void)in_sizes; (void)n_in; (void)out_size;
  const int* x      = (const int*)d_in[0];
  const int* events = (const int*)d_in[1];
  const void* embed = d_in[8];

  char* ws = (char*)d_ws;
  size_t off = 0;
  auto alloc = [&](size_t bytes) -> void* {
    void* p = ws + off;
    off += (bytes + 255) & ~(size_t)255;
    return p;
  };

  static const int cidx[NCANON] = {9,10,11,12, 13,14,15,16, 17,18,19,20, 21,22,23,24,
                                   25,26,27,28,29,30,31, 32,33,34,35, 36,37,38,40, 5,7};
  static const int csz[NCANON]  = {2*G3*D_EMB, 2*G3*Hh, 2*G3, 2*G3,
                                   2*G3*H2,    2*G3*Hh, 2*G3, 2*G3,
                                   2*G3*H2,    2*G3*Hh, 2*G3, 2*G3,
                                   2*G3*D_EMB, 2*G3*Hh, 2*G3, 2*G3,
                                   40*50, 30*50, H2, H2*H2, 1, 1, 1,
                                   H2, H2*2*H2, 50, 50,
                                   H2*H2, 1, 1, 1, E_TOT, S_TOT};
  Canon cd;
  int tot = 0;
  for (int i = 0; i < NCANON; ++i) { cd.src[i] = d_in[cidx[i]]; cd.off[i] = tot; tot += csz[i]; }
  cd.off[NCANON] = tot;

  int*   flag  = (int*)alloc(256);
  float* canon = (float*)alloc((size_t)tot * 4);
  float* cptr[NCANON];
  for (int i = 0; i < NCANON; ++i) cptr[i] = canon + cd.off[i];
  float *cw_wih = cptr[0], *cw_whh = cptr[1], *cw_bih = cptr[2], *cw_bhh = cptr[3];
  float *cs_wih = cptr[4], *cs_whh = cptr[5], *cs_bih = cptr[6], *cs_bhh = cptr[7];
  float *cd_wih = cptr[8], *cd_whh = cptr[9], *cd_bih = cptr[10], *cd_bhh = cptr[11];
  float *ce_wih = cptr[12], *ce_whh = cptr[13], *ce_bih = cptr[14], *ce_bhh = cptr[15];
  float *c_dpe = cptr[16], *c_spe = cptr[17], *c_wec = cptr[18], *c_Wes = cptr[19];
  float *c_tf = cptr[20], *c_sent = cptr[21], *c_ebias = cptr[22];
  float *c_wsc = cptr[23], *c_Wss = cptr[24], *c_wsdp = cptr[25], *c_wsp = cptr[26];
  float *c_Wer = cptr[27], *c_brel = cptr[28], *c_para = cptr[29], *c_sbias = cptr[30];
  float *c_tfs = cptr[31], *c_starg = cptr[32];

  bf16_t* packW = (bf16_t*)alloc((size_t)2 * G3 * Hh * 2);
  bf16_t* packE = (bf16_t*)alloc((size_t)2 * G3 * Hh * 2);
  bf16_t* packS = (bf16_t*)alloc((size_t)2 * G3 * Hh * 2);
  bf16_t* packD = (bf16_t*)alloc((size_t)2 * G3 * Hh * 2);
  bf16_t* packGiW = (bf16_t*)alloc((size_t)2 * 12 * 40 * 64 * 8 * 2);
  bf16_t* packGiE = (bf16_t*)alloc((size_t)2 * 12 * 40 * 64 * 8 * 2);
  float*  bcW  = (float*)alloc((size_t)2 * G3 * 4);
  float*  bcE  = (float*)alloc((size_t)2 * G3 * 4);
  float*  bcS  = (float*)alloc((size_t)2 * G3 * 4);
  float*  bcD  = (float*)alloc((size_t)2 * G3 * 4);
  float*  sv   = (float*)alloc((size_t)S_TOT * H2 * 4);
  float*  evv  = (float*)alloc((size_t)E_TOT * H2 * 4);
  float*  dv   = (float*)alloc((size_t)32 * H2 * 4);
  float*  blog = (float*)alloc((size_t)H2 * 4);
  float*  wSt  = (float*)alloc((size_t)2 * H2 * G3 * 4);
  float*  wDt  = (float*)alloc((size_t)2 * H2 * G3 * 4);
  float*  u    = (float*)alloc((size_t)S_TOT * H2 * 4);
  float*  part = (float*)alloc((size_t)48 * H2 * 4);
  float*  esum = (float*)alloc((size_t)H2 * 4);
  float*  ves  = (float*)alloc((size_t)H2 * 4);
  float*  wsal = (float*)alloc((size_t)32 * H2 * 4);
  float*  probs= (float*)alloc((size_t)E_TOT * 4);
  int*    lens = (int*)alloc((size_t)S_TOT * 4);
  bf16_t* sgi  = (bf16_t*)alloc((size_t)2 * S_TOT * G3 * 2);
  bf16_t* dgi  = (bf16_t*)alloc((size_t)2 * 32 * G3 * 2);

  size_t fixed = off;
  size_t avail = (ws_size > fixed) ? (ws_size - fixed) : 0;
  long long rpc = (long long)(avail / ((size_t)G3 * 2 * 2));   // bf16 rows, both dirs
  rpc &= ~511LL;
  if (rpc < 512) rpc = 512;
  if (rpc > 32768) rpc = 32768;
  bf16_t* gib = (bf16_t*)(ws + fixed);

  // ---- prep ----
  k_detect<<<1, 64, 0, stream>>>((const unsigned short*)embed, flag);
  k_canon<<<(tot + 255) / 256, 256, 0, stream>>>(cd, flag, canon);
  k_packB<<<192, 256, 0, stream>>>(cw_whh, packW);
  k_packB<<<192, 256, 0, stream>>>(ce_whh, packE);
  k_packB<<<192, 256, 0, stream>>>(cs_whh, packS);
  k_packB<<<192, 256, 0, stream>>>(cd_whh, packD);
  k_packWih<<<240, 256, 0, stream>>>(cw_wih, packGiW);
  k_packWih<<<240, 256, 0, stream>>>(ce_wih, packGiE);
  k_biasC<<<6, 256, 0, stream>>>(cw_bih, cw_bhh, bcW);
  k_biasC<<<6, 256, 0, stream>>>(ce_bih, ce_bhh, bcE);
  k_biasC<<<6, 256, 0, stream>>>(cs_bih, cs_bhh, bcS);
  k_biasC<<<6, 256, 0, stream>>>(cd_bih, cd_bhh, bcD);
  k_lens<<<4, 256, 0, stream>>>(x, lens);
  k_transpose<<<dim3(24, 16, 2), 256, 0, stream>>>(cs_wih, wSt);
  k_transpose<<<dim3(24, 16, 2), 256, 0, stream>>>(cd_wih, wDt);

  // ---- word BiGRU -> sent_vec ----
  for (long long r0 = 0; r0 < 32768; r0 += rpc) {
    long long rows = 32768 - r0; if (rows > rpc) rows = rpc;
    for (int d = 0; d < 2; ++d)
      k_giB<<<dim3((int)(rows / 128)), 512, 0, stream>>>(
          x, embed, packGiW + (size_t)d * 245760, bcW + d * G3, flag,
          gib + (size_t)d * rows * G3, (int)r0);
    k_gruM<<<dim3((int)(rows / 512), 2), 512, 0, stream>>>(
        gib, (size_t)rows * G3, packW, cw_bhh, lens, sv, 32, (int)(r0 / 32),
        (int)(rows / 32));
  }
  // ---- event BiGRU -> event_vec ----
  for (long long r0 = 0; r0 < 12288; r0 += rpc) {
    long long rows = 12288 - r0; if (rows > rpc) rows = rpc;
    for (int d = 0; d < 2; ++d)
      k_giB<<<dim3((int)(rows / 128)), 512, 0, stream>>>(
          events, embed, packGiE + (size_t)d * 245760, bcE + d * G3, flag,
          gib + (size_t)d * rows * G3, (int)r0);
    k_gruM<<<dim3((int)(rows / 64), 2), 512, 0, stream>>>(
        gib, (size_t)rows * G3, packE, ce_bhh, nullptr, evv, 4, (int)(r0 / 4),
        (int)(rows / 4));
  }
  // ---- sent BiGRU (batch=32 docs, T=32) -> doc_vec ----
  for (int d = 0; d < 2; ++d)
    k_sgemm<<<dim3(16, 12), 256, 0, stream>>>(sv, wSt + (size_t)d * H2 * G3,
                                              bcS + d * G3,
                                              sgi + (size_t)d * S_TOT * G3, 1024, G3, H2, 1);
  k_gruM<<<dim3(2, 2), 512, 0, stream>>>(sgi, (size_t)S_TOT * G3, packS, cs_bhh,
                                         nullptr, dv, 32, 0, 32);
  // ---- doc BiGRU (batch=1, T=32) -> blog_vec ----
  for (int d = 0; d < 2; ++d)
    k_sgemm<<<dim3(1, 12), 256, 0, stream>>>(dv, wDt + (size_t)d * H2 * G3,
                                             bcD + d * G3,
                                             dgi + (size_t)d * 32 * G3, 32, G3, H2, 1);
  k_gruM<<<dim3(1, 2), 512, 0, stream>>>(dgi, (size_t)32 * G3, packD, cd_bhh,
                                         nullptr, blog, 32, 0, 1);
  // ---- u = sent_vec @ W_event_rel (f32 out) ----
  k_sgemm<<<dim3(16, 8), 256, 0, stream>>>(sv, c_Wer, nullptr, u, 1024, H2, H2, 0);
  // ---- event_sum, ves, wsal ----
  k_colsumP<<<48, 512, 0, stream>>>(evv, part);
  k_esum<<<1, 512, 0, stream>>>(part, esum);
  k_ves<<<8, 64, 0, stream>>>(c_Wes, esum, ves);
  k_sal<<<dim3(8, 32), 64, 0, stream>>>(c_Wss, blog, dv, wsal);
  // ---- outputs ----
  k_eventprobs<<<768, 256, 0, stream>>>(evv, ves, c_wec, c_tfs, c_starg,
                                        c_tf, c_sent, c_ebias, flag, probs, d_out);
  k_sentout<<<256, 256, 0, stream>>>(sv, u, evv, probs, wsal, c_wsc, c_dpe, c_spe,
                                     c_wsdp, c_wsp, c_brel, c_para, c_sbias, flag, d_out);
}

// Round 11
// 972.551 us; speedup vs baseline: 1.5913x; 1.2691x over previous
//
#include <hip/hip_runtime.h>
#include <hip/hip_bf16.h>
#include <math.h>

typedef __bf16 bf16_t;
typedef __bf16 bf16x8 __attribute__((ext_vector_type(8)));
typedef __bf16 bf16x4 __attribute__((ext_vector_type(4)));
typedef float  f32x4  __attribute__((ext_vector_type(4)));

#define S_TOT 1024
#define T_W   32
#define D_EMB 300
#define KP    320
#define G3    768
#define Hh    256
#define H2    512
#define E_TOT 3072
#define NCANON 33

__device__ __forceinline__ float fsigm(float x) {
  float e = __builtin_amdgcn_exp2f(x * -1.4426950408889634f);
  return __builtin_amdgcn_rcpf(1.f + e);
}
__device__ __forceinline__ float ftanh_(float x) {
  float e = __builtin_amdgcn_exp2f(x * 2.8853900817779268f);
  return 1.f - 2.f * __builtin_amdgcn_rcpf(1.f + e);
}

// ---------- dtype detector ----------
__global__ void k_detect(const unsigned short* __restrict__ w, int* __restrict__ flag) {
  int lane = threadIdx.x;
  int sane = 0;
  for (int i = lane; i < 256; i += 64) {
    unsigned short v = w[2 * i];
    int ex = (v >> 7) & 0xFF;
    sane += (ex >= 96 && ex <= 134) ? 1 : 0;
  }
  #pragma unroll
  for (int o = 32; o > 0; o >>= 1) sane += __shfl_down(sane, o, 64);
  if (lane == 0) flag[0] = (sane >= 128) ? 1 : 0;
}

// ---------- canonicalize ----------
struct Canon {
  const void* src[NCANON];
  int off[NCANON + 1];
};
__global__ void k_canon(Canon c, const int* __restrict__ flag, float* __restrict__ dst) {
  int i = blockIdx.x * 256 + threadIdx.x;
  if (i >= c.off[NCANON]) return;
  int seg = 0;
  while (c.off[seg + 1] <= i) ++seg;
  int j = i - c.off[seg];
  dst[i] = flag[0] ? (float)((const bf16_t*)c.src[seg])[j]
                   : ((const float*)c.src[seg])[j];
}

// ---------- fat prep kernel: packB x4, packWih x2, biasC x4, transpose x2, lens ----------
// Collapses 13 tiny serialized launches into one dispatch (launch-gap + latency
// overlap). Block-range dispatch, all sections 256 threads.
struct PrepArgs {
  const float* whh[4];   bf16_t* pk[4];        // packB
  const float* wih2[2];  bf16_t* pw2[2];       // packWih
  const float* bih4[4];  const float* bhh4[4]; float* bc4[4];   // biasC
  const float* tsrc[2];  float* tdst[2];       // transpose
  const int* x; int* lens;
};
__global__ __launch_bounds__(256) void k_prep(PrepArgs a) {
  int b = blockIdx.x, tid = threadIdx.x;
  if (b < 768) {                       // ---- packB x4 ----
    int ti = b / 192, lb = b % 192;
    int id = lb * 256 + tid;
    int lane = id & 63;
    int k0 = (id >> 6) & 7;
    int t9 = id >> 9;
    int sl = t9 % 6;
    int wb = t9 / 6;
    int wv = wb & 7;
    int dir = wb >> 3;
    int g = sl >> 1, jt = sl & 1;
    int l16 = lane & 15, quad = lane >> 4;
    int n = g * Hh + wv * 32 + jt * 16 + l16;
    const float* src = a.whh[ti] + ((size_t)dir * G3 + n) * Hh + k0 * 32 + quad * 8;
    bf16_t* dst = a.pk[ti] + (size_t)id * 8;
    #pragma unroll
    for (int i = 0; i < 8; ++i) dst[i] = (bf16_t)src[i];
  } else if (b < 1248) {               // ---- packWih x2 ----
    int ti = (b - 768) / 240, lb = (b - 768) % 240;
    int id = lb * 256 + tid;
    int lane = id & 63;
    int su = id >> 6;
    int s  = su % 40;
    int n0 = (su / 40) % 12;
    int dir = su / 480;
    int j = s / 10, k0 = s % 10;
    int l16 = lane & 15, quad = lane >> 4;
    int n = n0 * 64 + j * 16 + l16;
    int c = k0 * 32 + quad * 8;
    const float* src = a.wih2[ti] + ((size_t)dir * G3 + n) * D_EMB + c;
    bf16_t* dst = a.pw2[ti] + (size_t)id * 8;
    #pragma unroll
    for (int i = 0; i < 8; ++i)
      dst[i] = (c + i < D_EMB) ? (bf16_t)src[i] : (bf16_t)0.f;
  } else if (b < 1272) {               // ---- biasC x4 ----
    int ti = (b - 1248) / 6, lb = (b - 1248) % 6;
    int i = lb * 256 + tid;
    if (i < 2 * G3) {
      int c = i % G3;
      a.bc4[ti][i] = a.bih4[ti][i] + (c < 2 * Hh ? a.bhh4[ti][i] : 0.f);
    }
  } else if (b < 2808) {               // ---- transpose x2 ----
    __shared__ float tile[32][33];
    int lb = b - 1272;
    int which = lb / 768;
    int r = lb % 768;
    int bx = r % 24, by = (r / 24) % 16, d = r / 384;
    const float* w = a.tsrc[which];
    float* out = a.tdst[which];
    int n0 = bx * 32, k0 = by * 32;
    int tx = tid & 31, ty = tid >> 5;
    for (int i = ty; i < 32; i += 8)
      tile[i][tx] = w[((size_t)d * G3 + n0 + i) * H2 + k0 + tx];
    __syncthreads();
    for (int i = ty; i < 32; i += 8)
      out[((size_t)d * H2 + k0 + i) * G3 + n0 + tx] = tile[tx][i];
  } else {                             // ---- lens ----
    int s = (b - 2808) * 256 + tid;
    if (s < S_TOT) {
      int c = 0;
      for (int t = 0; t < T_W; ++t) c += (a.x[s * T_W + t] != 0) ? 1 : 0;
      a.lens[s] = c;
    }
  }
}

// ---------- fused gather + input projection (512t, 2 waves/SIMD, dir-fused) ----------
__global__ __launch_bounds__(512, 1) void k_giB(
    const int* __restrict__ toks, const void* __restrict__ embed,
    const bf16_t* __restrict__ wpk_base,   // [dir][12][40][64][8]
    const float* __restrict__ bih_base,    // [dir][768]
    const int* __restrict__ flag, bf16_t* __restrict__ gi_base,
    size_t gi_dstride, int mbase) {
  __shared__ __align__(16) bf16_t Bt[2][20480];   // 2 x 40KB
  int tid = threadIdx.x;
  int wave = tid >> 6, lane = tid & 63;
  int l16 = lane & 15, quad = lane >> 4;
  int m0 = blockIdx.x * 128;
  int dir = blockIdx.y;
  int isb = flag[0];
  const bf16_t* wpk = wpk_base + (size_t)dir * 245760;
  const float*  bih = bih_base + (size_t)dir * G3;
  bf16_t* gi = gi_base + (size_t)dir * gi_dstride;

  bf16x8 ah[10], al[10];
  {
    int tok = toks[mbase + m0 + wave * 16 + l16];
    if (isb) {
      const bf16_t* er = (const bf16_t*)embed + (size_t)tok * D_EMB;
      #pragma unroll
      for (int k0 = 0; k0 < 10; ++k0) {
        int c = k0 * 32 + quad * 8;
        bf16x8 v = {};
        if (c + 8 <= D_EMB) {
          bf16x4 t0 = *(const bf16x4*)(er + c);
          bf16x4 t1 = *(const bf16x4*)(er + c + 4);
          v[0]=t0[0]; v[1]=t0[1]; v[2]=t0[2]; v[3]=t0[3];
          v[4]=t1[0]; v[5]=t1[1]; v[6]=t1[2]; v[7]=t1[3];
        } else if (c < D_EMB) {
          bf16x4 t0 = *(const bf16x4*)(er + c);
          v[0]=t0[0]; v[1]=t0[1]; v[2]=t0[2]; v[3]=t0[3];
        }
        ah[k0] = v;
        al[k0] = (bf16x8){};
      }
    } else {
      const float* er = (const float*)embed + (size_t)tok * D_EMB;
      #pragma unroll
      for (int k0 = 0; k0 < 10; ++k0) {
        int c = k0 * 32 + quad * 8;
        float v[8];
        #pragma unroll
        for (int i = 0; i < 8; ++i) v[i] = 0.f;
        if (c + 4 <= D_EMB) { float4 t = *(const float4*)(er + c);
                              v[0]=t.x; v[1]=t.y; v[2]=t.z; v[3]=t.w; }
        if (c + 8 <= D_EMB) { float4 t = *(const float4*)(er + c + 4);
                              v[4]=t.x; v[5]=t.y; v[6]=t.z; v[7]=t.w; }
        bf16x8 h, l;
        #pragma unroll
        for (int i = 0; i < 8; ++i) {
          bf16_t hv = (bf16_t)v[i];
          h[i] = hv; l[i] = (bf16_t)(v[i] - (float)hv);
        }
        ah[k0] = h; al[k0] = l;
      }
    }
  }

  bf16x8 stg[5];
  {
    const bf16_t* base = wpk + (size_t)tid * 8;
    #pragma unroll
    for (int i = 0; i < 5; ++i) stg[i] = *(const bf16x8*)(base + i * 4096);
    bf16_t* dst = &Bt[0][tid * 8];
    #pragma unroll
    for (int i = 0; i < 5; ++i) *(bf16x8*)(dst + i * 4096) = stg[i];
  }
  __syncthreads();

  for (int n0 = 0; n0 < 12; ++n0) {
    int cur = n0 & 1;
    if (n0 + 1 < 12) {
      const bf16_t* base = wpk + (size_t)(n0 + 1) * 20480 + (size_t)tid * 8;
      #pragma unroll
      for (int i = 0; i < 5; ++i) stg[i] = *(const bf16x8*)(base + i * 4096);
    }
    f32x4 acc[4];
    #pragma unroll
    for (int j = 0; j < 4; ++j) acc[j] = (f32x4){0.f, 0.f, 0.f, 0.f};
    const bf16_t* Bc = Bt[cur];
    #pragma unroll
    for (int k0 = 0; k0 < 10; ++k0) {
      bf16x8 b[4];
      #pragma unroll
      for (int j = 0; j < 4; ++j)
        b[j] = *(const bf16x8*)&Bc[((j * 10 + k0) * 64 + lane) * 8];
      if (isb) {
        #pragma unroll
        for (int j = 0; j < 4; ++j)
          acc[j] = __builtin_amdgcn_mfma_f32_16x16x32_bf16(ah[k0], b[j], acc[j], 0, 0, 0);
      } else {
        #pragma unroll
        for (int j = 0; j < 4; ++j)
          acc[j] = __builtin_amdgcn_mfma_f32_16x16x32_bf16(al[k0], b[j], acc[j], 0, 0, 0);
        #pragma unroll
        for (int j = 0; j < 4; ++j)
          acc[j] = __builtin_amdgcn_mfma_f32_16x16x32_bf16(ah[k0], b[j], acc[j], 0, 0, 0);
      }
    }
    {
      int row0 = m0 + wave * 16 + quad * 4;
      #pragma unroll
      for (int j = 0; j < 4; ++j) {
        int col = n0 * 64 + j * 16 + l16;
        float bb = bih[col];
        #pragma unroll
        for (int rr = 0; rr < 4; ++rr)
          gi[(size_t)(row0 + rr) * G3 + col] = (bf16_t)(acc[j][rr] + bb);
      }
    }
    if (n0 + 1 < 12) {
      bf16_t* dst = &Bt[cur ^ 1][tid * 8];
      #pragma unroll
      for (int i = 0; i < 5; ++i) *(bf16x8*)(dst + i * 4096) = stg[i];
      __syncthreads();
    }
  }
}

// ---------- SGEMM device body + fused wrappers ----------
__device__ __forceinline__ void dev_sgemm(
    const float* __restrict__ A, const float* __restrict__ B,
    const float* __restrict__ bias, void* __restrict__ C,
    int M, int N, int K, int obf, int bx, int by) {
  __shared__ float As[32][65];
  __shared__ float Bs[32][65];
  int bm = bx * 64, bn = by * 64;
  int tid = threadIdx.x;
  int tx = tid & 15, ty = tid >> 4;
  float acc[4][4] = {};
  for (int k0 = 0; k0 < K; k0 += 32) {
    for (int i = tid; i < 64 * 32; i += 256) {
      int m = i >> 5, k = i & 31;
      As[k][m] = (bm + m < M) ? A[(size_t)(bm + m) * K + k0 + k] : 0.f;
    }
    for (int i = tid; i < 32 * 64; i += 256) {
      int k = i >> 6, n = i & 63;
      Bs[k][n] = B[(size_t)(k0 + k) * N + bn + n];
    }
    __syncthreads();
    #pragma unroll 8
    for (int k = 0; k < 32; ++k) {
      float a[4], b[4];
      #pragma unroll
      for (int i = 0; i < 4; ++i) a[i] = As[k][ty + i * 16];
      #pragma unroll
      for (int j = 0; j < 4; ++j) b[j] = Bs[k][tx + j * 16];
      #pragma unroll
      for (int i = 0; i < 4; ++i)
        #pragma unroll
        for (int j = 0; j < 4; ++j) acc[i][j] += a[i] * b[j];
    }
    __syncthreads();
  }
  for (int i = 0; i < 4; ++i) {
    int m = bm + ty + i * 16;
    if (m >= M) continue;
    for (int j = 0; j < 4; ++j) {
      int n = bn + tx + j * 16;
      float v = acc[i][j] + (bias ? bias[n] : 0.f);
      if (obf) ((bf16_t*)C)[(size_t)m * N + n] = (bf16_t)v;
      else     ((float*)C)[(size_t)m * N + n] = v;
    }
  }
}

// sent d0 + sent d1 + u, one dispatch: grid (16, 32)
__global__ __launch_bounds__(256) void k_sgemm_su(
    const float* __restrict__ sv, const float* __restrict__ wSt,
    const float* __restrict__ bcS, bf16_t* __restrict__ sgi,
    const float* __restrict__ wer, float* __restrict__ u) {
  int y = blockIdx.y;
  if (y < 12)
    dev_sgemm(sv, wSt, bcS, sgi, 1024, G3, H2, 1, blockIdx.x, y);
  else if (y < 24)
    dev_sgemm(sv, wSt + (size_t)H2 * G3, bcS + G3, sgi + (size_t)S_TOT * G3,
              1024, G3, H2, 1, blockIdx.x, y - 12);
  else
    dev_sgemm(sv, wer, nullptr, u, 1024, H2, H2, 0, blockIdx.x, y - 24);
}

// doc d0 + doc d1, one dispatch: grid (1, 24)
__global__ __launch_bounds__(256) void k_sgemm_d(
    const float* __restrict__ dv, const float* __restrict__ wDt,
    const float* __restrict__ bcD, bf16_t* __restrict__ dgi) {
  int y = blockIdx.y;
  if (y < 12)
    dev_sgemm(dv, wDt, bcD, dgi, 32, G3, H2, 1, 0, y);
  else
    dev_sgemm(dv, wDt + (size_t)H2 * G3, bcD + G3, dgi + (size_t)32 * G3,
              32, G3, H2, 1, 0, y - 12);
}

// ---------- GRU body (exact round-2 v2 — frozen local optimum) ----------
__device__ __forceinline__ void gru_body(
    const bf16_t* __restrict__ gi, size_t gi_dstride,
    const bf16_t* __restrict__ whhP, const float* __restrict__ bhh,
    const int* __restrict__ lens, float* __restrict__ pool,
    int T, int sbase, int nsent, int sblk) {
  int dir = blockIdx.y;
  int tid = threadIdx.x;
  int wave = tid >> 6, lane = tid & 63;
  int l16 = lane & 15, quad = lane >> 4;
  const bf16_t* giD  = gi + (size_t)dir * gi_dstride;
  const float*  bhhD = bhh + (size_t)dir * G3;

  __shared__ __align__(16) bf16_t hA[2][8][16][4][8];

  bf16x8 Bf[48];
  {
    const bf16_t* Bb = whhP + (size_t)dir * G3 * Hh + (size_t)wave * 48 * 512 + lane * 8;
    #pragma unroll
    for (int s = 0; s < 48; ++s) Bf[s] = *(const bf16x8*)(Bb + s * 512);
  }
  float bhn[2];
  #pragma unroll
  for (int jt = 0; jt < 2; ++jt)
    bhn[jt] = bhhD[2 * Hh + wave * 32 + jt * 16 + l16];
  int Lm[4];
  #pragma unroll
  for (int r = 0; r < 4; ++r) {
    int sa = sblk + quad * 4 + r;
    Lm[r] = (lens && sa < nsent) ? lens[sbase + sa] : T;
  }
  float pmax[2][4], hreg[2][4];
  #pragma unroll
  for (int jt = 0; jt < 2; ++jt)
    #pragma unroll
    for (int r = 0; r < 4; ++r) { pmax[jt][r] = -1e30f; hreg[jt][r] = 0.f; }

  int t0 = dir ? (T - 1) : 0;
  long long stepoff = dir ? -(long long)G3 : (long long)G3;
  const bf16_t* rp[4];
  #pragma unroll
  for (int r = 0; r < 4; ++r)
    rp[r] = giD + ((size_t)(sblk + quad * 4 + r) * T + t0) * (size_t)G3;

  {
    bf16_t* hz = &hA[0][0][0][0][0];
    for (int i = tid; i < 8 * 16 * 4 * 8; i += 512) hz[i] = (bf16_t)0.f;
  }

  bf16_t gv[3][2][4];
  #pragma unroll
  for (int jt = 0; jt < 2; ++jt) {
    int j = wave * 32 + jt * 16 + l16;
    #pragma unroll
    for (int r = 0; r < 4; ++r) {
      gv[0][jt][r] = rp[r][j];
      gv[1][jt][r] = rp[r][Hh + j];
      gv[2][jt][r] = rp[r][2 * Hh + j];
    }
  }
  __syncthreads();

  int cur = 0;
  for (int step = 0; step < T; ++step) {
    int t = dir ? (T - 1 - step) : step;
    f32x4 C[3][2];
    #pragma unroll
    for (int g = 0; g < 3; ++g)
      #pragma unroll
      for (int jt = 0; jt < 2; ++jt) C[g][jt] = (f32x4){0.f, 0.f, 0.f, 0.f};
    #pragma unroll
    for (int k0 = 0; k0 < 8; ++k0) {
      bf16x8 a8 = *(const bf16x8*)&hA[cur][k0][l16][quad][0];
      #pragma unroll
      for (int g = 0; g < 3; ++g)
        #pragma unroll
        for (int jt = 0; jt < 2; ++jt)
          C[g][jt] = __builtin_amdgcn_mfma_f32_16x16x32_bf16(a8, Bf[(g * 2 + jt) * 8 + k0], C[g][jt], 0, 0, 0);
    }
    #pragma unroll
    for (int jt = 0; jt < 2; ++jt) {
      int q2 = jt * 2 + (l16 >> 3);
      int ii = l16 & 7;
      #pragma unroll
      for (int r = 0; r < 4; ++r) {
        int m = quad * 4 + r;
        float hp = hreg[jt][r];
        float rr = fsigm((float)gv[0][jt][r] + C[0][jt][r]);
        float zz = fsigm((float)gv[1][jt][r] + C[1][jt][r]);
        float nn = ftanh_((float)gv[2][jt][r] + rr * (C[2][jt][r] + bhn[jt]));
        float hnew = nn + zz * (hp - nn);
        hreg[jt][r] = hnew;
        hA[cur ^ 1][wave][m][q2][ii] = (bf16_t)hnew;
        if (t < Lm[r]) pmax[jt][r] = fmaxf(pmax[jt][r], hnew);
      }
    }
    #pragma unroll
    for (int r = 0; r < 4; ++r) rp[r] += stepoff;
    if (step + 1 < T) {
      #pragma unroll
      for (int jt = 0; jt < 2; ++jt) {
        int j = wave * 32 + jt * 16 + l16;
        #pragma unroll
        for (int r = 0; r < 4; ++r) {
          gv[0][jt][r] = rp[r][j];
          gv[1][jt][r] = rp[r][Hh + j];
          gv[2][jt][r] = rp[r][2 * Hh + j];
        }
      }
    }
    asm volatile("s_waitcnt lgkmcnt(0)" ::: "memory");
    __builtin_amdgcn_s_barrier();
    cur ^= 1;
  }
  #pragma unroll
  for (int jt = 0; jt < 2; ++jt) {
    int j = wave * 32 + jt * 16 + l16;
    #pragma unroll
    for (int r = 0; r < 4; ++r) {
      int sa = sblk + quad * 4 + r;
      if (sa < nsent) {
        float v = pmax[jt][r];
        if (v < -9e29f) v = 0.f;
        pool[(size_t)(sbase + sa) * H2 + dir * Hh + j] = v;
      }
    }
  }
}

__global__ __launch_bounds__(512)
__attribute__((amdgpu_waves_per_eu(2, 2)))
void k_gruM(
    const bf16_t* __restrict__ gi, size_t gi_dstride,
    const bf16_t* __restrict__ whhP, const float* __restrict__ bhh,
    const int* __restrict__ lens, float* __restrict__ pool,
    int T, int sbase, int nsent) {
  gru_body(gi, gi_dstride, whhP, bhh, lens, pool, T, sbase, nsent, blockIdx.x * 16);
}

// fused word + event GRU: event blocks (T=4, short) fill the CUs the 128 word
// blocks leave idle -> serialized event gruM (~25us) hides under word's 115us.
__global__ __launch_bounds__(512)
__attribute__((amdgpu_waves_per_eu(2, 2)))
void k_gruM2(
    const bf16_t* __restrict__ giW, size_t strideW,
    const bf16_t* __restrict__ whhW, const float* __restrict__ bhhW,
    const int* __restrict__ lens, float* __restrict__ poolW, int nsentW,
    const bf16_t* __restrict__ giE, size_t strideE,
    const bf16_t* __restrict__ whhE, const float* __restrict__ bhhE,
    float* __restrict__ poolE, int nsentE, int wordBlocks) {
  if ((int)blockIdx.x < wordBlocks)
    gru_body(giW, strideW, whhW, bhhW, lens, poolW, 32, 0, nsentW,
             blockIdx.x * 16);
  else
    gru_body(giE, strideE, whhE, bhhE, nullptr, poolE, 4, 0, nsentE,
             (blockIdx.x - wordBlocks) * 16);
}

// ---------- fused epilogue: colsumP (48 blocks) + sal (32 blocks x 512t) ----------
__global__ __launch_bounds__(512) void k_colsal(
    const float* __restrict__ ev, float* __restrict__ part,
    const float* __restrict__ W, const float* __restrict__ blog,
    const float* __restrict__ dv, float* __restrict__ wsal) {
  int b = blockIdx.x, t = threadIdx.x;
  if (b < 48) {
    int r0 = b * 64;
    float s = 0.f;
    for (int r = 0; r < 64; ++r) s += ev[(size_t)(r0 + r) * H2 + t];
    part[(size_t)b * H2 + t] = s;
  } else {
    int doc = b - 48;
    const float* row = W + (size_t)t * (2 * H2);
    const float* dvr = dv + (size_t)doc * H2;
    float s = 0.f;
    for (int f = 0; f < H2; ++f) s += row[f] * blog[f];
    for (int f = 0; f < H2; ++f) s += row[H2 + f] * dvr[f];
    wsal[(size_t)doc * H2 + t] = s;
  }
}

// ---------- fused esum + ves (1 block, 512t) ----------
__global__ __launch_bounds__(512) void k_esumves(
    const float* __restrict__ part, const float* __restrict__ W,
    float* __restrict__ ves) {
  __shared__ float es[H2];
  int t = threadIdx.x;
  float s = 0.f;
  for (int b = 0; b < 48; ++b) s += part[(size_t)b * H2 + t];
  es[t] = s;
  __syncthreads();
  const float* row = W + (size_t)t * H2;
  float v = 0.f;
  for (int f = 0; f < H2; ++f) v += row[f] * es[f];
  ves[t] = v * (1.f / 3072.f);
}

__global__ __launch_bounds__(256) void k_eventprobs(
    const float* __restrict__ evv, const float* __restrict__ ves,
    const float* __restrict__ w_ec, const float* __restrict__ tfs,
    const float* __restrict__ st, const float* __restrict__ c_tf,
    const float* __restrict__ c_sent, const float* __restrict__ c_bias,
    const int* __restrict__ flag, float* __restrict__ probs, void* __restrict__ outp) {
  int lane = threadIdx.x & 63;
  int e = blockIdx.x * 4 + (threadIdx.x >> 6);
  const float* row = evv + (size_t)e * H2;
  float s = 0.f;
  for (int f = lane; f < H2; f += 64) s += row[f] * (w_ec[f] + ves[f]);
  #pragma unroll
  for (int o = 32; o > 0; o >>= 1) s += __shfl_down(s, o, 64);
  if (lane == 0) {
    float p = s + c_tf[0] * tfs[e] + c_bias[0] + c_sent[0] * st[e / 3];
    probs[e] = p;
    if (flag[0]) ((bf16_t*)outp)[S_TOT + e] = (bf16_t)p;
    else         ((float*)outp)[S_TOT + e] = p;
  }
}

__global__ __launch_bounds__(256) void k_sentout(
    const float* __restrict__ sv, const float* __restrict__ u,
    const float* __restrict__ evv, const float* __restrict__ probs,
    const float* __restrict__ wsal, const float* __restrict__ w_sc,
    const float* __restrict__ dpe, const float* __restrict__ spe,
    const float* __restrict__ w_sdp, const float* __restrict__ w_sp,
    const float* __restrict__ b_rel, const float* __restrict__ para,
    const float* __restrict__ sbias, const int* __restrict__ flag,
    void* __restrict__ outp) {
  int lane = threadIdx.x & 63;
  int s = blockIdx.x * 4 + (threadIdx.x >> 6);
  int doc = s >> 5, jj = s & 31;
  const float* svr = sv + (size_t)s * H2;
  const float* ur  = u + (size_t)s * H2;
  const float* wd  = wsal + (size_t)doc * H2;
  float acc = 0.f, e0 = 0.f, e1 = 0.f, e2 = 0.f;
  for (int f = lane; f < H2; f += 64) {
    float svf = svr[f], uf = ur[f];
    acc += svf * (w_sc[f] + wd[f]);
    e0 += uf * evv[(size_t)(s * 3 + 0) * H2 + f];
    e1 += uf * evv[(size_t)(s * 3 + 1) * H2 + f];
    e2 += uf * evv[(size_t)(s * 3 + 2) * H2 + f];
  }
  if (lane < 50) {
    int dpos = (doc * 40) / 32;
    int spos = (jj * 30) / 32;
    acc += dpe[dpos * 50 + lane] * w_sdp[lane] + spe[spos * 50 + lane] * w_sp[lane];
  }
  #pragma unroll
  for (int o = 32; o > 0; o >>= 1) {
    acc += __shfl_down(acc, o, 64);
    e0  += __shfl_down(e0, o, 64);
    e1  += __shfl_down(e1, o, 64);
    e2  += __shfl_down(e2, o, 64);
  }
  if (lane == 0) {
    float br = b_rel[0];
    float rel = (e0 + br) * probs[s * 3 + 0] + (e1 + br) * probs[s * 3 + 1]
              + (e2 + br) * probs[s * 3 + 2];
    float v = acc + para[0] * rel + sbias[0];
    if (flag[0]) ((bf16_t*)outp)[s] = (bf16_t)v;
    else         ((float*)outp)[s] = v;
  }
}

// ---------------- launcher ----------------
extern "C" void kernel_launch(void* const* d_in, const int* in_sizes, int n_in,
                              void* d_out, int out_size, void* d_ws, size_t ws_size,
                              hipStream_t stream) {
  (void)in_sizes; (void)n_in; (void)out_size;
  const int* x      = (const int*)d_in[0];
  const int* events = (const int*)d_in[1];
  const void* embed = d_in[8];

  char* ws = (char*)d_ws;
  size_t off = 0;
  auto alloc = [&](size_t bytes) -> void* {
    void* p = ws + off;
    off += (bytes + 255) & ~(size_t)255;
    return p;
  };

  static const int cidx[NCANON] = {9,10,11,12, 13,14,15,16, 17,18,19,20, 21,22,23,24,
                                   25,26,27,28,29,30,31, 32,33,34,35, 36,37,38,40, 5,7};
  static const int csz[NCANON]  = {2*G3*D_EMB, 2*G3*Hh, 2*G3, 2*G3,
                                   2*G3*H2,    2*G3*Hh, 2*G3, 2*G3,
                                   2*G3*H2,    2*G3*Hh, 2*G3, 2*G3,
                                   2*G3*D_EMB, 2*G3*Hh, 2*G3, 2*G3,
                                   40*50, 30*50, H2, H2*H2, 1, 1, 1,
                                   H2, H2*2*H2, 50, 50,
                                   H2*H2, 1, 1, 1, E_TOT, S_TOT};
  Canon cd;
  int tot = 0;
  for (int i = 0; i < NCANON; ++i) { cd.src[i] = d_in[cidx[i]]; cd.off[i] = tot; tot += csz[i]; }
  cd.off[NCANON] = tot;

  int*   flag  = (int*)alloc(256);
  float* canon = (float*)alloc((size_t)tot * 4);
  float* cptr[NCANON];
  for (int i = 0; i < NCANON; ++i) cptr[i] = canon + cd.off[i];
  float *cw_wih = cptr[0], *cw_whh = cptr[1], *cw_bih = cptr[2], *cw_bhh = cptr[3];
  float *cs_wih = cptr[4], *cs_whh = cptr[5], *cs_bih = cptr[6], *cs_bhh = cptr[7];
  float *cd_wih = cptr[8], *cd_whh = cptr[9], *cd_bih = cptr[10], *cd_bhh = cptr[11];
  float *ce_wih = cptr[12], *ce_whh = cptr[13], *ce_bih = cptr[14], *ce_bhh = cptr[15];
  float *c_dpe = cptr[16], *c_spe = cptr[17], *c_wec = cptr[18], *c_Wes = cptr[19];
  float *c_tf = cptr[20], *c_sent = cptr[21], *c_ebias = cptr[22];
  float *c_wsc = cptr[23], *c_Wss = cptr[24], *c_wsdp = cptr[25], *c_wsp = cptr[26];
  float *c_Wer = cptr[27], *c_brel = cptr[28], *c_para = cptr[29], *c_sbias = cptr[30];
  float *c_tfs = cptr[31], *c_starg = cptr[32];

  bf16_t* packW = (bf16_t*)alloc((size_t)2 * G3 * Hh * 2);
  bf16_t* packE = (bf16_t*)alloc((size_t)2 * G3 * Hh * 2);
  bf16_t* packS = (bf16_t*)alloc((size_t)2 * G3 * Hh * 2);
  bf16_t* packD = (bf16_t*)alloc((size_t)2 * G3 * Hh * 2);
  bf16_t* packGiW = (bf16_t*)alloc((size_t)2 * 12 * 40 * 64 * 8 * 2);
  bf16_t* packGiE = (bf16_t*)alloc((size_t)2 * 12 * 40 * 64 * 8 * 2);
  float*  bcW  = (float*)alloc((size_t)2 * G3 * 4);
  float*  bcE  = (float*)alloc((size_t)2 * G3 * 4);
  float*  bcS  = (float*)alloc((size_t)2 * G3 * 4);
  float*  bcD  = (float*)alloc((size_t)2 * G3 * 4);
  float*  sv   = (float*)alloc((size_t)S_TOT * H2 * 4);
  float*  evv  = (float*)alloc((size_t)E_TOT * H2 * 4);
  float*  dv   = (float*)alloc((size_t)32 * H2 * 4);
  float*  blog = (float*)alloc((size_t)H2 * 4);
  float*  wSt  = (float*)alloc((size_t)2 * H2 * G3 * 4);
  float*  wDt  = (float*)alloc((size_t)2 * H2 * G3 * 4);
  float*  u    = (float*)alloc((size_t)S_TOT * H2 * 4);
  float*  part = (float*)alloc((size_t)48 * H2 * 4);
  float*  ves  = (float*)alloc((size_t)H2 * 4);
  float*  wsal = (float*)alloc((size_t)32 * H2 * 4);
  float*  probs= (float*)alloc((size_t)E_TOT * 4);
  int*    lens = (int*)alloc((size_t)S_TOT * 4);
  bf16_t* sgi  = (bf16_t*)alloc((size_t)2 * S_TOT * G3 * 2);
  bf16_t* dgi  = (bf16_t*)alloc((size_t)2 * 32 * G3 * 2);

  size_t fixed = off;
  size_t avail = (ws_size > fixed) ? (ws_size - fixed) : 0;
  const size_t needW = (size_t)2 * 32768 * G3 * 2;   // word gi, both dirs
  const size_t needE = (size_t)2 * 12288 * G3 * 2;   // event gi, both dirs
  bf16_t* gib = (bf16_t*)(ws + fixed);

  PrepArgs pa;
  pa.whh[0]=cw_whh; pa.whh[1]=ce_whh; pa.whh[2]=cs_whh; pa.whh[3]=cd_whh;
  pa.pk[0]=packW; pa.pk[1]=packE; pa.pk[2]=packS; pa.pk[3]=packD;
  pa.wih2[0]=cw_wih; pa.wih2[1]=ce_wih; pa.pw2[0]=packGiW; pa.pw2[1]=packGiE;
  pa.bih4[0]=cw_bih; pa.bih4[1]=ce_bih; pa.bih4[2]=cs_bih; pa.bih4[3]=cd_bih;
  pa.bhh4[0]=cw_bhh; pa.bhh4[1]=ce_bhh; pa.bhh4[2]=cs_bhh; pa.bhh4[3]=cd_bhh;
  pa.bc4[0]=bcW; pa.bc4[1]=bcE; pa.bc4[2]=bcS; pa.bc4[3]=bcD;
  pa.tsrc[0]=cs_wih; pa.tsrc[1]=cd_wih; pa.tdst[0]=wSt; pa.tdst[1]=wDt;
  pa.x = x; pa.lens = lens;

  // ---- prep (3 launches, was 15) ----
  k_detect<<<1, 64, 0, stream>>>((const unsigned short*)embed, flag);
  k_canon<<<(tot + 255) / 256, 256, 0, stream>>>(cd, flag, canon);
  k_prep<<<2812, 256, 0, stream>>>(pa);

  if (avail >= needW + needE) {
    // ---- fused path: word+event gi coexist; event gruM hides under word ----
    bf16_t* egib = (bf16_t*)((char*)gib + ((needW + 255) & ~(size_t)255));
    k_giB<<<dim3(256, 2), 512, 0, stream>>>(x, embed, packGiW, bcW, flag,
                                            gib, (size_t)32768 * G3, 0);
    k_giB<<<dim3(96, 2), 512, 0, stream>>>(events, embed, packGiE, bcE, flag,
                                           egib, (size_t)12288 * G3, 0);
    k_gruM2<<<dim3(64 + 192, 2), 512, 0, stream>>>(
        gib, (size_t)32768 * G3, packW, cw_bhh, lens, sv, 1024,
        egib, (size_t)12288 * G3, packE, ce_bhh, evv, 3072, 64);
  } else {
    // ---- fallback: r10 chunked sequential path ----
    long long rpc = (long long)(avail / ((size_t)G3 * 2 * 2));
    rpc &= ~511LL;
    if (rpc < 512) rpc = 512;
    if (rpc > 32768) rpc = 32768;
    for (long long r0 = 0; r0 < 32768; r0 += rpc) {
      long long rows = 32768 - r0; if (rows > rpc) rows = rpc;
      k_giB<<<dim3((int)(rows / 128), 2), 512, 0, stream>>>(
          x, embed, packGiW, bcW, flag, gib, (size_t)rows * G3, (int)r0);
      k_gruM<<<dim3((int)(rows / 512), 2), 512, 0, stream>>>(
          gib, (size_t)rows * G3, packW, cw_bhh, lens, sv, 32, (int)(r0 / 32),
          (int)(rows / 32));
    }
    for (long long r0 = 0; r0 < 12288; r0 += rpc) {
      long long rows = 12288 - r0; if (rows > rpc) rows = rpc;
      k_giB<<<dim3((int)(rows / 128), 2), 512, 0, stream>>>(
          events, embed, packGiE, bcE, flag, gib, (size_t)rows * G3, (int)r0);
      k_gruM<<<dim3((int)(rows / 64), 2), 512, 0, stream>>>(
          gib, (size_t)rows * G3, packE, ce_bhh, nullptr, evv, 4, (int)(r0 / 4),
          (int)(rows / 4));
    }
  }

  // ---- sent sgemm (both dirs) + u, one dispatch ----
  k_sgemm_su<<<dim3(16, 32), 256, 0, stream>>>(sv, wSt, bcS, sgi, c_Wer, u);
  k_gruM<<<dim3(2, 2), 512, 0, stream>>>(sgi, (size_t)S_TOT * G3, packS, cs_bhh,
                                         nullptr, dv, 32, 0, 32);
  // ---- doc sgemm (both dirs), one dispatch ----
  k_sgemm_d<<<dim3(1, 24), 256, 0, stream>>>(dv, wDt, bcD, dgi);
  k_gruM<<<dim3(1, 2), 512, 0, stream>>>(dgi, (size_t)32 * G3, packD, cd_bhh,
                                         nullptr, blog, 32, 0, 1);
  // ---- epilogue ----
  k_colsal<<<80, 512, 0, stream>>>(evv, part, c_Wss, blog, dv, wsal);
  k_esumves<<<1, 512, 0, stream>>>(part, c_Wes, ves);
  k_eventprobs<<<768, 256, 0, stream>>>(evv, ves, c_wec, c_tfs, c_starg,
                                        c_tf, c_sent, c_ebias, flag, probs, d_out);
  k_sentout<<<256, 256, 0, stream>>>(sv, u, evv, probs, wsal, c_wsc, c_dpe, c_spe,
                                     c_wsdp, c_wsp, c_brel, c_para, c_sbias, flag, d_out);
}

// Round 12
// 912.985 us; speedup vs baseline: 1.6951x; 1.0652x over previous
//
#include <hip/hip_runtime.h>
#include <hip/hip_bf16.h>
#include <math.h>

typedef __bf16 bf16_t;
typedef __bf16 bf16x8 __attribute__((ext_vector_type(8)));
typedef __bf16 bf16x4 __attribute__((ext_vector_type(4)));
typedef float  f32x4  __attribute__((ext_vector_type(4)));

#define S_TOT 1024
#define T_W   32
#define D_EMB 300
#define KP    320
#define G3    768
#define Hh    256
#define H2    512
#define E_TOT 3072
#define NCANON 33

__device__ __forceinline__ float fsigm(float x) {
  float e = __builtin_amdgcn_exp2f(x * -1.4426950408889634f);
  return __builtin_amdgcn_rcpf(1.f + e);
}
__device__ __forceinline__ float ftanh_(float x) {
  float e = __builtin_amdgcn_exp2f(x * 2.8853900817779268f);
  return 1.f - 2.f * __builtin_amdgcn_rcpf(1.f + e);
}

// ---------- dtype detector ----------
__global__ void k_detect(const unsigned short* __restrict__ w, int* __restrict__ flag) {
  int lane = threadIdx.x;
  int sane = 0;
  for (int i = lane; i < 256; i += 64) {
    unsigned short v = w[2 * i];
    int ex = (v >> 7) & 0xFF;
    sane += (ex >= 96 && ex <= 134) ? 1 : 0;
  }
  #pragma unroll
  for (int o = 32; o > 0; o >>= 1) sane += __shfl_down(sane, o, 64);
  if (lane == 0) flag[0] = (sane >= 128) ? 1 : 0;
}

// ---------- canonicalize ----------
struct Canon {
  const void* src[NCANON];
  int off[NCANON + 1];
};
__global__ void k_canon(Canon c, const int* __restrict__ flag, float* __restrict__ dst) {
  int i = blockIdx.x * 256 + threadIdx.x;
  if (i >= c.off[NCANON]) return;
  int seg = 0;
  while (c.off[seg + 1] <= i) ++seg;
  int j = i - c.off[seg];
  dst[i] = flag[0] ? (float)((const bf16_t*)c.src[seg])[j]
                   : ((const float*)c.src[seg])[j];
}

// ---------- fat prep kernel ----------
struct PrepArgs {
  const float* whh[4];   bf16_t* pk[4];
  const float* wih2[2];  bf16_t* pw2[2];
  const float* bih4[4];  const float* bhh4[4]; float* bc4[4];
  const float* tsrc[2];  float* tdst[2];
  const int* x; int* lens;
};
__global__ __launch_bounds__(256) void k_prep(PrepArgs a) {
  int b = blockIdx.x, tid = threadIdx.x;
  if (b < 768) {                       // ---- packB x4 ----
    int ti = b / 192, lb = b % 192;
    int id = lb * 256 + tid;
    int lane = id & 63;
    int k0 = (id >> 6) & 7;
    int t9 = id >> 9;
    int sl = t9 % 6;
    int wb = t9 / 6;
    int wv = wb & 7;
    int dir = wb >> 3;
    int g = sl >> 1, jt = sl & 1;
    int l16 = lane & 15, quad = lane >> 4;
    int n = g * Hh + wv * 32 + jt * 16 + l16;
    const float* src = a.whh[ti] + ((size_t)dir * G3 + n) * Hh + k0 * 32 + quad * 8;
    bf16_t* dst = a.pk[ti] + (size_t)id * 8;
    #pragma unroll
    for (int i = 0; i < 8; ++i) dst[i] = (bf16_t)src[i];
  } else if (b < 1248) {               // ---- packWih x2 ----
    int ti = (b - 768) / 240, lb = (b - 768) % 240;
    int id = lb * 256 + tid;
    int lane = id & 63;
    int su = id >> 6;
    int s  = su % 40;
    int n0 = (su / 40) % 12;
    int dir = su / 480;
    int j = s / 10, k0 = s % 10;
    int l16 = lane & 15, quad = lane >> 4;
    int n = n0 * 64 + j * 16 + l16;
    int c = k0 * 32 + quad * 8;
    const float* src = a.wih2[ti] + ((size_t)dir * G3 + n) * D_EMB + c;
    bf16_t* dst = a.pw2[ti] + (size_t)id * 8;
    #pragma unroll
    for (int i = 0; i < 8; ++i)
      dst[i] = (c + i < D_EMB) ? (bf16_t)src[i] : (bf16_t)0.f;
  } else if (b < 1272) {               // ---- biasC x4 ----
    int ti = (b - 1248) / 6, lb = (b - 1248) % 6;
    int i = lb * 256 + tid;
    if (i < 2 * G3) {
      int c = i % G3;
      a.bc4[ti][i] = a.bih4[ti][i] + (c < 2 * Hh ? a.bhh4[ti][i] : 0.f);
    }
  } else if (b < 2808) {               // ---- transpose x2 ----
    __shared__ float tile[32][33];
    int lb = b - 1272;
    int which = lb / 768;
    int r = lb % 768;
    int bx = r % 24, by = (r / 24) % 16, d = r / 384;
    const float* w = a.tsrc[which];
    float* out = a.tdst[which];
    int n0 = bx * 32, k0 = by * 32;
    int tx = tid & 31, ty = tid >> 5;
    for (int i = ty; i < 32; i += 8)
      tile[i][tx] = w[((size_t)d * G3 + n0 + i) * H2 + k0 + tx];
    __syncthreads();
    for (int i = ty; i < 32; i += 8)
      out[((size_t)d * H2 + k0 + i) * G3 + n0 + tx] = tile[tx][i];
  } else {                             // ---- lens ----
    int s = (b - 2808) * 256 + tid;
    if (s < S_TOT) {
      int c = 0;
      for (int t = 0; t < T_W; ++t) c += (a.x[s * T_W + t] != 0) ? 1 : 0;
      a.lens[s] = c;
    }
  }
}

// ---------- giB device body (512t, 2 waves/SIMD, dir from blockIdx.y) ----------
__device__ __forceinline__ void gib_body(
    const int* __restrict__ toks, const void* __restrict__ embed,
    const bf16_t* __restrict__ wpk_base, const float* __restrict__ bih_base,
    const int* __restrict__ flag, bf16_t* __restrict__ gi_base,
    size_t gi_dstride, int mbase, int bx) {
  __shared__ __align__(16) bf16_t Bt[2][20480];   // 2 x 40KB
  int tid = threadIdx.x;
  int wave = tid >> 6, lane = tid & 63;
  int l16 = lane & 15, quad = lane >> 4;
  int m0 = bx * 128;
  int dir = blockIdx.y;
  int isb = flag[0];
  const bf16_t* wpk = wpk_base + (size_t)dir * 245760;
  const float*  bih = bih_base + (size_t)dir * G3;
  bf16_t* gi = gi_base + (size_t)dir * gi_dstride;

  bf16x8 ah[10], al[10];
  {
    int tok = toks[mbase + m0 + wave * 16 + l16];
    if (isb) {
      const bf16_t* er = (const bf16_t*)embed + (size_t)tok * D_EMB;
      #pragma unroll
      for (int k0 = 0; k0 < 10; ++k0) {
        int c = k0 * 32 + quad * 8;
        bf16x8 v = {};
        if (c + 8 <= D_EMB) {
          bf16x4 t0 = *(const bf16x4*)(er + c);
          bf16x4 t1 = *(const bf16x4*)(er + c + 4);
          v[0]=t0[0]; v[1]=t0[1]; v[2]=t0[2]; v[3]=t0[3];
          v[4]=t1[0]; v[5]=t1[1]; v[6]=t1[2]; v[7]=t1[3];
        } else if (c < D_EMB) {
          bf16x4 t0 = *(const bf16x4*)(er + c);
          v[0]=t0[0]; v[1]=t0[1]; v[2]=t0[2]; v[3]=t0[3];
        }
        ah[k0] = v;
        al[k0] = (bf16x8){};
      }
    } else {
      const float* er = (const float*)embed + (size_t)tok * D_EMB;
      #pragma unroll
      for (int k0 = 0; k0 < 10; ++k0) {
        int c = k0 * 32 + quad * 8;
        float v[8];
        #pragma unroll
        for (int i = 0; i < 8; ++i) v[i] = 0.f;
        if (c + 4 <= D_EMB) { float4 t = *(const float4*)(er + c);
                              v[0]=t.x; v[1]=t.y; v[2]=t.z; v[3]=t.w; }
        if (c + 8 <= D_EMB) { float4 t = *(const float4*)(er + c + 4);
                              v[4]=t.x; v[5]=t.y; v[6]=t.z; v[7]=t.w; }
        bf16x8 h, l;
        #pragma unroll
        for (int i = 0; i < 8; ++i) {
          bf16_t hv = (bf16_t)v[i];
          h[i] = hv; l[i] = (bf16_t)(v[i] - (float)hv);
        }
        ah[k0] = h; al[k0] = l;
      }
    }
  }

  bf16x8 stg[5];
  {
    const bf16_t* base = wpk + (size_t)tid * 8;
    #pragma unroll
    for (int i = 0; i < 5; ++i) stg[i] = *(const bf16x8*)(base + i * 4096);
    bf16_t* dst = &Bt[0][tid * 8];
    #pragma unroll
    for (int i = 0; i < 5; ++i) *(bf16x8*)(dst + i * 4096) = stg[i];
  }
  __syncthreads();

  for (int n0 = 0; n0 < 12; ++n0) {
    int cur = n0 & 1;
    if (n0 + 1 < 12) {
      const bf16_t* base = wpk + (size_t)(n0 + 1) * 20480 + (size_t)tid * 8;
      #pragma unroll
      for (int i = 0; i < 5; ++i) stg[i] = *(const bf16x8*)(base + i * 4096);
    }
    f32x4 acc[4];
    #pragma unroll
    for (int j = 0; j < 4; ++j) acc[j] = (f32x4){0.f, 0.f, 0.f, 0.f};
    const bf16_t* Bc = Bt[cur];
    #pragma unroll
    for (int k0 = 0; k0 < 10; ++k0) {
      bf16x8 b[4];
      #pragma unroll
      for (int j = 0; j < 4; ++j)
        b[j] = *(const bf16x8*)&Bc[((j * 10 + k0) * 64 + lane) * 8];
      if (isb) {
        #pragma unroll
        for (int j = 0; j < 4; ++j)
          acc[j] = __builtin_amdgcn_mfma_f32_16x16x32_bf16(ah[k0], b[j], acc[j], 0, 0, 0);
      } else {
        #pragma unroll
        for (int j = 0; j < 4; ++j)
          acc[j] = __builtin_amdgcn_mfma_f32_16x16x32_bf16(al[k0], b[j], acc[j], 0, 0, 0);
        #pragma unroll
        for (int j = 0; j < 4; ++j)
          acc[j] = __builtin_amdgcn_mfma_f32_16x16x32_bf16(ah[k0], b[j], acc[j], 0, 0, 0);
      }
    }
    {
      int row0 = m0 + wave * 16 + quad * 4;
      #pragma unroll
      for (int j = 0; j < 4; ++j) {
        int col = n0 * 64 + j * 16 + l16;
        float bb = bih[col];
        #pragma unroll
        for (int rr = 0; rr < 4; ++rr)
          gi[(size_t)(row0 + rr) * G3 + col] = (bf16_t)(acc[j][rr] + bb);
      }
    }
    if (n0 + 1 < 12) {
      bf16_t* dst = &Bt[cur ^ 1][tid * 8];
      #pragma unroll
      for (int i = 0; i < 5; ++i) *(bf16x8*)(dst + i * 4096) = stg[i];
      __syncthreads();
    }
  }
}

__global__ __launch_bounds__(512, 1) void k_giB(
    const int* __restrict__ toks, const void* __restrict__ embed,
    const bf16_t* __restrict__ wpk_base, const float* __restrict__ bih_base,
    const int* __restrict__ flag, bf16_t* __restrict__ gi_base,
    size_t gi_dstride, int mbase) {
  gib_body(toks, embed, wpk_base, bih_base, flag, gi_base, gi_dstride, mbase,
           blockIdx.x);
}

// ---------- SGEMM device body + fused wrappers ----------
__device__ __forceinline__ void dev_sgemm(
    const float* __restrict__ A, const float* __restrict__ B,
    const float* __restrict__ bias, void* __restrict__ C,
    int M, int N, int K, int obf, int bx, int by) {
  __shared__ float As[32][65];
  __shared__ float Bs[32][65];
  int bm = bx * 64, bn = by * 64;
  int tid = threadIdx.x;
  int tx = tid & 15, ty = tid >> 4;
  float acc[4][4] = {};
  for (int k0 = 0; k0 < K; k0 += 32) {
    for (int i = tid; i < 64 * 32; i += 256) {
      int m = i >> 5, k = i & 31;
      As[k][m] = (bm + m < M) ? A[(size_t)(bm + m) * K + k0 + k] : 0.f;
    }
    for (int i = tid; i < 32 * 64; i += 256) {
      int k = i >> 6, n = i & 63;
      Bs[k][n] = B[(size_t)(k0 + k) * N + bn + n];
    }
    __syncthreads();
    #pragma unroll 8
    for (int k = 0; k < 32; ++k) {
      float a[4], b[4];
      #pragma unroll
      for (int i = 0; i < 4; ++i) a[i] = As[k][ty + i * 16];
      #pragma unroll
      for (int j = 0; j < 4; ++j) b[j] = Bs[k][tx + j * 16];
      #pragma unroll
      for (int i = 0; i < 4; ++i)
        #pragma unroll
        for (int j = 0; j < 4; ++j) acc[i][j] += a[i] * b[j];
    }
    __syncthreads();
  }
  for (int i = 0; i < 4; ++i) {
    int m = bm + ty + i * 16;
    if (m >= M) continue;
    for (int j = 0; j < 4; ++j) {
      int n = bn + tx + j * 16;
      float v = acc[i][j] + (bias ? bias[n] : 0.f);
      if (obf) ((bf16_t*)C)[(size_t)m * N + n] = (bf16_t)v;
      else     ((float*)C)[(size_t)m * N + n] = v;
    }
  }
}

__global__ __launch_bounds__(256) void k_sgemm_su(
    const float* __restrict__ sv, const float* __restrict__ wSt,
    const float* __restrict__ bcS, bf16_t* __restrict__ sgi,
    const float* __restrict__ wer, float* __restrict__ u) {
  int y = blockIdx.y;
  if (y < 12)
    dev_sgemm(sv, wSt, bcS, sgi, 1024, G3, H2, 1, blockIdx.x, y);
  else if (y < 24)
    dev_sgemm(sv, wSt + (size_t)H2 * G3, bcS + G3, sgi + (size_t)S_TOT * G3,
              1024, G3, H2, 1, blockIdx.x, y - 12);
  else
    dev_sgemm(sv, wer, nullptr, u, 1024, H2, H2, 0, blockIdx.x, y - 24);
}

__global__ __launch_bounds__(256) void k_sgemm_d(
    const float* __restrict__ dv, const float* __restrict__ wDt,
    const float* __restrict__ bcD, bf16_t* __restrict__ dgi) {
  int y = blockIdx.y;
  if (y < 12)
    dev_sgemm(dv, wDt, bcD, dgi, 32, G3, H2, 1, 0, y);
  else
    dev_sgemm(dv, wDt + (size_t)H2 * G3, bcD + G3, dgi + (size_t)32 * G3,
              32, G3, H2, 1, 0, y - 12);
}

// ---------- GRU body (exact round-2 v2 — frozen local optimum) ----------
__device__ __forceinline__ void gru_body(
    const bf16_t* __restrict__ gi, size_t gi_dstride,
    const bf16_t* __restrict__ whhP, const float* __restrict__ bhh,
    const int* __restrict__ lens, float* __restrict__ pool,
    int T, int sbase, int nsent, int sblk) {
  int dir = blockIdx.y;
  int tid = threadIdx.x;
  int wave = tid >> 6, lane = tid & 63;
  int l16 = lane & 15, quad = lane >> 4;
  const bf16_t* giD  = gi + (size_t)dir * gi_dstride;
  const float*  bhhD = bhh + (size_t)dir * G3;

  __shared__ __align__(16) bf16_t hA[2][8][16][4][8];

  bf16x8 Bf[48];
  {
    const bf16_t* Bb = whhP + (size_t)dir * G3 * Hh + (size_t)wave * 48 * 512 + lane * 8;
    #pragma unroll
    for (int s = 0; s < 48; ++s) Bf[s] = *(const bf16x8*)(Bb + s * 512);
  }
  float bhn[2];
  #pragma unroll
  for (int jt = 0; jt < 2; ++jt)
    bhn[jt] = bhhD[2 * Hh + wave * 32 + jt * 16 + l16];
  int Lm[4];
  #pragma unroll
  for (int r = 0; r < 4; ++r) {
    int sa = sblk + quad * 4 + r;
    Lm[r] = (lens && sa < nsent) ? lens[sbase + sa] : T;
  }
  float pmax[2][4], hreg[2][4];
  #pragma unroll
  for (int jt = 0; jt < 2; ++jt)
    #pragma unroll
    for (int r = 0; r < 4; ++r) { pmax[jt][r] = -1e30f; hreg[jt][r] = 0.f; }

  int t0 = dir ? (T - 1) : 0;
  long long stepoff = dir ? -(long long)G3 : (long long)G3;
  const bf16_t* rp[4];
  #pragma unroll
  for (int r = 0; r < 4; ++r)
    rp[r] = giD + ((size_t)(sblk + quad * 4 + r) * T + t0) * (size_t)G3;

  {
    bf16_t* hz = &hA[0][0][0][0][0];
    for (int i = tid; i < 8 * 16 * 4 * 8; i += 512) hz[i] = (bf16_t)0.f;
  }

  bf16_t gv[3][2][4];
  #pragma unroll
  for (int jt = 0; jt < 2; ++jt) {
    int j = wave * 32 + jt * 16 + l16;
    #pragma unroll
    for (int r = 0; r < 4; ++r) {
      gv[0][jt][r] = rp[r][j];
      gv[1][jt][r] = rp[r][Hh + j];
      gv[2][jt][r] = rp[r][2 * Hh + j];
    }
  }
  __syncthreads();

  int cur = 0;
  for (int step = 0; step < T; ++step) {
    int t = dir ? (T - 1 - step) : step;
    f32x4 C[3][2];
    #pragma unroll
    for (int g = 0; g < 3; ++g)
      #pragma unroll
      for (int jt = 0; jt < 2; ++jt) C[g][jt] = (f32x4){0.f, 0.f, 0.f, 0.f};
    #pragma unroll
    for (int k0 = 0; k0 < 8; ++k0) {
      bf16x8 a8 = *(const bf16x8*)&hA[cur][k0][l16][quad][0];
      #pragma unroll
      for (int g = 0; g < 3; ++g)
        #pragma unroll
        for (int jt = 0; jt < 2; ++jt)
          C[g][jt] = __builtin_amdgcn_mfma_f32_16x16x32_bf16(a8, Bf[(g * 2 + jt) * 8 + k0], C[g][jt], 0, 0, 0);
    }
    #pragma unroll
    for (int jt = 0; jt < 2; ++jt) {
      int q2 = jt * 2 + (l16 >> 3);
      int ii = l16 & 7;
      #pragma unroll
      for (int r = 0; r < 4; ++r) {
        int m = quad * 4 + r;
        float hp = hreg[jt][r];
        float rr = fsigm((float)gv[0][jt][r] + C[0][jt][r]);
        float zz = fsigm((float)gv[1][jt][r] + C[1][jt][r]);
        float nn = ftanh_((float)gv[2][jt][r] + rr * (C[2][jt][r] + bhn[jt]));
        float hnew = nn + zz * (hp - nn);
        hreg[jt][r] = hnew;
        hA[cur ^ 1][wave][m][q2][ii] = (bf16_t)hnew;
        if (t < Lm[r]) pmax[jt][r] = fmaxf(pmax[jt][r], hnew);
      }
    }
    #pragma unroll
    for (int r = 0; r < 4; ++r) rp[r] += stepoff;
    if (step + 1 < T) {
      #pragma unroll
      for (int jt = 0; jt < 2; ++jt) {
        int j = wave * 32 + jt * 16 + l16;
        #pragma unroll
        for (int r = 0; r < 4; ++r) {
          gv[0][jt][r] = rp[r][j];
          gv[1][jt][r] = rp[r][Hh + j];
          gv[2][jt][r] = rp[r][2 * Hh + j];
        }
      }
    }
    asm volatile("s_waitcnt lgkmcnt(0)" ::: "memory");
    __builtin_amdgcn_s_barrier();
    cur ^= 1;
  }
  #pragma unroll
  for (int jt = 0; jt < 2; ++jt) {
    int j = wave * 32 + jt * 16 + l16;
    #pragma unroll
    for (int r = 0; r < 4; ++r) {
      int sa = sblk + quad * 4 + r;
      if (sa < nsent) {
        float v = pmax[jt][r];
        if (v < -9e29f) v = 0.f;
        pool[(size_t)(sbase + sa) * H2 + dir * Hh + j] = v;
      }
    }
  }
}

__global__ __launch_bounds__(512)
__attribute__((amdgpu_waves_per_eu(2, 2)))
void k_gruM(
    const bf16_t* __restrict__ gi, size_t gi_dstride,
    const bf16_t* __restrict__ whhP, const float* __restrict__ bhh,
    const int* __restrict__ lens, float* __restrict__ pool,
    int T, int sbase, int nsent) {
  gru_body(gi, gi_dstride, whhP, bhh, lens, pool, T, sbase, nsent, blockIdx.x * 16);
}

// ---------- fused [word gruM || event giB] ----------
// r11 lesson: fusing word+event GRUs co-resided them on CUs (both 16KB LDS)
// and stretched word's serial chain 115->168. Here the filler is event giB:
// combined static LDS = Bt 80KB + hA 16KB = 96KB forces 1 block/CU -> word
// blocks own their CUs uncontended; the 192 giB blocks fill the other 128 CUs
// and finish (~40-60us) under word's 115us shadow.
__global__ __launch_bounds__(512)
__attribute__((amdgpu_waves_per_eu(2, 2)))
void k_wg(
    const bf16_t* __restrict__ giW, size_t strideW,
    const bf16_t* __restrict__ whhW, const float* __restrict__ bhhW,
    const int* __restrict__ lens, float* __restrict__ poolW,
    const int* __restrict__ etoks, const void* __restrict__ embed,
    const bf16_t* __restrict__ wpkE, const float* __restrict__ bihE,
    const int* __restrict__ flag, bf16_t* __restrict__ giE, size_t strideE) {
  if ((int)blockIdx.x < 64)
    gru_body(giW, strideW, whhW, bhhW, lens, poolW, 32, 0, 1024,
             blockIdx.x * 16);
  else
    gib_body(etoks, embed, wpkE, bihE, flag, giE, strideE, 0,
             blockIdx.x - 64);
}

// ---------- fused epilogue: colsumP (48 blocks) + sal (32 blocks x 512t) ----------
__global__ __launch_bounds__(512) void k_colsal(
    const float* __restrict__ ev, float* __restrict__ part,
    const float* __restrict__ W, const float* __restrict__ blog,
    const float* __restrict__ dv, float* __restrict__ wsal) {
  int b = blockIdx.x, t = threadIdx.x;
  if (b < 48) {
    int r0 = b * 64;
    float s = 0.f;
    for (int r = 0; r < 64; ++r) s += ev[(size_t)(r0 + r) * H2 + t];
    part[(size_t)b * H2 + t] = s;
  } else {
    int doc = b - 48;
    const float* row = W + (size_t)t * (2 * H2);
    const float* dvr = dv + (size_t)doc * H2;
    float s = 0.f;
    for (int f = 0; f < H2; ++f) s += row[f] * blog[f];
    for (int f = 0; f < H2; ++f) s += row[H2 + f] * dvr[f];
    wsal[(size_t)doc * H2 + t] = s;
  }
}

// ---------- fused esum + ves (1 block, 512t) ----------
__global__ __launch_bounds__(512) void k_esumves(
    const float* __restrict__ part, const float* __restrict__ W,
    float* __restrict__ ves) {
  __shared__ float es[H2];
  int t = threadIdx.x;
  float s = 0.f;
  for (int b = 0; b < 48; ++b) s += part[(size_t)b * H2 + t];
  es[t] = s;
  __syncthreads();
  const float* row = W + (size_t)t * H2;
  float v = 0.f;
  for (int f = 0; f < H2; ++f) v += row[f] * es[f];
  ves[t] = v * (1.f / 3072.f);
}

__global__ __launch_bounds__(256) void k_eventprobs(
    const float* __restrict__ evv, const float* __restrict__ ves,
    const float* __restrict__ w_ec, const float* __restrict__ tfs,
    const float* __restrict__ st, const float* __restrict__ c_tf,
    const float* __restrict__ c_sent, const float* __restrict__ c_bias,
    const int* __restrict__ flag, float* __restrict__ probs, void* __restrict__ outp) {
  int lane = threadIdx.x & 63;
  int e = blockIdx.x * 4 + (threadIdx.x >> 6);
  const float* row = evv + (size_t)e * H2;
  float s = 0.f;
  for (int f = lane; f < H2; f += 64) s += row[f] * (w_ec[f] + ves[f]);
  #pragma unroll
  for (int o = 32; o > 0; o >>= 1) s += __shfl_down(s, o, 64);
  if (lane == 0) {
    float p = s + c_tf[0] * tfs[e] + c_bias[0] + c_sent[0] * st[e / 3];
    probs[e] = p;
    if (flag[0]) ((bf16_t*)outp)[S_TOT + e] = (bf16_t)p;
    else         ((float*)outp)[S_TOT + e] = p;
  }
}

__global__ __launch_bounds__(256) void k_sentout(
    const float* __restrict__ sv, const float* __restrict__ u,
    const float* __restrict__ evv, const float* __restrict__ probs,
    const float* __restrict__ wsal, const float* __restrict__ w_sc,
    const float* __restrict__ dpe, const float* __restrict__ spe,
    const float* __restrict__ w_sdp, const float* __restrict__ w_sp,
    const float* __restrict__ b_rel, const float* __restrict__ para,
    const float* __restrict__ sbias, const int* __restrict__ flag,
    void* __restrict__ outp) {
  int lane = threadIdx.x & 63;
  int s = blockIdx.x * 4 + (threadIdx.x >> 6);
  int doc = s >> 5, jj = s & 31;
  const float* svr = sv + (size_t)s * H2;
  const float* ur  = u + (size_t)s * H2;
  const float* wd  = wsal + (size_t)doc * H2;
  float acc = 0.f, e0 = 0.f, e1 = 0.f, e2 = 0.f;
  for (int f = lane; f < H2; f += 64) {
    float svf = svr[f], uf = ur[f];
    acc += svf * (w_sc[f] + wd[f]);
    e0 += uf * evv[(size_t)(s * 3 + 0) * H2 + f];
    e1 += uf * evv[(size_t)(s * 3 + 1) * H2 + f];
    e2 += uf * evv[(size_t)(s * 3 + 2) * H2 + f];
  }
  if (lane < 50) {
    int dpos = (doc * 40) / 32;
    int spos = (jj * 30) / 32;
    acc += dpe[dpos * 50 + lane] * w_sdp[lane] + spe[spos * 50 + lane] * w_sp[lane];
  }
  #pragma unroll
  for (int o = 32; o > 0; o >>= 1) {
    acc += __shfl_down(acc, o, 64);
    e0  += __shfl_down(e0, o, 64);
    e1  += __shfl_down(e1, o, 64);
    e2  += __shfl_down(e2, o, 64);
  }
  if (lane == 0) {
    float br = b_rel[0];
    float rel = (e0 + br) * probs[s * 3 + 0] + (e1 + br) * probs[s * 3 + 1]
              + (e2 + br) * probs[s * 3 + 2];
    float v = acc + para[0] * rel + sbias[0];
    if (flag[0]) ((bf16_t*)outp)[s] = (bf16_t)v;
    else         ((float*)outp)[s] = v;
  }
}

// ---------------- launcher ----------------
extern "C" void kernel_launch(void* const* d_in, const int* in_sizes, int n_in,
                              void* d_out, int out_size, void* d_ws, size_t ws_size,
                              hipStream_t stream) {
  (void)in_sizes; (void)n_in; (void)out_size;
  const int* x      = (const int*)d_in[0];
  const int* events = (const int*)d_in[1];
  const void* embed = d_in[8];

  char* ws = (char*)d_ws;
  size_t off = 0;
  auto alloc = [&](size_t bytes) -> void* {
    void* p = ws + off;
    off += (bytes + 255) & ~(size_t)255;
    return p;
  };

  static const int cidx[NCANON] = {9,10,11,12, 13,14,15,16, 17,18,19,20, 21,22,23,24,
                                   25,26,27,28,29,30,31, 32,33,34,35, 36,37,38,40, 5,7};
  static const int csz[NCANON]  = {2*G3*D_EMB, 2*G3*Hh, 2*G3, 2*G3,
                                   2*G3*H2,    2*G3*Hh, 2*G3, 2*G3,
                                   2*G3*H2,    2*G3*Hh, 2*G3, 2*G3,
                                   2*G3*D_EMB, 2*G3*Hh, 2*G3, 2*G3,
                                   40*50, 30*50, H2, H2*H2, 1, 1, 1,
                                   H2, H2*2*H2, 50, 50,
                                   H2*H2, 1, 1, 1, E_TOT, S_TOT};
  Canon cd;
  int tot = 0;
  for (int i = 0; i < NCANON; ++i) { cd.src[i] = d_in[cidx[i]]; cd.off[i] = tot; tot += csz[i]; }
  cd.off[NCANON] = tot;

  int*   flag  = (int*)alloc(256);
  float* canon = (float*)alloc((size_t)tot * 4);
  float* cptr[NCANON];
  for (int i = 0; i < NCANON; ++i) cptr[i] = canon + cd.off[i];
  float *cw_wih = cptr[0], *cw_whh = cptr[1], *cw_bih = cptr[2], *cw_bhh = cptr[3];
  float *cs_wih = cptr[4], *cs_whh = cptr[5], *cs_bih = cptr[6], *cs_bhh = cptr[7];
  float *cd_wih = cptr[8], *cd_whh = cptr[9], *cd_bih = cptr[10], *cd_bhh = cptr[11];
  float *ce_wih = cptr[12], *ce_whh = cptr[13], *ce_bih = cptr[14], *ce_bhh = cptr[15];
  float *c_dpe = cptr[16], *c_spe = cptr[17], *c_wec = cptr[18], *c_Wes = cptr[19];
  float *c_tf = cptr[20], *c_sent = cptr[21], *c_ebias = cptr[22];
  float *c_wsc = cptr[23], *c_Wss = cptr[24], *c_wsdp = cptr[25], *c_wsp = cptr[26];
  float *c_Wer = cptr[27], *c_brel = cptr[28], *c_para = cptr[29], *c_sbias = cptr[30];
  float *c_tfs = cptr[31], *c_starg = cptr[32];

  bf16_t* packW = (bf16_t*)alloc((size_t)2 * G3 * Hh * 2);
  bf16_t* packE = (bf16_t*)alloc((size_t)2 * G3 * Hh * 2);
  bf16_t* packS = (bf16_t*)alloc((size_t)2 * G3 * Hh * 2);
  bf16_t* packD = (bf16_t*)alloc((size_t)2 * G3 * Hh * 2);
  bf16_t* packGiW = (bf16_t*)alloc((size_t)2 * 12 * 40 * 64 * 8 * 2);
  bf16_t* packGiE = (bf16_t*)alloc((size_t)2 * 12 * 40 * 64 * 8 * 2);
  float*  bcW  = (float*)alloc((size_t)2 * G3 * 4);
  float*  bcE  = (float*)alloc((size_t)2 * G3 * 4);
  float*  bcS  = (float*)alloc((size_t)2 * G3 * 4);
  float*  bcD  = (float*)alloc((size_t)2 * G3 * 4);
  float*  sv   = (float*)alloc((size_t)S_TOT * H2 * 4);
  float*  evv  = (float*)alloc((size_t)E_TOT * H2 * 4);
  float*  dv   = (float*)alloc((size_t)32 * H2 * 4);
  float*  blog = (float*)alloc((size_t)H2 * 4);
  float*  wSt  = (float*)alloc((size_t)2 * H2 * G3 * 4);
  float*  wDt  = (float*)alloc((size_t)2 * H2 * G3 * 4);
  float*  u    = (float*)alloc((size_t)S_TOT * H2 * 4);
  float*  part = (float*)alloc((size_t)48 * H2 * 4);
  float*  ves  = (float*)alloc((size_t)H2 * 4);
  float*  wsal = (float*)alloc((size_t)32 * H2 * 4);
  float*  probs= (float*)alloc((size_t)E_TOT * 4);
  int*    lens = (int*)alloc((size_t)S_TOT * 4);
  bf16_t* sgi  = (bf16_t*)alloc((size_t)2 * S_TOT * G3 * 2);
  bf16_t* dgi  = (bf16_t*)alloc((size_t)2 * 32 * G3 * 2);

  size_t fixed = off;
  size_t avail = (ws_size > fixed) ? (ws_size - fixed) : 0;
  const size_t needW = (size_t)2 * 32768 * G3 * 2;   // word gi, both dirs
  const size_t needE = (size_t)2 * 12288 * G3 * 2;   // event gi, both dirs
  bf16_t* gib = (bf16_t*)(ws + fixed);

  PrepArgs pa;
  pa.whh[0]=cw_whh; pa.whh[1]=ce_whh; pa.whh[2]=cs_whh; pa.whh[3]=cd_whh;
  pa.pk[0]=packW; pa.pk[1]=packE; pa.pk[2]=packS; pa.pk[3]=packD;
  pa.wih2[0]=cw_wih; pa.wih2[1]=ce_wih; pa.pw2[0]=packGiW; pa.pw2[1]=packGiE;
  pa.bih4[0]=cw_bih; pa.bih4[1]=ce_bih; pa.bih4[2]=cs_bih; pa.bih4[3]=cd_bih;
  pa.bhh4[0]=cw_bhh; pa.bhh4[1]=ce_bhh; pa.bhh4[2]=cs_bhh; pa.bhh4[3]=cd_bhh;
  pa.bc4[0]=bcW; pa.bc4[1]=bcE; pa.bc4[2]=bcS; pa.bc4[3]=bcD;
  pa.tsrc[0]=cs_wih; pa.tsrc[1]=cd_wih; pa.tdst[0]=wSt; pa.tdst[1]=wDt;
  pa.x = x; pa.lens = lens;

  // ---- prep ----
  k_detect<<<1, 64, 0, stream>>>((const unsigned short*)embed, flag);
  k_canon<<<(tot + 255) / 256, 256, 0, stream>>>(cd, flag, canon);
  k_prep<<<2812, 256, 0, stream>>>(pa);

  if (avail >= needW + needE) {
    // giB_w -> [gruM_w || giB_e] -> gruM_e
    bf16_t* egib = (bf16_t*)((char*)gib + ((needW + 255) & ~(size_t)255));
    k_giB<<<dim3(256, 2), 512, 0, stream>>>(x, embed, packGiW, bcW, flag,
                                            gib, (size_t)32768 * G3, 0);
    k_wg<<<dim3(64 + 96, 2), 512, 0, stream>>>(
        gib, (size_t)32768 * G3, packW, cw_bhh, lens, sv,
        events, embed, packGiE, bcE, flag, egib, (size_t)12288 * G3);
    k_gruM<<<dim3(192, 2), 512, 0, stream>>>(
        egib, (size_t)12288 * G3, packE, ce_bhh, nullptr, evv, 4, 0, 3072);
  } else {
    // ---- fallback: chunked sequential path ----
    long long rpc = (long long)(avail / ((size_t)G3 * 2 * 2));
    rpc &= ~511LL;
    if (rpc < 512) rpc = 512;
    if (rpc > 32768) rpc = 32768;
    for (long long r0 = 0; r0 < 32768; r0 += rpc) {
      long long rows = 32768 - r0; if (rows > rpc) rows = rpc;
      k_giB<<<dim3((int)(rows / 128), 2), 512, 0, stream>>>(
          x, embed, packGiW, bcW, flag, gib, (size_t)rows * G3, (int)r0);
      k_gruM<<<dim3((int)(rows / 512), 2), 512, 0, stream>>>(
          gib, (size_t)rows * G3, packW, cw_bhh, lens, sv, 32, (int)(r0 / 32),
          (int)(rows / 32));
    }
    for (long long r0 = 0; r0 < 12288; r0 += rpc) {
      long long rows = 12288 - r0; if (rows > rpc) rows = rpc;
      k_giB<<<dim3((int)(rows / 128), 2), 512, 0, stream>>>(
          events, embed, packGiE, bcE, flag, gib, (size_t)rows * G3, (int)r0);
      k_gruM<<<dim3((int)(rows / 64), 2), 512, 0, stream>>>(
          gib, (size_t)rows * G3, packE, ce_bhh, nullptr, evv, 4, (int)(r0 / 4),
          (int)(rows / 4));
    }
  }

  // ---- sent sgemm (both dirs) + u, one dispatch ----
  k_sgemm_su<<<dim3(16, 32), 256, 0, stream>>>(sv, wSt, bcS, sgi, c_Wer, u);
  k_gruM<<<dim3(2, 2), 512, 0, stream>>>(sgi, (size_t)S_TOT * G3, packS, cs_bhh,
                                         nullptr, dv, 32, 0, 32);
  // ---- doc sgemm (both dirs), one dispatch ----
  k_sgemm_d<<<dim3(1, 24), 256, 0, stream>>>(dv, wDt, bcD, dgi);
  k_gruM<<<dim3(1, 2), 512, 0, stream>>>(dgi, (size_t)32 * G3, packD, cd_bhh,
                                         nullptr, blog, 32, 0, 1);
  // ---- epilogue ----
  k_colsal<<<80, 512, 0, stream>>>(evv, part, c_Wss, blog, dv, wsal);
  k_esumves<<<1, 512, 0, stream>>>(part, c_Wes, ves);
  k_eventprobs<<<768, 256, 0, stream>>>(evv, ves, c_wec, c_tfs, c_starg,
                                        c_tf, c_sent, c_ebias, flag, probs, d_out);
  k_sentout<<<256, 256, 0, stream>>>(sv, u, evv, probs, wsal, c_wsc, c_dpe, c_spe,
                                     c_wsdp, c_wsp, c_brel, c_para, c_sbias, flag, d_out);
}

// Round 13
// 865.574 us; speedup vs baseline: 1.7880x; 1.0548x over previous
//
#include <hip/hip_runtime.h>
#include <hip/hip_bf16.h>
#include <math.h>

typedef __bf16 bf16_t;
typedef __bf16 bf16x8 __attribute__((ext_vector_type(8)));
typedef __bf16 bf16x4 __attribute__((ext_vector_type(4)));
typedef float  f32x4  __attribute__((ext_vector_type(4)));

#define S_TOT 1024
#define T_W   32
#define D_EMB 300
#define G3    768
#define Hh    256
#define H2    512
#define E_TOT 3072
#define NC2   21

__device__ __forceinline__ float fsigm(float x) {
  float e = __builtin_amdgcn_exp2f(x * -1.4426950408889634f);
  return __builtin_amdgcn_rcpf(1.f + e);
}
__device__ __forceinline__ float ftanh_(float x) {
  float e = __builtin_amdgcn_exp2f(x * 2.8853900817779268f);
  return 1.f - 2.f * __builtin_amdgcn_rcpf(1.f + e);
}
// raw-weight load with dtype dispatch (bf16 roundtrip is exact)
__device__ __forceinline__ float ldf(const void* p, size_t i, int isb) {
  return isb ? (float)((const bf16_t*)p)[i] : ((const float*)p)[i];
}

// ---------- dtype detector ----------
__global__ void k_detect(const unsigned short* __restrict__ w, int* __restrict__ flag) {
  int lane = threadIdx.x;
  int sane = 0;
  for (int i = lane; i < 256; i += 64) {
    unsigned short v = w[2 * i];
    int ex = (v >> 7) & 0xFF;
    sane += (ex >= 96 && ex <= 134) ? 1 : 0;
  }
  #pragma unroll
  for (int o = 32; o > 0; o >>= 1) sane += __shfl_down(sane, o, 64);
  if (lane == 0) flag[0] = (sane >= 128) ? 1 : 0;
}

// ---------- mega prep: packB x4, packWih x2, biasC x4, transpose x2, lens, canon ----------
struct Canon {
  const void* src[NC2];
  int off[NC2 + 1];
};
struct PrepArgs {
  const void* whhR[4];  bf16_t* pk[4];
  const void* wihR[2];  bf16_t* pw2[2];
  const void* bihR[4];  const void* bhhR[4]; float* bc4[4];
  const void* tsrcR[2]; float* tdst[2];
  const int* x; int* lens;
  const int* flag;
  Canon c; float* canon_dst; int tot2;
};
__global__ __launch_bounds__(256) void k_prepAll(PrepArgs a) {
  int b = blockIdx.x, tid = threadIdx.x;
  int isb = a.flag[0];
  if (b < 768) {                       // ---- packB x4 (raw whh) ----
    int ti = b / 192, lb = b % 192;
    int id = lb * 256 + tid;
    int lane = id & 63;
    int k0 = (id >> 6) & 7;
    int t9 = id >> 9;
    int sl = t9 % 6;
    int wb = t9 / 6;
    int wv = wb & 7;
    int dir = wb >> 3;
    int g = sl >> 1, jt = sl & 1;
    int l16 = lane & 15, quad = lane >> 4;
    int n = g * Hh + wv * 32 + jt * 16 + l16;
    size_t base = ((size_t)dir * G3 + n) * Hh + k0 * 32 + quad * 8;
    bf16_t* dst = a.pk[ti] + (size_t)id * 8;
    #pragma unroll
    for (int i = 0; i < 8; ++i) dst[i] = (bf16_t)ldf(a.whhR[ti], base + i, isb);
  } else if (b < 1248) {               // ---- packWih x2 (raw wih) ----
    int ti = (b - 768) / 240, lb = (b - 768) % 240;
    int id = lb * 256 + tid;
    int lane = id & 63;
    int su = id >> 6;
    int s  = su % 40;
    int n0 = (su / 40) % 12;
    int dir = su / 480;
    int j = s / 10, k0 = s % 10;
    int l16 = lane & 15, quad = lane >> 4;
    int n = n0 * 64 + j * 16 + l16;
    int c = k0 * 32 + quad * 8;
    size_t base = ((size_t)dir * G3 + n) * D_EMB + c;
    bf16_t* dst = a.pw2[ti] + (size_t)id * 8;
    #pragma unroll
    for (int i = 0; i < 8; ++i)
      dst[i] = (c + i < D_EMB) ? (bf16_t)ldf(a.wihR[ti], base + i, isb) : (bf16_t)0.f;
  } else if (b < 1272) {               // ---- biasC x4 (raw bih/bhh) ----
    int ti = (b - 1248) / 6, lb = (b - 1248) % 6;
    int i = lb * 256 + tid;
    if (i < 2 * G3) {
      int c = i % G3;
      a.bc4[ti][i] = ldf(a.bihR[ti], i, isb) + (c < 2 * Hh ? ldf(a.bhhR[ti], i, isb) : 0.f);
    }
  } else if (b < 2808) {               // ---- transpose x2 (raw sent/doc wih) ----
    __shared__ float tile[32][33];
    int lb = b - 1272;
    int which = lb / 768;
    int r = lb % 768;
    int bx = r % 24, by = (r / 24) % 16, d = r / 384;
    const void* w = a.tsrcR[which];
    float* out = a.tdst[which];
    int n0 = bx * 32, k0 = by * 32;
    int tx = tid & 31, ty = tid >> 5;
    for (int i = ty; i < 32; i += 8)
      tile[i][tx] = ldf(w, ((size_t)d * G3 + n0 + i) * H2 + k0 + tx, isb);
    __syncthreads();
    for (int i = ty; i < 32; i += 8)
      out[((size_t)d * H2 + k0 + i) * G3 + n0 + tx] = tile[tx][i];
  } else if (b < 2812) {               // ---- lens ----
    int s = (b - 2808) * 256 + tid;
    if (s < S_TOT) {
      int c = 0;
      for (int t = 0; t < T_W; ++t) c += (a.x[s * T_W + t] != 0) ? 1 : 0;
      a.lens[s] = c;
    }
  } else {                             // ---- canon (small tensors only) ----
    int i = (b - 2812) * 256 + tid;
    if (i < a.tot2) {
      int seg = 0;
      while (a.c.off[seg + 1] <= i) ++seg;
      int j = i - a.c.off[seg];
      a.canon_dst[i] = isb ? (float)((const bf16_t*)a.c.src[seg])[j]
                           : ((const float*)a.c.src[seg])[j];
    }
  }
}

// ---------- giB device body (512t, 2 waves/SIMD) ----------
__device__ __forceinline__ void gib_body(
    const int* __restrict__ toks, const void* __restrict__ embed,
    const bf16_t* __restrict__ wpk_base, const float* __restrict__ bih_base,
    const int* __restrict__ flag, bf16_t* __restrict__ gi_base,
    size_t gi_dstride, int mbase, int bx, int dir) {
  __shared__ __align__(16) bf16_t Bt[2][20480];   // 2 x 40KB
  int tid = threadIdx.x;
  int wave = tid >> 6, lane = tid & 63;
  int l16 = lane & 15, quad = lane >> 4;
  int m0 = bx * 128;
  int isb = flag[0];
  const bf16_t* wpk = wpk_base + (size_t)dir * 245760;
  const float*  bih = bih_base + (size_t)dir * G3;
  bf16_t* gi = gi_base + (size_t)dir * gi_dstride;

  bf16x8 ah[10], al[10];
  {
    int tok = toks[mbase + m0 + wave * 16 + l16];
    if (isb) {
      const bf16_t* er = (const bf16_t*)embed + (size_t)tok * D_EMB;
      #pragma unroll
      for (int k0 = 0; k0 < 10; ++k0) {
        int c = k0 * 32 + quad * 8;
        bf16x8 v = {};
        if (c + 8 <= D_EMB) {
          bf16x4 t0 = *(const bf16x4*)(er + c);
          bf16x4 t1 = *(const bf16x4*)(er + c + 4);
          v[0]=t0[0]; v[1]=t0[1]; v[2]=t0[2]; v[3]=t0[3];
          v[4]=t1[0]; v[5]=t1[1]; v[6]=t1[2]; v[7]=t1[3];
        } else if (c < D_EMB) {
          bf16x4 t0 = *(const bf16x4*)(er + c);
          v[0]=t0[0]; v[1]=t0[1]; v[2]=t0[2]; v[3]=t0[3];
        }
        ah[k0] = v;
        al[k0] = (bf16x8){};
      }
    } else {
      const float* er = (const float*)embed + (size_t)tok * D_EMB;
      #pragma unroll
      for (int k0 = 0; k0 < 10; ++k0) {
        int c = k0 * 32 + quad * 8;
        float v[8];
        #pragma unroll
        for (int i = 0; i < 8; ++i) v[i] = 0.f;
        if (c + 4 <= D_EMB) { float4 t = *(const float4*)(er + c);
                              v[0]=t.x; v[1]=t.y; v[2]=t.z; v[3]=t.w; }
        if (c + 8 <= D_EMB) { float4 t = *(const float4*)(er + c + 4);
                              v[4]=t.x; v[5]=t.y; v[6]=t.z; v[7]=t.w; }
        bf16x8 h, l;
        #pragma unroll
        for (int i = 0; i < 8; ++i) {
          bf16_t hv = (bf16_t)v[i];
          h[i] = hv; l[i] = (bf16_t)(v[i] - (float)hv);
        }
        ah[k0] = h; al[k0] = l;
      }
    }
  }

  bf16x8 stg[5];
  {
    const bf16_t* base = wpk + (size_t)tid * 8;
    #pragma unroll
    for (int i = 0; i < 5; ++i) stg[i] = *(const bf16x8*)(base + i * 4096);
    bf16_t* dst = &Bt[0][tid * 8];
    #pragma unroll
    for (int i = 0; i < 5; ++i) *(bf16x8*)(dst + i * 4096) = stg[i];
  }
  __syncthreads();

  for (int n0 = 0; n0 < 12; ++n0) {
    int cur = n0 & 1;
    if (n0 + 1 < 12) {
      const bf16_t* base = wpk + (size_t)(n0 + 1) * 20480 + (size_t)tid * 8;
      #pragma unroll
      for (int i = 0; i < 5; ++i) stg[i] = *(const bf16x8*)(base + i * 4096);
    }
    f32x4 acc[4];
    #pragma unroll
    for (int j = 0; j < 4; ++j) acc[j] = (f32x4){0.f, 0.f, 0.f, 0.f};
    const bf16_t* Bc = Bt[cur];
    #pragma unroll
    for (int k0 = 0; k0 < 10; ++k0) {
      bf16x8 b[4];
      #pragma unroll
      for (int j = 0; j < 4; ++j)
        b[j] = *(const bf16x8*)&Bc[((j * 10 + k0) * 64 + lane) * 8];
      if (isb) {
        #pragma unroll
        for (int j = 0; j < 4; ++j)
          acc[j] = __builtin_amdgcn_mfma_f32_16x16x32_bf16(ah[k0], b[j], acc[j], 0, 0, 0);
      } else {
        #pragma unroll
        for (int j = 0; j < 4; ++j)
          acc[j] = __builtin_amdgcn_mfma_f32_16x16x32_bf16(al[k0], b[j], acc[j], 0, 0, 0);
        #pragma unroll
        for (int j = 0; j < 4; ++j)
          acc[j] = __builtin_amdgcn_mfma_f32_16x16x32_bf16(ah[k0], b[j], acc[j], 0, 0, 0);
      }
    }
    {
      int row0 = m0 + wave * 16 + quad * 4;
      #pragma unroll
      for (int j = 0; j < 4; ++j) {
        int col = n0 * 64 + j * 16 + l16;
        float bb = bih[col];
        #pragma unroll
        for (int rr = 0; rr < 4; ++rr)
          gi[(size_t)(row0 + rr) * G3 + col] = (bf16_t)(acc[j][rr] + bb);
      }
    }
    if (n0 + 1 < 12) {
      bf16_t* dst = &Bt[cur ^ 1][tid * 8];
      #pragma unroll
      for (int i = 0; i < 5; ++i) *(bf16x8*)(dst + i * 4096) = stg[i];
      __syncthreads();
    }
  }
}

__global__ __launch_bounds__(512, 1) void k_giB(
    const int* __restrict__ toks, const void* __restrict__ embed,
    const bf16_t* __restrict__ wpk_base, const float* __restrict__ bih_base,
    const int* __restrict__ flag, bf16_t* __restrict__ gi_base,
    size_t gi_dstride, int mbase) {
  gib_body(toks, embed, wpk_base, bih_base, flag, gi_base, gi_dstride, mbase,
           blockIdx.x, blockIdx.y);
}

// ---------- SGEMM device bodies ----------
__device__ __forceinline__ void dev_sgemm(
    const float* __restrict__ A, const float* __restrict__ B,
    const float* __restrict__ bias, void* __restrict__ C,
    int M, int N, int K, int obf, int bx, int by) {
  __shared__ float As[32][65];
  __shared__ float Bs[32][65];
  int bm = bx * 64, bn = by * 64;
  int tid = threadIdx.x;
  int tx = tid & 15, ty = tid >> 4;
  float acc[4][4] = {};
  for (int k0 = 0; k0 < K; k0 += 32) {
    for (int i = tid; i < 64 * 32; i += 256) {
      int m = i >> 5, k = i & 31;
      As[k][m] = (bm + m < M) ? A[(size_t)(bm + m) * K + k0 + k] : 0.f;
    }
    for (int i = tid; i < 32 * 64; i += 256) {
      int k = i >> 6, n = i & 63;
      Bs[k][n] = B[(size_t)(k0 + k) * N + bn + n];
    }
    __syncthreads();
    #pragma unroll 8
    for (int k = 0; k < 32; ++k) {
      float a[4], b[4];
      #pragma unroll
      for (int i = 0; i < 4; ++i) a[i] = As[k][ty + i * 16];
      #pragma unroll
      for (int j = 0; j < 4; ++j) b[j] = Bs[k][tx + j * 16];
      #pragma unroll
      for (int i = 0; i < 4; ++i)
        #pragma unroll
        for (int j = 0; j < 4; ++j) acc[i][j] += a[i] * b[j];
    }
    __syncthreads();
  }
  for (int i = 0; i < 4; ++i) {
    int m = bm + ty + i * 16;
    if (m >= M) continue;
    for (int j = 0; j < 4; ++j) {
      int n = bn + tx + j * 16;
      float v = acc[i][j] + (bias ? bias[n] : 0.f);
      if (obf) ((bf16_t*)C)[(size_t)m * N + n] = (bf16_t)v;
      else     ((float*)C)[(size_t)m * N + n] = v;
    }
  }
}

// 512-thread variant: staging uses all threads; compute/writeback guarded to
// tid<256 with UNIFORM barriers (k0 loop trip count is uniform).
__device__ __forceinline__ void dev_sgemm512(
    const float* __restrict__ A, const float* __restrict__ B,
    const float* __restrict__ bias, void* __restrict__ C,
    int M, int N, int K, int obf, int bx, int by) {
  __shared__ float As[32][65];
  __shared__ float Bs[32][65];
  int bm = bx * 64, bn = by * 64;
  int tid = threadIdx.x;
  int tx = tid & 15, ty = (tid >> 4) & 15;
  float acc[4][4] = {};
  for (int k0 = 0; k0 < K; k0 += 32) {
    for (int i = tid; i < 64 * 32; i += 512) {
      int m = i >> 5, k = i & 31;
      As[k][m] = (bm + m < M) ? A[(size_t)(bm + m) * K + k0 + k] : 0.f;
    }
    for (int i = tid; i < 32 * 64; i += 512) {
      int k = i >> 6, n = i & 63;
      Bs[k][n] = B[(size_t)(k0 + k) * N + bn + n];
    }
    __syncthreads();
    if (tid < 256) {
      #pragma unroll 8
      for (int k = 0; k < 32; ++k) {
        float a[4], b[4];
        #pragma unroll
        for (int i = 0; i < 4; ++i) a[i] = As[k][ty + i * 16];
        #pragma unroll
        for (int j = 0; j < 4; ++j) b[j] = Bs[k][tx + j * 16];
        #pragma unroll
        for (int i = 0; i < 4; ++i)
          #pragma unroll
          for (int j = 0; j < 4; ++j) acc[i][j] += a[i] * b[j];
      }
    }
    __syncthreads();
  }
  if (tid < 256) {
    for (int i = 0; i < 4; ++i) {
      int m = bm + ty + i * 16;
      if (m >= M) continue;
      for (int j = 0; j < 4; ++j) {
        int n = bn + tx + j * 16;
        float v = acc[i][j] + (bias ? bias[n] : 0.f);
        if (obf) ((bf16_t*)C)[(size_t)m * N + n] = (bf16_t)v;
        else     ((float*)C)[(size_t)m * N + n] = v;
      }
    }
  }
}

// ---------- GRU body (exact round-2 v2 — frozen local optimum; dir is a param) ----------
__device__ __forceinline__ void gru_body(
    const bf16_t* __restrict__ gi, size_t gi_dstride,
    const bf16_t* __restrict__ whhP, const float* __restrict__ bhh,
    const int* __restrict__ lens, float* __restrict__ pool,
    int T, int sbase, int nsent, int sblk, int dir) {
  int tid = threadIdx.x;
  int wave = tid >> 6, lane = tid & 63;
  int l16 = lane & 15, quad = lane >> 4;
  const bf16_t* giD  = gi + (size_t)dir * gi_dstride;
  const float*  bhhD = bhh + (size_t)dir * G3;

  __shared__ __align__(16) bf16_t hA[2][8][16][4][8];

  bf16x8 Bf[48];
  {
    const bf16_t* Bb = whhP + (size_t)dir * G3 * Hh + (size_t)wave * 48 * 512 + lane * 8;
    #pragma unroll
    for (int s = 0; s < 48; ++s) Bf[s] = *(const bf16x8*)(Bb + s * 512);
  }
  float bhn[2];
  #pragma unroll
  for (int jt = 0; jt < 2; ++jt)
    bhn[jt] = bhhD[2 * Hh + wave * 32 + jt * 16 + l16];
  int Lm[4];
  #pragma unroll
  for (int r = 0; r < 4; ++r) {
    int sa = sblk + quad * 4 + r;
    Lm[r] = (lens && sa < nsent) ? lens[sbase + sa] : T;
  }
  float pmax[2][4], hreg[2][4];
  #pragma unroll
  for (int jt = 0; jt < 2; ++jt)
    #pragma unroll
    for (int r = 0; r < 4; ++r) { pmax[jt][r] = -1e30f; hreg[jt][r] = 0.f; }

  int t0 = dir ? (T - 1) : 0;
  long long stepoff = dir ? -(long long)G3 : (long long)G3;
  const bf16_t* rp[4];
  #pragma unroll
  for (int r = 0; r < 4; ++r)
    rp[r] = giD + ((size_t)(sblk + quad * 4 + r) * T + t0) * (size_t)G3;

  {
    bf16_t* hz = &hA[0][0][0][0][0];
    for (int i = tid; i < 8 * 16 * 4 * 8; i += 512) hz[i] = (bf16_t)0.f;
  }

  bf16_t gv[3][2][4];
  #pragma unroll
  for (int jt = 0; jt < 2; ++jt) {
    int j = wave * 32 + jt * 16 + l16;
    #pragma unroll
    for (int r = 0; r < 4; ++r) {
      gv[0][jt][r] = rp[r][j];
      gv[1][jt][r] = rp[r][Hh + j];
      gv[2][jt][r] = rp[r][2 * Hh + j];
    }
  }
  __syncthreads();

  int cur = 0;
  for (int step = 0; step < T; ++step) {
    int t = dir ? (T - 1 - step) : step;
    f32x4 C[3][2];
    #pragma unroll
    for (int g = 0; g < 3; ++g)
      #pragma unroll
      for (int jt = 0; jt < 2; ++jt) C[g][jt] = (f32x4){0.f, 0.f, 0.f, 0.f};
    #pragma unroll
    for (int k0 = 0; k0 < 8; ++k0) {
      bf16x8 a8 = *(const bf16x8*)&hA[cur][k0][l16][quad][0];
      #pragma unroll
      for (int g = 0; g < 3; ++g)
        #pragma unroll
        for (int jt = 0; jt < 2; ++jt)
          C[g][jt] = __builtin_amdgcn_mfma_f32_16x16x32_bf16(a8, Bf[(g * 2 + jt) * 8 + k0], C[g][jt], 0, 0, 0);
    }
    #pragma unroll
    for (int jt = 0; jt < 2; ++jt) {
      int q2 = jt * 2 + (l16 >> 3);
      int ii = l16 & 7;
      #pragma unroll
      for (int r = 0; r < 4; ++r) {
        int m = quad * 4 + r;
        float hp = hreg[jt][r];
        float rr = fsigm((float)gv[0][jt][r] + C[0][jt][r]);
        float zz = fsigm((float)gv[1][jt][r] + C[1][jt][r]);
        float nn = ftanh_((float)gv[2][jt][r] + rr * (C[2][jt][r] + bhn[jt]));
        float hnew = nn + zz * (hp - nn);
        hreg[jt][r] = hnew;
        hA[cur ^ 1][wave][m][q2][ii] = (bf16_t)hnew;
        if (t < Lm[r]) pmax[jt][r] = fmaxf(pmax[jt][r], hnew);
      }
    }
    #pragma unroll
    for (int r = 0; r < 4; ++r) rp[r] += stepoff;
    if (step + 1 < T) {
      #pragma unroll
      for (int jt = 0; jt < 2; ++jt) {
        int j = wave * 32 + jt * 16 + l16;
        #pragma unroll
        for (int r = 0; r < 4; ++r) {
          gv[0][jt][r] = rp[r][j];
          gv[1][jt][r] = rp[r][Hh + j];
          gv[2][jt][r] = rp[r][2 * Hh + j];
        }
      }
    }
    asm volatile("s_waitcnt lgkmcnt(0)" ::: "memory");
    __builtin_amdgcn_s_barrier();
    cur ^= 1;
  }
  #pragma unroll
  for (int jt = 0; jt < 2; ++jt) {
    int j = wave * 32 + jt * 16 + l16;
    #pragma unroll
    for (int r = 0; r < 4; ++r) {
      int sa = sblk + quad * 4 + r;
      if (sa < nsent) {
        float v = pmax[jt][r];
        if (v < -9e29f) v = 0.f;
        pool[(size_t)(sbase + sa) * H2 + dir * Hh + j] = v;
      }
    }
  }
}

__global__ __launch_bounds__(512)
__attribute__((amdgpu_waves_per_eu(2, 2)))
void k_gruM(
    const bf16_t* __restrict__ gi, size_t gi_dstride,
    const bf16_t* __restrict__ whhP, const float* __restrict__ bhh,
    const int* __restrict__ lens, float* __restrict__ pool,
    int T, int sbase, int nsent) {
  gru_body(gi, gi_dstride, whhP, bhh, lens, pool, T, sbase, nsent,
           blockIdx.x * 16, blockIdx.y);
}

// ---------- fused [word gruM || event giB] (96KB LDS -> 1 block/CU) ----------
__global__ __launch_bounds__(512)
__attribute__((amdgpu_waves_per_eu(2, 2)))
void k_wg(
    const bf16_t* __restrict__ giW, size_t strideW,
    const bf16_t* __restrict__ whhW, const float* __restrict__ bhhW,
    const int* __restrict__ lens, float* __restrict__ poolW,
    const int* __restrict__ etoks, const void* __restrict__ embed,
    const bf16_t* __restrict__ wpkE, const float* __restrict__ bihE,
    const int* __restrict__ flag, bf16_t* __restrict__ giE, size_t strideE) {
  if ((int)blockIdx.x < 64)
    gru_body(giW, strideW, whhW, bhhW, lens, poolW, 32, 0, 1024,
             blockIdx.x * 16, blockIdx.y);
  else
    gib_body(etoks, embed, wpkE, bihE, flag, giE, strideE, 0,
             blockIdx.x - 64, blockIdx.y);
}

// ---------- tail 1: event gruM (evblocks) || sgemm_su (512 blocks) ----------
__global__ __launch_bounds__(512)
__attribute__((amdgpu_waves_per_eu(2, 2)))
void k_tail1(
    const bf16_t* __restrict__ giE, size_t strideE,
    const bf16_t* __restrict__ packE, const float* __restrict__ bhhE,
    float* __restrict__ evv,
    const float* __restrict__ sv, const float* __restrict__ wSt,
    const float* __restrict__ bcS, bf16_t* __restrict__ sgi,
    const float* __restrict__ wer, float* __restrict__ u, int evblocks) {
  int b = blockIdx.x;
  if (b < evblocks) {
    int dir = b / 192, bx = b % 192;
    gru_body(giE, strideE, packE, bhhE, nullptr, evv, 4, 0, 3072, bx * 16, dir);
  } else {
    int b2 = b - evblocks;
    int bx = b2 & 15, y = b2 >> 4;
    if (y < 12)
      dev_sgemm512(sv, wSt, bcS, sgi, 1024, G3, H2, 1, bx, y);
    else if (y < 24)
      dev_sgemm512(sv, wSt + (size_t)H2 * G3, bcS + G3, sgi + (size_t)S_TOT * G3,
                   1024, G3, H2, 1, bx, y - 12);
    else
      dev_sgemm512(sv, wer, nullptr, u, 1024, H2, H2, 0, bx, y - 24);
  }
}

// ---------- tail 2: sent gruM (4) || colsum (48) ----------
__global__ __launch_bounds__(512)
__attribute__((amdgpu_waves_per_eu(2, 2)))
void k_tail2(
    const bf16_t* __restrict__ sgi, const bf16_t* __restrict__ packS,
    const float* __restrict__ bhhS, float* __restrict__ dv,
    const float* __restrict__ evv, float* __restrict__ part) {
  int b = blockIdx.x, t = threadIdx.x;
  if (b < 4) {
    gru_body(sgi, (size_t)S_TOT * G3, packS, bhhS, nullptr, dv, 32, 0, 32,
             (b & 1) * 16, b >> 1);
  } else {
    int cb = b - 4;
    int r0 = cb * 64;
    float s = 0.f;
    for (int r = 0; r < 64; ++r) s += evv[(size_t)(r0 + r) * H2 + t];
    part[(size_t)cb * H2 + t] = s;
  }
}

// ---------- tail 3 (256t): doc sgemm (24) || esumves (1) ----------
__global__ __launch_bounds__(256) void k_tail3(
    const float* __restrict__ dv, const float* __restrict__ wDt,
    const float* __restrict__ bcD, bf16_t* __restrict__ dgi,
    const float* __restrict__ part, const float* __restrict__ Wes,
    float* __restrict__ ves) {
  int b = blockIdx.x, t = threadIdx.x;
  if (b < 24) {
    int y = b;
    if (y < 12)
      dev_sgemm(dv, wDt, bcD, dgi, 32, G3, H2, 1, 0, y);
    else
      dev_sgemm(dv, wDt + (size_t)H2 * G3, bcD + G3, dgi + (size_t)32 * G3,
                32, G3, H2, 1, 0, y - 12);
  } else {
    __shared__ float es[H2];
    for (int c = t; c < H2; c += 256) {
      float s = 0.f;
      for (int bb = 0; bb < 48; ++bb) s += part[(size_t)bb * H2 + c];
      es[c] = s;
    }
    __syncthreads();
    for (int r = t; r < H2; r += 256) {
      const float* row = Wes + (size_t)r * H2;
      float v = 0.f;
      for (int f = 0; f < H2; ++f) v += row[f] * es[f];
      ves[r] = v * (1.f / 3072.f);
    }
  }
}

// ---------- tail 4: doc gruM (2) || eventprobs (384 blocks, 8 events each) ----------
__global__ __launch_bounds__(512)
__attribute__((amdgpu_waves_per_eu(2, 2)))
void k_tail4(
    const bf16_t* __restrict__ dgi, const bf16_t* __restrict__ packD,
    const float* __restrict__ bhhD, float* __restrict__ blog,
    const float* __restrict__ evv, const float* __restrict__ ves,
    const float* __restrict__ w_ec, const float* __restrict__ tfs,
    const float* __restrict__ st, const float* __restrict__ c_tf,
    const float* __restrict__ c_sent, const float* __restrict__ c_bias,
    const int* __restrict__ flag, float* __restrict__ probs,
    void* __restrict__ outp) {
  int b = blockIdx.x;
  if (b < 2) {
    gru_body(dgi, (size_t)32 * G3, packD, bhhD, nullptr, blog, 32, 0, 1, 0, b);
  } else {
    int lane = threadIdx.x & 63;
    int e = (b - 2) * 8 + (threadIdx.x >> 6);
    const float* row = evv + (size_t)e * H2;
    float s = 0.f;
    for (int f = lane; f < H2; f += 64) s += row[f] * (w_ec[f] + ves[f]);
    #pragma unroll
    for (int o = 32; o > 0; o >>= 1) s += __shfl_down(s, o, 64);
    if (lane == 0) {
      float p = s + c_tf[0] * tfs[e] + c_bias[0] + c_sent[0] * st[e / 3];
      probs[e] = p;
      if (flag[0]) ((bf16_t*)outp)[S_TOT + e] = (bf16_t)p;
      else         ((float*)outp)[S_TOT + e] = p;
    }
  }
}

// ---------- tail 5: wsal (32 blocks) ----------
__global__ __launch_bounds__(512) void k_tail5(
    const float* __restrict__ W, const float* __restrict__ blog,
    const float* __restrict__ dv, float* __restrict__ wsal) {
  int doc = blockIdx.x, t = threadIdx.x;
  const float* row = W + (size_t)t * (2 * H2);
  const float* dvr = dv + (size_t)doc * H2;
  float s = 0.f;
  for (int f = 0; f < H2; ++f) s += row[f] * blog[f];
  for (int f = 0; f < H2; ++f) s += row[H2 + f] * dvr[f];
  wsal[(size_t)doc * H2 + t] = s;
}

__global__ __launch_bounds__(256) void k_sentout(
    const float* __restrict__ sv, const float* __restrict__ u,
    const float* __restrict__ evv, const float* __restrict__ probs,
    const float* __restrict__ wsal, const float* __restrict__ w_sc,
    const float* __restrict__ dpe, const float* __restrict__ spe,
    const float* __restrict__ w_sdp, const float* __restrict__ w_sp,
    const float* __restrict__ b_rel, const float* __restrict__ para,
    const float* __restrict__ sbias, const int* __restrict__ flag,
    void* __restrict__ outp) {
  int lane = threadIdx.x & 63;
  int s = blockIdx.x * 4 + (threadIdx.x >> 6);
  int doc = s >> 5, jj = s & 31;
  const float* svr = sv + (size_t)s * H2;
  const float* ur  = u + (size_t)s * H2;
  const float* wd  = wsal + (size_t)doc * H2;
  float acc = 0.f, e0 = 0.f, e1 = 0.f, e2 = 0.f;
  for (int f = lane; f < H2; f += 64) {
    float svf = svr[f], uf = ur[f];
    acc += svf * (w_sc[f] + wd[f]);
    e0 += uf * evv[(size_t)(s * 3 + 0) * H2 + f];
    e1 += uf * evv[(size_t)(s * 3 + 1) * H2 + f];
    e2 += uf * evv[(size_t)(s * 3 + 2) * H2 + f];
  }
  if (lane < 50) {
    int dpos = (doc * 40) / 32;
    int spos = (jj * 30) / 32;
    acc += dpe[dpos * 50 + lane] * w_sdp[lane] + spe[spos * 50 + lane] * w_sp[lane];
  }
  #pragma unroll
  for (int o = 32; o > 0; o >>= 1) {
    acc += __shfl_down(acc, o, 64);
    e0  += __shfl_down(e0, o, 64);
    e1  += __shfl_down(e1, o, 64);
    e2  += __shfl_down(e2, o, 64);
  }
  if (lane == 0) {
    float br = b_rel[0];
    float rel = (e0 + br) * probs[s * 3 + 0] + (e1 + br) * probs[s * 3 + 1]
              + (e2 + br) * probs[s * 3 + 2];
    float v = acc + para[0] * rel + sbias[0];
    if (flag[0]) ((bf16_t*)outp)[s] = (bf16_t)v;
    else         ((float*)outp)[s] = v;
  }
}

// ---------------- launcher ----------------
extern "C" void kernel_launch(void* const* d_in, const int* in_sizes, int n_in,
                              void* d_out, int out_size, void* d_ws, size_t ws_size,
                              hipStream_t stream) {
  (void)in_sizes; (void)n_in; (void)out_size;
  const int* x      = (const int*)d_in[0];
  const int* events = (const int*)d_in[1];
  const void* embed = d_in[8];

  char* ws = (char*)d_ws;
  size_t off = 0;
  auto alloc = [&](size_t bytes) -> void* {
    void* p = ws + off;
    off += (bytes + 255) & ~(size_t)255;
    return p;
  };

  // canon keeps only non-weight tensors (weights are read raw by k_prepAll)
  static const int cidx[NC2] = {12,16,20,24, 25,26,27,28,29,30,31,
                                32,33,34,35,36,37,38,40, 5,7};
  static const int csz[NC2]  = {2*G3, 2*G3, 2*G3, 2*G3,
                                40*50, 30*50, H2, H2*H2, 1, 1, 1,
                                H2, H2*2*H2, 50, 50, H2*H2, 1, 1, 1,
                                E_TOT, S_TOT};
  Canon cd;
  int tot2 = 0;
  for (int i = 0; i < NC2; ++i) { cd.src[i] = d_in[cidx[i]]; cd.off[i] = tot2; tot2 += csz[i]; }
  cd.off[NC2] = tot2;

  int*   flag  = (int*)alloc(256);
  float* canon = (float*)alloc((size_t)tot2 * 4);
  float* cptr[NC2];
  for (int i = 0; i < NC2; ++i) cptr[i] = canon + cd.off[i];
  float *cw_bhh = cptr[0], *cs_bhh = cptr[1], *cd_bhh = cptr[2], *ce_bhh = cptr[3];
  float *c_dpe = cptr[4], *c_spe = cptr[5], *c_wec = cptr[6], *c_Wes = cptr[7];
  float *c_tf = cptr[8], *c_sent = cptr[9], *c_ebias = cptr[10];
  float *c_wsc = cptr[11], *c_Wss = cptr[12], *c_wsdp = cptr[13], *c_wsp = cptr[14];
  float *c_Wer = cptr[15], *c_brel = cptr[16], *c_para = cptr[17], *c_sbias = cptr[18];
  float *c_tfs = cptr[19], *c_starg = cptr[20];

  bf16_t* packW = (bf16_t*)alloc((size_t)2 * G3 * Hh * 2);
  bf16_t* packE = (bf16_t*)alloc((size_t)2 * G3 * Hh * 2);
  bf16_t* packS = (bf16_t*)alloc((size_t)2 * G3 * Hh * 2);
  bf16_t* packD = (bf16_t*)alloc((size_t)2 * G3 * Hh * 2);
  bf16_t* packGiW = (bf16_t*)alloc((size_t)2 * 12 * 40 * 64 * 8 * 2);
  bf16_t* packGiE = (bf16_t*)alloc((size_t)2 * 12 * 40 * 64 * 8 * 2);
  float*  bcW  = (float*)alloc((size_t)2 * G3 * 4);
  float*  bcE  = (float*)alloc((size_t)2 * G3 * 4);
  float*  bcS  = (float*)alloc((size_t)2 * G3 * 4);
  float*  bcD  = (float*)alloc((size_t)2 * G3 * 4);
  float*  sv   = (float*)alloc((size_t)S_TOT * H2 * 4);
  float*  evv  = (float*)alloc((size_t)E_TOT * H2 * 4);
  float*  dv   = (float*)alloc((size_t)32 * H2 * 4);
  float*  blog = (float*)alloc((size_t)H2 * 4);
  float*  wSt  = (float*)alloc((size_t)2 * H2 * G3 * 4);
  float*  wDt  = (float*)alloc((size_t)2 * H2 * G3 * 4);
  float*  u    = (float*)alloc((size_t)S_TOT * H2 * 4);
  float*  part = (float*)alloc((size_t)48 * H2 * 4);
  float*  ves  = (float*)alloc((size_t)H2 * 4);
  float*  wsal = (float*)alloc((size_t)32 * H2 * 4);
  float*  probs= (float*)alloc((size_t)E_TOT * 4);
  int*    lens = (int*)alloc((size_t)S_TOT * 4);
  bf16_t* sgi  = (bf16_t*)alloc((size_t)2 * S_TOT * G3 * 2);
  bf16_t* dgi  = (bf16_t*)alloc((size_t)2 * 32 * G3 * 2);

  size_t fixed = off;
  size_t avail = (ws_size > fixed) ? (ws_size - fixed) : 0;
  const size_t needW = (size_t)2 * 32768 * G3 * 2;
  const size_t needE = (size_t)2 * 12288 * G3 * 2;
  bf16_t* gib = (bf16_t*)(ws + fixed);

  PrepArgs pa;
  pa.whhR[0]=d_in[10]; pa.whhR[1]=d_in[22]; pa.whhR[2]=d_in[14]; pa.whhR[3]=d_in[18];
  pa.pk[0]=packW; pa.pk[1]=packE; pa.pk[2]=packS; pa.pk[3]=packD;
  pa.wihR[0]=d_in[9]; pa.wihR[1]=d_in[21]; pa.pw2[0]=packGiW; pa.pw2[1]=packGiE;
  pa.bihR[0]=d_in[11]; pa.bihR[1]=d_in[23]; pa.bihR[2]=d_in[15]; pa.bihR[3]=d_in[19];
  pa.bhhR[0]=d_in[12]; pa.bhhR[1]=d_in[24]; pa.bhhR[2]=d_in[16]; pa.bhhR[3]=d_in[20];
  pa.bc4[0]=bcW; pa.bc4[1]=bcE; pa.bc4[2]=bcS; pa.bc4[3]=bcD;
  pa.tsrcR[0]=d_in[13]; pa.tsrcR[1]=d_in[17]; pa.tdst[0]=wSt; pa.tdst[1]=wDt;
  pa.x = x; pa.lens = lens;
  pa.flag = flag; pa.c = cd; pa.canon_dst = canon; pa.tot2 = tot2;

  int prepBlocks = 2812 + (tot2 + 255) / 256;

  // ---- head: 2 dispatches ----
  k_detect<<<1, 64, 0, stream>>>((const unsigned short*)embed, flag);
  k_prepAll<<<prepBlocks, 256, 0, stream>>>(pa);

  if (avail >= needW + needE) {
    bf16_t* egib = (bf16_t*)((char*)gib + ((needW + 255) & ~(size_t)255));
    k_giB<<<dim3(256, 2), 512, 0, stream>>>(x, embed, packGiW, bcW, flag,
                                            gib, (size_t)32768 * G3, 0);
    k_wg<<<dim3(64 + 96, 2), 512, 0, stream>>>(
        gib, (size_t)32768 * G3, packW, cw_bhh, lens, sv,
        events, embed, packGiE, bcE, flag, egib, (size_t)12288 * G3);
    k_tail1<<<384 + 512, 512, 0, stream>>>(
        egib, (size_t)12288 * G3, packE, ce_bhh, evv,
        sv, wSt, bcS, sgi, c_Wer, u, 384);
  } else {
    // ---- fallback: chunked sequential path ----
    long long rpc = (long long)(avail / ((size_t)G3 * 2 * 2));
    rpc &= ~511LL;
    if (rpc < 512) rpc = 512;
    if (rpc > 32768) rpc = 32768;
    for (long long r0 = 0; r0 < 32768; r0 += rpc) {
      long long rows = 32768 - r0; if (rows > rpc) rows = rpc;
      k_giB<<<dim3((int)(rows / 128), 2), 512, 0, stream>>>(
          x, embed, packGiW, bcW, flag, gib, (size_t)rows * G3, (int)r0);
      k_gruM<<<dim3((int)(rows / 512), 2), 512, 0, stream>>>(
          gib, (size_t)rows * G3, packW, cw_bhh, lens, sv, 32, (int)(r0 / 32),
          (int)(rows / 32));
    }
    for (long long r0 = 0; r0 < 12288; r0 += rpc) {
      long long rows = 12288 - r0; if (rows > rpc) rows = rpc;
      k_giB<<<dim3((int)(rows / 128), 2), 512, 0, stream>>>(
          events, embed, packGiE, bcE, flag, gib, (size_t)rows * G3, (int)r0);
      k_gruM<<<dim3((int)(rows / 64), 2), 512, 0, stream>>>(
          gib, (size_t)rows * G3, packE, ce_bhh, nullptr, evv, 4, (int)(r0 / 4),
          (int)(rows / 4));
    }
    k_tail1<<<512, 512, 0, stream>>>(
        nullptr, 0, packE, ce_bhh, evv, sv, wSt, bcS, sgi, c_Wer, u, 0);
  }

  // ---- overlapped tail ----
  k_tail2<<<52, 512, 0, stream>>>(sgi, packS, cs_bhh, dv, evv, part);
  k_tail3<<<25, 256, 0, stream>>>(dv, wDt, bcD, dgi, part, c_Wes, ves);
  k_tail4<<<386, 512, 0, stream>>>(dgi, packD, cd_bhh, blog, evv, ves,
                                   c_wec, c_tfs, c_starg, c_tf, c_sent, c_ebias,
                                   flag, probs, d_out);
  k_tail5<<<32, 512, 0, stream>>>(c_Wss, blog, dv, wsal);
  k_sentout<<<256, 256, 0, stream>>>(sv, u, evv, probs, wsal, c_wsc, c_dpe, c_spe,
                                     c_wsdp, c_wsp, c_brel, c_para, c_sbias, flag, d_out);
}